// Round 1
// baseline (880.820 us; speedup 1.0000x reference)
//
#include <hip/hip_runtime.h>
#include <hip/hip_bf16.h>
#include <math.h>

typedef __attribute__((ext_vector_type(8))) short short8;
typedef __attribute__((ext_vector_type(4))) float float4_t;
typedef unsigned short ushort_t;

// Problem constants: B=8, C=256, L=2048, E=512, CH=4
#define NBL 16384          // B*L
#define FPAD 2052          // padded complex row length (2049 used)

// ---------------- workspace layout (bytes). total 233,517,056 ----------------
#define WS_CONVA   ((size_t)0)          // bf16 [512][768]
#define WS_WV      ((size_t)786432)     // bf16 [512][512]
#define WS_WO      ((size_t)1310720)    // bf16 [512][512]
#define WS_W1      ((size_t)1835008)    // bf16 [512][2048]
#define WS_WCAT    ((size_t)3932160)    // bf16 [512][256]  rows 0-255 res_w, 256-511 skip_w
#define WS_A2      ((size_t)4194304)    // bf16 [512][512]  I + Wo@Wv
#define WS_ACOMB   ((size_t)4718592)    // bf16 [512][2048] A2 @ s4_out_w
#define WS_B2      ((size_t)6815744)    // f32 [512]
#define WS_BCOMB   ((size_t)6817792)    // f32 [512]
#define WS_XN      ((size_t)6819840)    // f32 [8][256][2048]
#define WS_H0P     ((size_t)23597056)   // bf16 [256][8][2050]  padded x+orig
#define WS_U       ((size_t)31993856)   // f32 [512][16384]   conv+gelu -> (in-place LN) u
#define WS_UF      ((size_t)65548288)   // float2 [4096][2052]
#define WS_KF      ((size_t)132788224)  // float2 [2048][2052]
#define WS_G       ((size_t)166408192)  // bf16 [2048][16384] gelu(y + D*u)
#define WS_H2      WS_KF                // bf16 [512][16384]  (kf dead by then)
#define WS_GATE    WS_H0P               // bf16 [256][16384]  (h0p dead by then)

__device__ inline float gelu_f(float x) {
    return 0.5f * x * (1.0f + erff(x * 0.70710678118654752f));
}

// ============================ weight prep (fused converts + b2) ============================
__global__ __launch_bounds__(256) void wprep_kernel(
    const float* __restrict__ conv_w, const float* __restrict__ attn_v_w,
    const float* __restrict__ attn_o_w, const float* __restrict__ s4_out_w,
    const float* __restrict__ res_w, const float* __restrict__ skip_w,
    const float* __restrict__ attn_v_b, const float* __restrict__ attn_o_b,
    __hip_bfloat16* __restrict__ convA, __hip_bfloat16* __restrict__ WvBf,
    __hip_bfloat16* __restrict__ WoBf, __hip_bfloat16* __restrict__ W1Bf,
    __hip_bfloat16* __restrict__ Wcat, float* __restrict__ b2)
{
    const int N0 = 393216, N1 = 655360, N2c = 917504, N3 = 1966080, N4 = 2097152, N5 = 2097664;
    for (int i = blockIdx.x * 256 + threadIdx.x; i < N5; i += gridDim.x * 256) {
        if (i < N0)       convA[i]     = __float2bfloat16(conv_w[i]);
        else if (i < N1)  WvBf[i - N0] = __float2bfloat16(attn_v_w[i - N0]);
        else if (i < N2c) WoBf[i - N1] = __float2bfloat16(attn_o_w[i - N1]);
        else if (i < N3)  W1Bf[i - N2c] = __float2bfloat16(s4_out_w[i - N2c]);
        else if (i < N4) {
            int j = i - N3; int m = j >> 8, c = j & 255;
            float v = (m < 256) ? res_w[m * 256 + c] : skip_w[(m - 256) * 256 + c];
            Wcat[j] = __float2bfloat16(v);
        } else {
            int o = i - N4;
            float s = attn_o_b[o];
            for (int e = 0; e < 512; ++e) s += attn_o_w[o * 512 + e] * attn_v_b[e];
            b2[o] = s;  // b2 = Wo@bv + bo
        }
    }
}

__global__ __launch_bounds__(256) void bcomb_kernel(
    const __hip_bfloat16* __restrict__ A2, const float* __restrict__ b1,
    const float* __restrict__ b2, float* __restrict__ bcomb)
{
    int o = blockIdx.x * 256 + threadIdx.x;
    if (o >= 512) return;
    float s = b2[o];
    for (int e = 0; e < 512; ++e) s += __bfloat162float(A2[o * 512 + e]) * b1[e];
    bcomb[o] = s;   // bcomb = A2 @ s4_out_b + b2
}

// ============================ prep: RMSNorm(x) + padded bf16 (x+orig) ============================
__global__ __launch_bounds__(256) void prep_kernel(
    const float* __restrict__ x, const float* __restrict__ orig,
    const float* __restrict__ sn, float* __restrict__ xn, ushort_t* __restrict__ h0p)
{
    __shared__ float red[4][64];
    int blk = blockIdx.x, t = threadIdx.x;
    int lane = t & 63, cg = t >> 6;
    int b = blk >> 5, l = ((blk & 31) << 6) + lane;
    size_t basein = (size_t)b * 524288 + l;
    float ss = 0.f;
    for (int c = cg; c < 256; c += 4) { float v = x[basein + (size_t)c * 2048]; ss += v * v; }
    red[cg][lane] = ss;
    __syncthreads();
    float tot = red[0][lane] + red[1][lane] + red[2][lane] + red[3][lane];
    float inv = 1.0f / (sqrtf(tot) * 0.0625f + 1e-8f);   // rms = sqrt(sum)/16
    __hip_bfloat16* hp = (__hip_bfloat16*)h0p;
    for (int c = cg; c < 256; c += 4) {
        size_t idx = basein + (size_t)c * 2048;
        float xv = x[idx];
        xn[idx] = sn[c] * xv * inv;
        hp[(size_t)c * 16400 + b * 2050 + 1 + l] = __float2bfloat16(xv + orig[idx]);
    }
    if ((blk & 31) == 0) {   // zero pads, one c per thread
        hp[(size_t)t * 16400 + b * 2050]        = __float2bfloat16(0.f);
        hp[(size_t)t * 16400 + b * 2050 + 2049] = __float2bfloat16(0.f);
    }
}

// ============================ LayerNorm over E (in-place) ============================
__global__ __launch_bounds__(256) void ln_kernel(
    float* __restrict__ h, const float* __restrict__ gam, const float* __restrict__ bet)
{
    __shared__ float r1[4][64], r2[4][64];
    int blk = blockIdx.x, t = threadIdx.x;
    int lane = t & 63, og = t >> 6;
    int n = (blk << 6) + lane;
    float s1 = 0.f, s2 = 0.f;
    for (int o = og; o < 512; o += 4) { float v = h[(size_t)o * NBL + n]; s1 += v; s2 += v * v; }
    r1[og][lane] = s1; r2[og][lane] = s2;
    __syncthreads();
    float mu = (r1[0][lane] + r1[1][lane] + r1[2][lane] + r1[3][lane]) * (1.f / 512.f);
    float m2 = (r2[0][lane] + r2[1][lane] + r2[2][lane] + r2[3][lane]) * (1.f / 512.f);
    float rstd = rsqrtf(m2 - mu * mu + 1e-5f);
    for (int o = og; o < 512; o += 4) {
        size_t idx = (size_t)o * NBL + n;
        h[idx] = (h[idx] - mu) * rstd * gam[o] + bet[o];
    }
}

// ============================ FFT core: radix-4 DIT, 4096 pts, in skewed LDS ============================
__device__ inline int rev4_12(int i) {   // reverse 6 base-4 digits
    return ((i & 3) << 10) | ((i & 12) << 6) | ((i & 48) << 2) |
           ((i >> 2) & 48) | ((i >> 6) & 12) | ((i >> 10) & 3);
}
#define SKW(i) ((i) + ((i) >> 4))

__device__ inline float2 cmulf(float2 a, float2 b) {
    return make_float2(a.x * b.x - a.y * b.y, a.x * b.y + a.y * b.x);
}

__device__ void fft_core(float2* S, int t)   // forward FFT (W = e^{-2pi i/len})
{
    for (int s = 0; s < 6; ++s) {
        int lq = 2 * s; int q = 1 << lq;
        float invlen = 1.0f / (float)(q << 2);
        #pragma unroll
        for (int it = 0; it < 4; ++it) {
            int bf = t + it * 256;
            int p = bf & (q - 1);
            int g = bf >> lq;
            int base = (g << (lq + 2)) + p;
            float2 u0 = S[SKW(base)], u1 = S[SKW(base + q)];
            float2 u2 = S[SKW(base + 2 * q)], u3 = S[SKW(base + 3 * q)];
            float ang = -6.283185307179586f * (float)p * invlen;
            float sn, cs; __sincosf(ang, &sn, &cs);
            float2 w1 = make_float2(cs, sn);
            float2 w2 = make_float2(cs * cs - sn * sn, 2.0f * cs * sn);
            float2 w3 = cmulf(w1, w2);
            float2 b1 = cmulf(u1, w1), b2v = cmulf(u2, w2), b3 = cmulf(u3, w3);
            float2 s02 = make_float2(u0.x + b2v.x, u0.y + b2v.y);
            float2 d02 = make_float2(u0.x - b2v.x, u0.y - b2v.y);
            float2 s13 = make_float2(b1.x + b3.x, b1.y + b3.y);
            float2 d13 = make_float2(b1.x - b3.x, b1.y - b3.y);
            float2 X0 = make_float2(s02.x + s13.x, s02.y + s13.y);
            float2 X2 = make_float2(s02.x - s13.x, s02.y - s13.y);
            float2 X1 = make_float2(d02.x + d13.y, d02.y - d13.x);  // d02 - i*d13
            float2 X3 = make_float2(d02.x - d13.y, d02.y + d13.x);  // d02 + i*d13
            S[SKW(base)] = X0; S[SKW(base + q)] = X1;
            S[SKW(base + 2 * q)] = X2; S[SKW(base + 3 * q)] = X3;
        }
        __syncthreads();
    }
}

// forward rfft rows: wg < 4096 -> u rows (b,e); else s4_kernel rows (ch,e)
__global__ __launch_bounds__(256) void fft_fwd_kernel(
    const float* __restrict__ u, const float* __restrict__ s4k,
    float2* __restrict__ uf, float2* __restrict__ kf)
{
    __shared__ float2 S[4352];
    int wg = blockIdx.x, t = threadIdx.x;
    const float* src; float2* dst;
    if (wg < 4096) { int b = wg >> 9, e = wg & 511; src = u + (size_t)e * NBL + b * 2048; dst = uf + (size_t)wg * FPAD; }
    else           { int w2 = wg - 4096;            src = s4k + (size_t)w2 * 2048;        dst = kf + (size_t)w2 * FPAD; }
    for (int i = t; i < 4096; i += 256) {
        float2 v = make_float2((i < 2048) ? src[i] : 0.0f, 0.0f);
        S[SKW(rev4_12(i))] = v;
    }
    __syncthreads();
    fft_core(S, t);
    for (int k = t; k < 2049; k += 256) dst[k] = S[SKW(k)];
}

// inverse: y = Re(FFT(conj(S)))/4096 with S = Hermitian extension of uf*kf; fused D-skip + GELU -> g bf16
__global__ __launch_bounds__(256) void fft_inv_kernel(
    const float2* __restrict__ uf, const float2* __restrict__ kf,
    const float* __restrict__ u, const float* __restrict__ s4D, ushort_t* __restrict__ g)
{
    __shared__ float2 S[4352];
    int wg = blockIdx.x, t = threadIdx.x;
    int b = wg >> 11, ch = (wg >> 9) & 3, e = wg & 511;
    const float2* ur = uf + (size_t)(b * 512 + e) * FPAD;
    const float2* kr = kf + (size_t)(ch * 512 + e) * FPAD;
    for (int i = t; i < 4096; i += 256) {
        int k = (i <= 2048) ? i : (4096 - i);
        float2 a = ur[k], bb = kr[k];
        float2 p = make_float2(a.x * bb.x - a.y * bb.y, a.x * bb.y + a.y * bb.x);
        float2 v = (i <= 2048) ? make_float2(p.x, -p.y) : p;
        S[SKW(rev4_12(i))] = v;
    }
    __syncthreads();
    fft_core(S, t);
    float d = s4D[ch * 512 + e];
    const float* urow = u + (size_t)e * NBL + b * 2048;
    __hip_bfloat16* gout = (__hip_bfloat16*)g + ((size_t)(ch * 512 + e) * NBL + b * 2048);
    const float inv = 1.0f / 4096.0f;
    for (int l = t; l < 2048; l += 256) {
        float y = S[SKW(l)].x * inv;
        float z = y + d * urow[l];
        gout[l] = __float2bfloat16(gelu_f(z));
    }
}

// ============================ generic bf16 MFMA GEMM ============================
// C[M][N] = A[M][K] * B[K][N]; 128x128 tile, BK=32, 4 waves (2x2), 16x16x32 MFMA.
// BMODE 0: B is bf16 [K][N] row-major.  BMODE 1: im2col from padded h0p (K=768, k=c*3+dk).
// EPI: 0 gelu(acc+bias)->f32 | 1 acc+I->bf16 | 2 acc->bf16 | 3 acc+bias->bf16 | 4 final outputs
template<int BMODE, int EPI>
__global__ __launch_bounds__(256) void gemm_kernel(
    const ushort_t* __restrict__ A, const ushort_t* __restrict__ Bm,
    ushort_t* __restrict__ Cb, float* __restrict__ Cf,
    int M, int N, int K,
    const float* __restrict__ bias, const float* __restrict__ bias2,
    const float* __restrict__ xn, float* __restrict__ dout)
{
    __shared__ ushort_t Alds[128 * 40];   // [m][k] k-contig, stride 40
    __shared__ ushort_t Blds[128 * 40];   // [n][k] k-contig, stride 40
    const int t = threadIdx.x;
    const int n0 = blockIdx.x * 128, m0 = blockIdx.y * 128;
    const int w = t >> 6, lane = t & 63, quad = lane >> 4, lr = lane & 15;
    const int wm = (w >> 1) * 64, wn = (w & 1) * 64;

    float4_t acc[4][4];
    #pragma unroll
    for (int i = 0; i < 4; ++i)
        #pragma unroll
        for (int j = 0; j < 4; ++j) { float4_t z = {0.f, 0.f, 0.f, 0.f}; acc[i][j] = z; }

    for (int kt = 0; kt < K; kt += 32) {
        __syncthreads();
        {   // stage A tile 128x32 (vectorized)
            int i = t >> 1, j0 = (t & 1) * 16;
            const short8* src = (const short8*)(A + (size_t)(m0 + i) * K + kt + j0);
            short8 v0 = src[0], v1 = src[1];
            *(short8*)&Alds[i * 40 + j0] = v0;
            *(short8*)&Alds[i * 40 + j0 + 8] = v1;
        }
        {   // stage B tile 32x128, transposed into [n][k]
            int k = t >> 3, nb = t & 7;
            if (BMODE == 0) {
                const short8* src = (const short8*)(Bm + (size_t)(kt + k) * N + n0 + nb * 16);
                short8 v0 = src[0], v1 = src[1];
                #pragma unroll
                for (int jj = 0; jj < 8; ++jj) Blds[(nb * 16 + jj) * 40 + k] = (ushort_t)v0[jj];
                #pragma unroll
                for (int jj = 0; jj < 8; ++jj) Blds[(nb * 16 + 8 + jj) * 40 + k] = (ushort_t)v1[jj];
            } else {
                int r = kt + k; int c = r / 3; int dk = r - c * 3;
                int ncs = n0 + nb * 16; int bb = ncs >> 11; int ls = ncs & 2047;
                const ushort_t* src = Bm + (size_t)c * 16400 + bb * 2050 + ls + dk;
                #pragma unroll
                for (int jj = 0; jj < 16; ++jj) Blds[(nb * 16 + jj) * 40 + k] = src[jj];
            }
        }
        __syncthreads();
        short8 af[4], bfr[4];
        #pragma unroll
        for (int im = 0; im < 4; ++im)
            af[im] = *(const short8*)&Alds[(wm + im * 16 + lr) * 40 + quad * 8];
        #pragma unroll
        for (int in_ = 0; in_ < 4; ++in_)
            bfr[in_] = *(const short8*)&Blds[(wn + in_ * 16 + lr) * 40 + quad * 8];
        #pragma unroll
        for (int im = 0; im < 4; ++im)
            #pragma unroll
            for (int in_ = 0; in_ < 4; ++in_)
                acc[im][in_] = __builtin_amdgcn_mfma_f32_16x16x32_bf16(af[im], bfr[in_], acc[im][in_], 0, 0, 0);
    }

    // epilogue: D row = 4*quad + reg, col = lane&15
    #pragma unroll
    for (int im = 0; im < 4; ++im) {
        #pragma unroll
        for (int in_ = 0; in_ < 4; ++in_) {
            int n = n0 + wn + in_ * 16 + lr;
            int mb = m0 + wm + im * 16 + quad * 4;
            #pragma unroll
            for (int r = 0; r < 4; ++r) {
                int m = mb + r;
                float v = acc[im][in_][r];
                if (EPI == 0) {
                    v += bias[m];
                    Cf[(size_t)m * N + n] = gelu_f(v);
                } else if (EPI == 1) {
                    v += (m == n) ? 1.0f : 0.0f;
                    ((__hip_bfloat16*)Cb)[(size_t)m * N + n] = __float2bfloat16(v);
                } else if (EPI == 2) {
                    ((__hip_bfloat16*)Cb)[(size_t)m * N + n] = __float2bfloat16(v);
                } else if (EPI == 3) {
                    v += bias[m];
                    ((__hip_bfloat16*)Cb)[(size_t)m * N + n] = __float2bfloat16(v);
                } else {
                    int bb = n >> 11, ll = n & 2047;
                    if (m < 256) {
                        v += bias[m];   // res_b
                        int idx = (bb << 19) + (m << 11) + ll;
                        dout[idx] = (xn[idx] + v) * 0.70710678118654752f;
                    } else {
                        v += bias2[m - 256];   // skip_b
                        dout[4194304 + (bb << 19) + ((m - 256) << 11) + ll] = v;
                    }
                }
            }
        }
    }
}

// ============================ gate: out = tanh(h2[:256]) * sigmoid(h2[256:]) ============================
__global__ __launch_bounds__(256) void gate_kernel(
    const ushort_t* __restrict__ h2, ushort_t* __restrict__ gout)
{
    const __hip_bfloat16* h2b = (const __hip_bfloat16*)h2;
    __hip_bfloat16* gb = (__hip_bfloat16*)gout;
    for (int i = blockIdx.x * 256 + threadIdx.x; i < 256 * NBL; i += gridDim.x * 256) {
        float a = __bfloat162float(h2b[i]);
        float bgt = __bfloat162float(h2b[i + 256 * NBL]);
        gb[i] = __float2bfloat16(tanhf(a) * (1.0f / (1.0f + __expf(-bgt))));
    }
}

// ============================ launch ============================
extern "C" void kernel_launch(void* const* d_in, const int* in_sizes, int n_in,
                              void* d_out, int out_size, void* d_ws, size_t ws_size,
                              hipStream_t stream)
{
    const float* x         = (const float*)d_in[0];
    const float* original  = (const float*)d_in[1];
    const float* sn_scale  = (const float*)d_in[2];
    const float* conv_w    = (const float*)d_in[3];
    const float* conv_b    = (const float*)d_in[4];
    const float* s4_ln_g   = (const float*)d_in[5];
    const float* s4_ln_b   = (const float*)d_in[6];
    const float* s4_kernel = (const float*)d_in[7];
    const float* s4_D      = (const float*)d_in[8];
    const float* s4_out_w  = (const float*)d_in[9];
    const float* s4_out_b  = (const float*)d_in[10];
    const float* attn_v_w  = (const float*)d_in[11];
    const float* attn_v_b  = (const float*)d_in[12];
    const float* attn_o_w  = (const float*)d_in[13];
    const float* attn_o_b  = (const float*)d_in[14];
    const float* res_w     = (const float*)d_in[15];
    const float* res_b     = (const float*)d_in[16];
    const float* skip_w    = (const float*)d_in[17];
    const float* skip_b    = (const float*)d_in[18];

    char* ws = (char*)d_ws;
    __hip_bfloat16* convA = (__hip_bfloat16*)(ws + WS_CONVA);
    __hip_bfloat16* WvBf  = (__hip_bfloat16*)(ws + WS_WV);
    __hip_bfloat16* WoBf  = (__hip_bfloat16*)(ws + WS_WO);
    __hip_bfloat16* W1Bf  = (__hip_bfloat16*)(ws + WS_W1);
    __hip_bfloat16* Wcat  = (__hip_bfloat16*)(ws + WS_WCAT);
    ushort_t* A2    = (ushort_t*)(ws + WS_A2);
    ushort_t* Acomb = (ushort_t*)(ws + WS_ACOMB);
    float* b2p    = (float*)(ws + WS_B2);
    float* bcombp = (float*)(ws + WS_BCOMB);
    float* xnp    = (float*)(ws + WS_XN);
    ushort_t* h0p = (ushort_t*)(ws + WS_H0P);
    float* uP     = (float*)(ws + WS_U);
    float2* ufP   = (float2*)(ws + WS_UF);
    float2* kfP   = (float2*)(ws + WS_KF);
    ushort_t* gP  = (ushort_t*)(ws + WS_G);
    ushort_t* h2P = (ushort_t*)(ws + WS_H2);
    ushort_t* gateP = (ushort_t*)(ws + WS_GATE);

    // weight prep + attention-fold precompute
    wprep_kernel<<<dim3(4096), dim3(256), 0, stream>>>(conv_w, attn_v_w, attn_o_w, s4_out_w,
        res_w, skip_w, attn_v_b, attn_o_b, convA, WvBf, WoBf, W1Bf, Wcat, b2p);
    gemm_kernel<0, 1><<<dim3(4, 4), dim3(256), 0, stream>>>(
        (const ushort_t*)WoBf, (const ushort_t*)WvBf, A2, nullptr, 512, 512, 512,
        nullptr, nullptr, nullptr, nullptr);
    bcomb_kernel<<<dim3(2), dim3(256), 0, stream>>>((const __hip_bfloat16*)A2, s4_out_b, b2p, bcombp);
    gemm_kernel<0, 2><<<dim3(16, 4), dim3(256), 0, stream>>>(
        A2, (const ushort_t*)W1Bf, Acomb, nullptr, 512, 2048, 512,
        nullptr, nullptr, nullptr, nullptr);

    // main pipeline
    prep_kernel<<<dim3(256), dim3(256), 0, stream>>>(x, original, sn_scale, xnp, h0p);
    gemm_kernel<1, 0><<<dim3(128, 4), dim3(256), 0, stream>>>(
        (const ushort_t*)convA, h0p, nullptr, uP, 512, NBL, 768,
        conv_b, nullptr, nullptr, nullptr);
    ln_kernel<<<dim3(256), dim3(256), 0, stream>>>(uP, s4_ln_g, s4_ln_b);
    fft_fwd_kernel<<<dim3(6144), dim3(256), 0, stream>>>(uP, s4_kernel, ufP, kfP);
    fft_inv_kernel<<<dim3(16384), dim3(256), 0, stream>>>(ufP, kfP, uP, s4_D, gP);
    gemm_kernel<0, 3><<<dim3(128, 4), dim3(256), 0, stream>>>(
        (const ushort_t*)Acomb, gP, h2P, nullptr, 512, NBL, 2048,
        bcombp, nullptr, nullptr, nullptr);
    gate_kernel<<<dim3(4096), dim3(256), 0, stream>>>(h2P, gateP);
    gemm_kernel<0, 4><<<dim3(128, 4), dim3(256), 0, stream>>>(
        (const ushort_t*)Wcat, gateP, nullptr, nullptr, 512, NBL, 256,
        res_b, skip_b, xnp, (float*)d_out);
}

// Round 3
// 584.040 us; speedup vs baseline: 1.5081x; 1.5081x over previous
//
#include <hip/hip_runtime.h>
#include <hip/hip_bf16.h>
#include <math.h>

typedef __attribute__((ext_vector_type(8))) short short8;
typedef __attribute__((ext_vector_type(4))) float float4_t;
typedef unsigned short ushort_t;

// Problem constants: B=8, C=256, L=2048, E=512, CH=4
#define NBL 16384          // B*L

// ---------------- workspace layout (bytes). total ~199.8 MB ----------------
#define WS_CONVA   ((size_t)0)          // bf16 [512][768]
#define WS_WV      ((size_t)786432)     // bf16 [512][512]
#define WS_WO      ((size_t)1310720)    // bf16 [512][512]
#define WS_W1      ((size_t)1835008)    // bf16 [512][2048]
#define WS_WCAT    ((size_t)3932160)    // bf16 [512][256]  rows 0-255 res_w, 256-511 skip_w
#define WS_A2      ((size_t)4194304)    // bf16 [512][512]  I + Wo@Wv
#define WS_ACOMB   ((size_t)4718592)    // bf16 [512][2048] A2 @ s4_out_w
#define WS_BCOMB   ((size_t)6815744)    // f32 [512]
#define WS_XN      ((size_t)6819840)    // f32 [8][256][2048]
#define WS_H0P     ((size_t)23597056)   // bf16 [256][8][2050]  padded x+orig
#define WS_U       ((size_t)31993856)   // f32 [512][16384]   conv+gelu -> (in-place LN) u
#define WS_UF      ((size_t)65548288)   // bf162 [2048][4096] packed u-pair spectra (digit-rev order)
#define WS_KF      ((size_t)99102720)   // bf162 [2048][4096] kernel spectra (digit-rev order)
#define WS_G       ((size_t)132657152)  // bf16 [2048][16384] gelu(y + D*u)   end 199766016
#define WS_H2      WS_UF                // bf16 [512][16384]  (uf dead by then)
#define WS_GATE    WS_H0P               // bf16 [256][16384]  (h0p dead by then)

__device__ inline float gelu_f(float x) {
    return 0.5f * x * (1.0f + erff(x * 0.70710678118654752f));
}

__device__ inline unsigned int pack_bf2(float a, float b) {
    __hip_bfloat16 ha = __float2bfloat16(a), hb = __float2bfloat16(b);
    unsigned short ua = *(unsigned short*)&ha, ub = *(unsigned short*)&hb;
    return (unsigned int)ua | ((unsigned int)ub << 16);
}
__device__ inline float2 unpack_bf2(unsigned int v) {
    float2 r;
    r.x = __uint_as_float(v << 16);
    r.y = __uint_as_float(v & 0xffff0000u);
    return r;
}

// ============================ weight prep ============================
__global__ __launch_bounds__(256) void wprep_kernel(
    const float* __restrict__ conv_w, const float* __restrict__ attn_v_w,
    const float* __restrict__ attn_o_w, const float* __restrict__ s4_out_w,
    const float* __restrict__ res_w, const float* __restrict__ skip_w,
    __hip_bfloat16* __restrict__ convA, __hip_bfloat16* __restrict__ WvBf,
    __hip_bfloat16* __restrict__ WoBf, __hip_bfloat16* __restrict__ W1Bf,
    __hip_bfloat16* __restrict__ Wcat)
{
    const int N0 = 393216, N1 = 655360, N2c = 917504, N3 = 1966080, N4 = 2097152;
    for (int i = blockIdx.x * 256 + threadIdx.x; i < N4; i += gridDim.x * 256) {
        if (i < N0)       convA[i]     = __float2bfloat16(conv_w[i]);
        else if (i < N1)  WvBf[i - N0] = __float2bfloat16(attn_v_w[i - N0]);
        else if (i < N2c) WoBf[i - N1] = __float2bfloat16(attn_o_w[i - N1]);
        else if (i < N3)  W1Bf[i - N2c] = __float2bfloat16(s4_out_w[i - N2c]);
        else {
            int j = i - N3; int m = j >> 8, c = j & 255;
            float v = (m < 256) ? res_w[m * 256 + c] : skip_w[(m - 256) * 256 + c];
            Wcat[j] = __float2bfloat16(v);
        }
    }
}

// bcomb = A2 @ s4_out_b + Wo @ bv + bo  (one block per output row)
__global__ __launch_bounds__(256) void bias2_kernel(
    const __hip_bfloat16* __restrict__ A2, const float* __restrict__ s4_out_b,
    const float* __restrict__ attn_o_w, const float* __restrict__ attn_v_b,
    const float* __restrict__ attn_o_b, float* __restrict__ bcomb)
{
    __shared__ float red[256];
    int o = blockIdx.x, t = threadIdx.x;
    float s = 0.f;
    for (int e = t; e < 512; e += 256)
        s += __bfloat162float(A2[o * 512 + e]) * s4_out_b[e] + attn_o_w[o * 512 + e] * attn_v_b[e];
    red[t] = s; __syncthreads();
    for (int k = 128; k > 0; k >>= 1) { if (t < k) red[t] += red[t + k]; __syncthreads(); }
    if (t == 0) bcomb[o] = red[0] + attn_o_b[o];
}

// ============================ prep: RMSNorm(x) + padded bf16 (x+orig) ============================
__global__ __launch_bounds__(256) void prep_kernel(
    const float* __restrict__ x, const float* __restrict__ orig,
    const float* __restrict__ sn, float* __restrict__ xn, ushort_t* __restrict__ h0p)
{
    __shared__ float red[4][64];
    int blk = blockIdx.x, t = threadIdx.x;
    int lane = t & 63, cg = t >> 6;
    int b = blk >> 5, l = ((blk & 31) << 6) + lane;
    size_t basein = (size_t)b * 524288 + l;
    float ss = 0.f;
    for (int c = cg; c < 256; c += 4) { float v = x[basein + (size_t)c * 2048]; ss += v * v; }
    red[cg][lane] = ss;
    __syncthreads();
    float tot = red[0][lane] + red[1][lane] + red[2][lane] + red[3][lane];
    float inv = 1.0f / (sqrtf(tot) * 0.0625f + 1e-8f);
    __hip_bfloat16* hp = (__hip_bfloat16*)h0p;
    for (int c = cg; c < 256; c += 4) {
        size_t idx = basein + (size_t)c * 2048;
        float xv = x[idx];
        xn[idx] = sn[c] * xv * inv;
        hp[(size_t)c * 16400 + b * 2050 + 1 + l] = __float2bfloat16(xv + orig[idx]);
    }
    if ((blk & 31) == 0) {
        hp[(size_t)t * 16400 + b * 2050]        = __float2bfloat16(0.f);
        hp[(size_t)t * 16400 + b * 2050 + 2049] = __float2bfloat16(0.f);
    }
}

// ============================ LayerNorm over E (in-place) ============================
__global__ __launch_bounds__(256) void ln_kernel(
    float* __restrict__ h, const float* __restrict__ gam, const float* __restrict__ bet)
{
    __shared__ float r1[4][64], r2[4][64];
    int blk = blockIdx.x, t = threadIdx.x;
    int lane = t & 63, og = t >> 6;
    int n = (blk << 6) + lane;
    float s1 = 0.f, s2 = 0.f;
    for (int o = og; o < 512; o += 4) { float v = h[(size_t)o * NBL + n]; s1 += v; s2 += v * v; }
    r1[og][lane] = s1; r2[og][lane] = s2;
    __syncthreads();
    float mu = (r1[0][lane] + r1[1][lane] + r1[2][lane] + r1[3][lane]) * (1.f / 512.f);
    float m2 = (r2[0][lane] + r2[1][lane] + r2[2][lane] + r2[3][lane]) * (1.f / 512.f);
    float rstd = rsqrtf(m2 - mu * mu + 1e-5f);
    for (int o = og; o < 512; o += 4) {
        size_t idx = (size_t)o * NBL + n;
        h[idx] = (h[idx] - mu) * rstd * gam[o] + bet[o];
    }
}

// ============================ FFT: 4096-pt, radix-16, 3 stages, register DFT-16 ============================
// Padded 3-level layout: i = 256B + 16c + d -> slot = 273B + 17c + d.
// INJECTIVE (17c+d <= 270 < 273; prior skew i+(i>>4)-8(i>>8) collided, e.g. g(249)=g(256)).
// Bank-pair = 2*slot mod 32 = 2(B+c+d) mod 32 (546,34 ≡ 2 mod 32): for every stage's
// fixed-j wave access the two varying digits sweep each residue mod 16 exactly 4x
// -> 4 lanes/bank-pair = the b64 bandwidth floor, all stages + load/store.
// DIF (SGN=-1, twiddle after) leaves digit-reversed order; DIT (SGN=+1, twiddle
// before) consumes it. Pointwise spectra products are order-agnostic.

__device__ __forceinline__ void dft4(float& r0, float& i0, float& r1, float& i1,
                                     float& r2, float& i2, float& r3, float& i3, float sg) {
    float t0r = r0 + r2, t0i = i0 + i2, t1r = r0 - r2, t1i = i0 - i2;
    float t2r = r1 + r3, t2i = i1 + i3, t3r = r1 - r3, t3i = i1 - i3;
    r0 = t0r + t2r; i0 = t0i + t2i;
    r2 = t0r - t2r; i2 = t0i - t2i;
    r1 = t1r - sg * t3i; i1 = t1i + sg * t3r;
    r3 = t1r + sg * t3i; i3 = t1i - sg * t3r;
}

template<int SGN>   // -1 forward (e^{-i}), +1 inverse (e^{+i})
__device__ __forceinline__ void dft16(float* xr, float* xi) {
    const float sg = (float)SGN;
    const float C16[10] = {1.f, 0.92387953f, 0.70710678f, 0.38268343f, 0.f,
                           -0.38268343f, -0.70710678f, -0.92387953f, -1.f, -0.92387953f};
    const float S16[10] = {0.f, 0.38268343f, 0.70710678f, 0.92387953f, 1.f,
                           0.92387953f, 0.70710678f, 0.38268343f, 0.f, -0.38268343f};
    #pragma unroll
    for (int r = 0; r < 4; ++r)
        dft4(xr[r], xi[r], xr[4 + r], xi[4 + r], xr[8 + r], xi[8 + r], xr[12 + r], xi[12 + r], sg);
    #pragma unroll
    for (int s = 1; s < 4; ++s) {
        #pragma unroll
        for (int r = 1; r < 4; ++r) {
            int e = s * r;
            float c = C16[e], si = sg * S16[e];
            int idx = 4 * s + r;
            float nr = xr[idx] * c - xi[idx] * si;
            float ni = xr[idx] * si + xi[idx] * c;
            xr[idx] = nr; xi[idx] = ni;
        }
    }
    #pragma unroll
    for (int s = 0; s < 4; ++s)
        dft4(xr[4 * s], xi[4 * s], xr[4 * s + 1], xi[4 * s + 1],
             xr[4 * s + 2], xi[4 * s + 2], xr[4 * s + 3], xi[4 * s + 3], sg);
}
// output bin m lives at register slot perm(m) = ((m&3)<<2)|(m>>2)

template<int SGN, bool TWB>
__device__ __forceinline__ void fft_stage(float2* S, int base, int stride, int p, float invQ) {
    float xr[16], xi[16];
    #pragma unroll
    for (int j = 0; j < 16; ++j) { float2 v = S[base + j * stride]; xr[j] = v.x; xi[j] = v.y; }
    if (invQ != 0.f) {
        float ang = (float)SGN * 6.283185307179586f * (float)p * invQ;
        float s1, c1; __sincosf(ang, &s1, &c1);
        if (TWB) {            // DIT: v_j = u_j * w^j before the DFT
            float wr = c1, wi = s1;
            #pragma unroll
            for (int j = 1; j < 16; ++j) {
                float nr = xr[j] * wr - xi[j] * wi;
                float ni = xr[j] * wi + xi[j] * wr;
                xr[j] = nr; xi[j] = ni;
                float ar = wr * c1 - wi * s1, ai = wr * s1 + wi * c1;
                wr = ar; wi = ai;
            }
            dft16<SGN>(xr, xi);
        } else {              // DIF: out_m *= w^m after the DFT
            dft16<SGN>(xr, xi);
            float wr = c1, wi = s1;
            #pragma unroll
            for (int m = 1; m < 16; ++m) {
                int idx = ((m & 3) << 2) | (m >> 2);
                float nr = xr[idx] * wr - xi[idx] * wi;
                float ni = xr[idx] * wi + xi[idx] * wr;
                xr[idx] = nr; xi[idx] = ni;
                float ar = wr * c1 - wi * s1, ai = wr * s1 + wi * c1;
                wr = ar; wi = ai;
            }
        }
    } else {
        dft16<SGN>(xr, xi);
    }
    #pragma unroll
    for (int m = 0; m < 16; ++m) {
        int idx = ((m & 3) << 2) | (m >> 2);
        S[base + m * stride] = make_float2(xr[idx], xi[idx]);
    }
}

// forward: wg<2048 -> packed u-pair rows (bp,e): z = u[2bp,e] + i*u[2bp+1,e]
//          wg>=2048 -> kernel rows (ch,e): z = k + i*0.  Full 4096-bin bf162 spectra out.
__global__ __launch_bounds__(256) void fft_fwd_kernel(
    const float* __restrict__ u, const float* __restrict__ s4k,
    unsigned int* __restrict__ uf, unsigned int* __restrict__ kf)
{
    __shared__ float2 S[4368];
    int wg = blockIdx.x, t = threadIdx.x;
    int tb = t + (t >> 4);               // = 17*(t>>4) + (t&15)
    if (wg < 2048) {
        int bp = wg >> 9, e = wg & 511;
        const float* p0 = u + (size_t)e * NBL + (size_t)bp * 4096;
        #pragma unroll
        for (int it = 0; it < 16; ++it) {
            int i = it * 256 + t;
            float re = 0.f, im = 0.f;
            if (i < 2048) { re = p0[i]; im = p0[i + 2048]; }
            S[it * 273 + tb] = make_float2(re, im);
        }
    } else {
        const float* p0 = s4k + (size_t)(wg - 2048) * 2048;
        #pragma unroll
        for (int it = 0; it < 16; ++it) {
            int i = it * 256 + t;
            float re = (i < 2048) ? p0[i] : 0.f;
            S[it * 273 + tb] = make_float2(re, 0.f);
        }
    }
    __syncthreads();
    fft_stage<-1, false>(S, tb, 273, t, 1.f / 4096.f);
    __syncthreads();
    fft_stage<-1, false>(S, (t >> 4) * 273 + (t & 15), 17, t & 15, 1.f / 256.f);
    __syncthreads();
    fft_stage<-1, false>(S, (t >> 4) * 273 + (t & 15) * 17, 1, 0, 0.f);
    __syncthreads();
    unsigned int* dst = (wg < 2048) ? (uf + (size_t)wg * 4096) : (kf + (size_t)(wg - 2048) * 4096);
    #pragma unroll
    for (int it = 0; it < 16; ++it) {
        float2 v = S[it * 273 + tb];
        dst[it * 256 + t] = pack_bf2(v.x, v.y);
    }
}

// inverse: W = KF[ch,e] (.) UF[bp,e] pointwise (digit-rev order), DIT -> natural order.
// y(2bp) = Re/4096, y(2bp+1) = Im/4096; fused D-skip + GELU -> g bf16 rows.
__global__ __launch_bounds__(256) void fft_inv_kernel(
    const unsigned int* __restrict__ uf, const unsigned int* __restrict__ kf,
    const float* __restrict__ u, const float* __restrict__ s4D, ushort_t* __restrict__ g)
{
    __shared__ float2 S[4368];
    int wg = blockIdx.x, t = threadIdx.x;
    int bp = wg >> 11, ch = (wg >> 9) & 3, e = wg & 511;
    int tb = t + (t >> 4);
    const unsigned int* zr = uf + (size_t)(bp * 512 + e) * 4096;
    const unsigned int* kr = kf + (size_t)(ch * 512 + e) * 4096;
    #pragma unroll
    for (int it = 0; it < 16; ++it) {
        int i = it * 256 + t;
        float2 a = unpack_bf2(zr[i]), b = unpack_bf2(kr[i]);
        S[it * 273 + tb] = make_float2(a.x * b.x - a.y * b.y, a.x * b.y + a.y * b.x);
    }
    __syncthreads();
    fft_stage<1, true>(S, (t >> 4) * 273 + (t & 15) * 17, 1, 0, 0.f);
    __syncthreads();
    fft_stage<1, true>(S, (t >> 4) * 273 + (t & 15), 17, t & 15, 1.f / 256.f);
    __syncthreads();
    fft_stage<1, true>(S, tb, 273, t, 1.f / 4096.f);
    __syncthreads();
    float d = s4D[ch * 512 + e];
    const float* ub = u + (size_t)e * NBL + (size_t)bp * 4096;
    __hip_bfloat16* go = (__hip_bfloat16*)g + ((size_t)(ch * 512 + e) * NBL + (size_t)bp * 4096);
    const float inv = 1.0f / 4096.0f;
    #pragma unroll
    for (int it = 0; it < 8; ++it) {
        int l = it * 256 + t;
        float2 w = S[it * 273 + tb];
        float y1 = w.x * inv + d * ub[l];
        float y2 = w.y * inv + d * ub[l + 2048];
        go[l]        = __float2bfloat16(gelu_f(y1));
        go[l + 2048] = __float2bfloat16(gelu_f(y2));
    }
}

// ============================ generic bf16 MFMA GEMM ============================
// C[M][N] = A[M][K] * B[K][N]; 128x128 tile, BK=32, 4 waves (2x2), 16x16x32 MFMA.
// BMODE 0: B bf16 [K][N] row-major.  BMODE 1: im2col from padded h0p (K=768).
// EPI: 0 gelu(acc+bias)->f32 | 1 acc+I->bf16 | 2 acc->bf16 | 3 acc+bias->bf16 | 4 final outputs
template<int BMODE, int EPI>
__global__ __launch_bounds__(256) void gemm_kernel(
    const ushort_t* __restrict__ A, const ushort_t* __restrict__ Bm,
    ushort_t* __restrict__ Cb, float* __restrict__ Cf,
    int M, int N, int K,
    const float* __restrict__ bias, const float* __restrict__ bias2,
    const float* __restrict__ xn, float* __restrict__ dout)
{
    __shared__ ushort_t Alds[128 * 40];
    __shared__ ushort_t Blds[128 * 40];
    const int t = threadIdx.x;
    const int n0 = blockIdx.x * 128, m0 = blockIdx.y * 128;
    const int w = t >> 6, lane = t & 63, quad = lane >> 4, lr = lane & 15;
    const int wm = (w >> 1) * 64, wn = (w & 1) * 64;

    float4_t acc[4][4];
    #pragma unroll
    for (int i = 0; i < 4; ++i)
        #pragma unroll
        for (int j = 0; j < 4; ++j) { float4_t z = {0.f, 0.f, 0.f, 0.f}; acc[i][j] = z; }

    for (int kt = 0; kt < K; kt += 32) {
        __syncthreads();
        {
            int i = t >> 1, j0 = (t & 1) * 16;
            const short8* src = (const short8*)(A + (size_t)(m0 + i) * K + kt + j0);
            short8 v0 = src[0], v1 = src[1];
            *(short8*)&Alds[i * 40 + j0] = v0;
            *(short8*)&Alds[i * 40 + j0 + 8] = v1;
        }
        {
            int k = t >> 3, nb = t & 7;
            if (BMODE == 0) {
                const short8* src = (const short8*)(Bm + (size_t)(kt + k) * N + n0 + nb * 16);
                short8 v0 = src[0], v1 = src[1];
                #pragma unroll
                for (int jj = 0; jj < 8; ++jj) Blds[(nb * 16 + jj) * 40 + k] = (ushort_t)v0[jj];
                #pragma unroll
                for (int jj = 0; jj < 8; ++jj) Blds[(nb * 16 + 8 + jj) * 40 + k] = (ushort_t)v1[jj];
            } else {
                int r = kt + k; int c = r / 3; int dk = r - c * 3;
                int ncs = n0 + nb * 16; int bb = ncs >> 11; int ls = ncs & 2047;
                const ushort_t* src = Bm + (size_t)c * 16400 + bb * 2050 + ls + dk;
                #pragma unroll
                for (int jj = 0; jj < 16; ++jj) Blds[(nb * 16 + jj) * 40 + k] = src[jj];
            }
        }
        __syncthreads();
        short8 af[4], bfr[4];
        #pragma unroll
        for (int im = 0; im < 4; ++im)
            af[im] = *(const short8*)&Alds[(wm + im * 16 + lr) * 40 + quad * 8];
        #pragma unroll
        for (int in_ = 0; in_ < 4; ++in_)
            bfr[in_] = *(const short8*)&Blds[(wn + in_ * 16 + lr) * 40 + quad * 8];
        #pragma unroll
        for (int im = 0; im < 4; ++im)
            #pragma unroll
            for (int in_ = 0; in_ < 4; ++in_)
                acc[im][in_] = __builtin_amdgcn_mfma_f32_16x16x32_bf16(af[im], bfr[in_], acc[im][in_], 0, 0, 0);
    }

    #pragma unroll
    for (int im = 0; im < 4; ++im) {
        #pragma unroll
        for (int in_ = 0; in_ < 4; ++in_) {
            int n = n0 + wn + in_ * 16 + lr;
            int mb = m0 + wm + im * 16 + quad * 4;
            #pragma unroll
            for (int r = 0; r < 4; ++r) {
                int m = mb + r;
                float v = acc[im][in_][r];
                if (EPI == 0) {
                    v += bias[m];
                    Cf[(size_t)m * N + n] = gelu_f(v);
                } else if (EPI == 1) {
                    v += (m == n) ? 1.0f : 0.0f;
                    ((__hip_bfloat16*)Cb)[(size_t)m * N + n] = __float2bfloat16(v);
                } else if (EPI == 2) {
                    ((__hip_bfloat16*)Cb)[(size_t)m * N + n] = __float2bfloat16(v);
                } else if (EPI == 3) {
                    v += bias[m];
                    ((__hip_bfloat16*)Cb)[(size_t)m * N + n] = __float2bfloat16(v);
                } else {
                    int bb = n >> 11, ll = n & 2047;
                    if (m < 256) {
                        v += bias[m];
                        int idx = (bb << 19) + (m << 11) + ll;
                        dout[idx] = (xn[idx] + v) * 0.70710678118654752f;
                    } else {
                        v += bias2[m - 256];
                        dout[4194304 + (bb << 19) + ((m - 256) << 11) + ll] = v;
                    }
                }
            }
        }
    }
}

// ============================ gate ============================
__global__ __launch_bounds__(256) void gate_kernel(
    const ushort_t* __restrict__ h2, ushort_t* __restrict__ gout)
{
    const __hip_bfloat16* h2b = (const __hip_bfloat16*)h2;
    __hip_bfloat16* gb = (__hip_bfloat16*)gout;
    for (int i = blockIdx.x * 256 + threadIdx.x; i < 256 * NBL; i += gridDim.x * 256) {
        float a = __bfloat162float(h2b[i]);
        float bgt = __bfloat162float(h2b[i + 256 * NBL]);
        gb[i] = __float2bfloat16(tanhf(a) * (1.0f / (1.0f + __expf(-bgt))));
    }
}

// ============================ launch ============================
extern "C" void kernel_launch(void* const* d_in, const int* in_sizes, int n_in,
                              void* d_out, int out_size, void* d_ws, size_t ws_size,
                              hipStream_t stream)
{
    const float* x         = (const float*)d_in[0];
    const float* original  = (const float*)d_in[1];
    const float* sn_scale  = (const float*)d_in[2];
    const float* conv_w    = (const float*)d_in[3];
    const float* conv_b    = (const float*)d_in[4];
    const float* s4_ln_g   = (const float*)d_in[5];
    const float* s4_ln_b   = (const float*)d_in[6];
    const float* s4_kernel = (const float*)d_in[7];
    const float* s4_D      = (const float*)d_in[8];
    const float* s4_out_w  = (const float*)d_in[9];
    const float* s4_out_b  = (const float*)d_in[10];
    const float* attn_v_w  = (const float*)d_in[11];
    const float* attn_v_b  = (const float*)d_in[12];
    const float* attn_o_w  = (const float*)d_in[13];
    const float* attn_o_b  = (const float*)d_in[14];
    const float* res_w     = (const float*)d_in[15];
    const float* res_b     = (const float*)d_in[16];
    const float* skip_w    = (const float*)d_in[17];
    const float* skip_b    = (const float*)d_in[18];

    char* ws = (char*)d_ws;
    __hip_bfloat16* convA = (__hip_bfloat16*)(ws + WS_CONVA);
    __hip_bfloat16* WvBf  = (__hip_bfloat16*)(ws + WS_WV);
    __hip_bfloat16* WoBf  = (__hip_bfloat16*)(ws + WS_WO);
    __hip_bfloat16* W1Bf  = (__hip_bfloat16*)(ws + WS_W1);
    __hip_bfloat16* Wcat  = (__hip_bfloat16*)(ws + WS_WCAT);
    ushort_t* A2    = (ushort_t*)(ws + WS_A2);
    ushort_t* Acomb = (ushort_t*)(ws + WS_ACOMB);
    float* bcombp = (float*)(ws + WS_BCOMB);
    float* xnp    = (float*)(ws + WS_XN);
    ushort_t* h0p = (ushort_t*)(ws + WS_H0P);
    float* uP     = (float*)(ws + WS_U);
    unsigned int* ufP = (unsigned int*)(ws + WS_UF);
    unsigned int* kfP = (unsigned int*)(ws + WS_KF);
    ushort_t* gP  = (ushort_t*)(ws + WS_G);
    ushort_t* h2P = (ushort_t*)(ws + WS_H2);
    ushort_t* gateP = (ushort_t*)(ws + WS_GATE);

    // weight prep + attention-fold precompute
    wprep_kernel<<<dim3(4096), dim3(256), 0, stream>>>(conv_w, attn_v_w, attn_o_w, s4_out_w,
        res_w, skip_w, convA, WvBf, WoBf, W1Bf, Wcat);
    gemm_kernel<0, 1><<<dim3(4, 4), dim3(256), 0, stream>>>(
        (const ushort_t*)WoBf, (const ushort_t*)WvBf, A2, nullptr, 512, 512, 512,
        nullptr, nullptr, nullptr, nullptr);
    bias2_kernel<<<dim3(512), dim3(256), 0, stream>>>(
        (const __hip_bfloat16*)A2, s4_out_b, attn_o_w, attn_v_b, attn_o_b, bcombp);
    gemm_kernel<0, 2><<<dim3(16, 4), dim3(256), 0, stream>>>(
        A2, (const ushort_t*)W1Bf, Acomb, nullptr, 512, 2048, 512,
        nullptr, nullptr, nullptr, nullptr);

    // main pipeline
    prep_kernel<<<dim3(256), dim3(256), 0, stream>>>(x, original, sn_scale, xnp, h0p);
    gemm_kernel<1, 0><<<dim3(128, 4), dim3(256), 0, stream>>>(
        (const ushort_t*)convA, h0p, nullptr, uP, 512, NBL, 768,
        conv_b, nullptr, nullptr, nullptr);
    ln_kernel<<<dim3(256), dim3(256), 0, stream>>>(uP, s4_ln_g, s4_ln_b);
    fft_fwd_kernel<<<dim3(4096), dim3(256), 0, stream>>>(uP, s4_kernel, ufP, kfP);
    fft_inv_kernel<<<dim3(8192), dim3(256), 0, stream>>>(ufP, kfP, uP, s4_D, gP);
    gemm_kernel<0, 3><<<dim3(128, 4), dim3(256), 0, stream>>>(
        (const ushort_t*)Acomb, gP, h2P, nullptr, 512, NBL, 2048,
        bcombp, nullptr, nullptr, nullptr);
    gate_kernel<<<dim3(4096), dim3(256), 0, stream>>>(h2P, gateP);
    gemm_kernel<0, 4><<<dim3(128, 4), dim3(256), 0, stream>>>(
        (const ushort_t*)Wcat, gateP, nullptr, nullptr, 512, NBL, 256,
        res_b, skip_b, xnp, (float*)d_out);
}

// Round 4
// 583.642 us; speedup vs baseline: 1.5092x; 1.0007x over previous
//
#include <hip/hip_runtime.h>
#include <hip/hip_bf16.h>
#include <math.h>

typedef __attribute__((ext_vector_type(8))) short short8;
typedef __attribute__((ext_vector_type(4))) float float4_t;
typedef unsigned short ushort_t;

// Problem constants: B=8, C=256, L=2048, E=512, CH=4
#define NBL 16384          // B*L

// ---------------- workspace layout (bytes). total ~208.2 MB (<= 233.5 verified) ----------------
#define WS_CONVA   ((size_t)0)          // bf16 [512][768]  K reordered: k' = dk*256 + c
#define WS_WV      ((size_t)786432)     // bf16 [512][512]  Wv^T  (row i, k=e contig)
#define WS_WO      ((size_t)1310720)    // bf16 [512][512]  Wo natural
#define WS_W1      ((size_t)1835008)    // bf16 [2048][512] s4_out_w^T (row ck, k=e contig)
#define WS_WCAT    ((size_t)3932160)    // bf16 [512][256]  rows 0-255 res_w, 256-511 skip_w
#define WS_A2      ((size_t)4194304)    // bf16 [512][512]  I + Wo@Wv
#define WS_ACOMB   ((size_t)4718592)    // bf16 [512][2048] A2 @ s4_out_w
#define WS_BCOMB   ((size_t)6815744)    // f32 [512]
#define WS_XN      ((size_t)6819840)    // f32 [8][256][2048]
#define WS_H0P     ((size_t)23597056)   // bf16 [256][8][2050]  padded x+orig (c-major)
#define WS_U       ((size_t)31993856)   // f32 [512][16384]   conv+gelu -> (in-place LN) u
#define WS_UF      ((size_t)65548288)   // bf162 [2048][4096] packed u-pair spectra
#define WS_KF      ((size_t)99102720)   // bf162 [2048][4096] kernel spectra
#define WS_G       ((size_t)132657152)  // bf16 [2048][16384] gelu(y + D*u)   end 199766016
#define WS_H0PT    ((size_t)199766016)  // bf16 [16400][256]  h0p transposed  end 208162816
#define WS_GT      WS_UF                // bf16 [16384][2048] g^T (UF+KF dead after fft_inv)
#define WS_H2      WS_G                 // bf16 [512][16384]  (g natural dead after transpose)
#define WS_GATE    (WS_G + 16777216)    // bf16 [256][16384]
#define WS_GATET   (WS_G + 25165824)    // bf16 [16384][256]

__device__ inline float gelu_f(float x) {
    return 0.5f * x * (1.0f + erff(x * 0.70710678118654752f));
}

__device__ inline unsigned int pack_bf2(float a, float b) {
    __hip_bfloat16 ha = __float2bfloat16(a), hb = __float2bfloat16(b);
    unsigned short ua = *(unsigned short*)&ha, ub = *(unsigned short*)&hb;
    return (unsigned int)ua | ((unsigned int)ub << 16);
}
__device__ inline float2 unpack_bf2(unsigned int v) {
    float2 r;
    r.x = __uint_as_float(v << 16);
    r.y = __uint_as_float(v & 0xffff0000u);
    return r;
}

// ============================ weight prep ============================
// convA: K reordered (k' = dk*256 + c); WvT/W1T stored transposed (k-major for GEMM B).
__global__ __launch_bounds__(256) void wprep_kernel(
    const float* __restrict__ conv_w, const float* __restrict__ attn_v_w,
    const float* __restrict__ attn_o_w, const float* __restrict__ s4_out_w,
    const float* __restrict__ res_w, const float* __restrict__ skip_w,
    __hip_bfloat16* __restrict__ convA, __hip_bfloat16* __restrict__ WvT,
    __hip_bfloat16* __restrict__ WoBf, __hip_bfloat16* __restrict__ W1T,
    __hip_bfloat16* __restrict__ Wcat)
{
    const int N0 = 393216, N1 = 655360, N2c = 917504, N3 = 1966080, N4 = 2097152;
    for (int i = blockIdx.x * 256 + threadIdx.x; i < N4; i += gridDim.x * 256) {
        if (i < N0) {
            int m = i / 768, r = i - m * 768, dk = r >> 8, c = r & 255;
            convA[i] = __float2bfloat16(conv_w[m * 768 + c * 3 + dk]);
        } else if (i < N1) {
            int j = i - N0; int row = j >> 9, e = j & 511;      // WvT[i][e] = Wv[e][i]
            WvT[j] = __float2bfloat16(attn_v_w[e * 512 + row]);
        } else if (i < N2c) {
            WoBf[i - N1] = __float2bfloat16(attn_o_w[i - N1]);
        } else if (i < N3) {
            int j = i - N2c; int ck = j >> 9, e = j & 511;      // W1T[ck][e] = W1[e][ck]
            W1T[j] = __float2bfloat16(s4_out_w[e * 2048 + ck]);
        } else {
            int j = i - N3; int m = j >> 8, c = j & 255;
            float v = (m < 256) ? res_w[m * 256 + c] : skip_w[(m - 256) * 256 + c];
            Wcat[j] = __float2bfloat16(v);
        }
    }
}

// bcomb = A2 @ s4_out_b + Wo @ bv + bo  (one block per output row)
__global__ __launch_bounds__(256) void bias2_kernel(
    const __hip_bfloat16* __restrict__ A2, const float* __restrict__ s4_out_b,
    const float* __restrict__ attn_o_w, const float* __restrict__ attn_v_b,
    const float* __restrict__ attn_o_b, float* __restrict__ bcomb)
{
    __shared__ float red[256];
    int o = blockIdx.x, t = threadIdx.x;
    float s = 0.f;
    for (int e = t; e < 512; e += 256)
        s += __bfloat162float(A2[o * 512 + e]) * s4_out_b[e] + attn_o_w[o * 512 + e] * attn_v_b[e];
    red[t] = s; __syncthreads();
    for (int k = 128; k > 0; k >>= 1) { if (t < k) red[t] += red[t + k]; __syncthreads(); }
    if (t == 0) bcomb[o] = red[0] + attn_o_b[o];
}

// ============================ prep: RMSNorm(x) + padded bf16 (x+orig) ============================
__global__ __launch_bounds__(256) void prep_kernel(
    const float* __restrict__ x, const float* __restrict__ orig,
    const float* __restrict__ sn, float* __restrict__ xn, ushort_t* __restrict__ h0p)
{
    __shared__ float red[4][64];
    int blk = blockIdx.x, t = threadIdx.x;
    int lane = t & 63, cg = t >> 6;
    int b = blk >> 5, l = ((blk & 31) << 6) + lane;
    size_t basein = (size_t)b * 524288 + l;
    float ss = 0.f;
    for (int c = cg; c < 256; c += 4) { float v = x[basein + (size_t)c * 2048]; ss += v * v; }
    red[cg][lane] = ss;
    __syncthreads();
    float tot = red[0][lane] + red[1][lane] + red[2][lane] + red[3][lane];
    float inv = 1.0f / (sqrtf(tot) * 0.0625f + 1e-8f);
    __hip_bfloat16* hp = (__hip_bfloat16*)h0p;
    for (int c = cg; c < 256; c += 4) {
        size_t idx = basein + (size_t)c * 2048;
        float xv = x[idx];
        xn[idx] = sn[c] * xv * inv;
        hp[(size_t)c * 16400 + b * 2050 + 1 + l] = __float2bfloat16(xv + orig[idx]);
    }
    if ((blk & 31) == 0) {
        hp[(size_t)t * 16400 + b * 2050]        = __float2bfloat16(0.f);
        hp[(size_t)t * 16400 + b * 2050 + 2049] = __float2bfloat16(0.f);
    }
}

// ============================ generic bf16 transpose: out[C][R] = in[R][C] ============================
// 64x64 LDS tiles, pad 65: both phases coalesced, 2-lane/bank (free).
__global__ __launch_bounds__(256) void transpose_kernel(
    const ushort_t* __restrict__ in, ushort_t* __restrict__ out, int R, int C)
{
    __shared__ ushort_t S[64 * 65];
    int c0 = blockIdx.x * 64, r0 = blockIdx.y * 64;
    int t = threadIdx.x, lx = t & 63, ly0 = t >> 6;
    #pragma unroll
    for (int ly = ly0; ly < 64; ly += 4) {
        int r = r0 + ly, c = c0 + lx;
        S[ly * 65 + lx] = (r < R && c < C) ? in[(size_t)r * C + c] : (ushort_t)0;
    }
    __syncthreads();
    #pragma unroll
    for (int ly = ly0; ly < 64; ly += 4) {
        int oc = c0 + ly, orr = r0 + lx;
        if (oc < C && orr < R) out[(size_t)oc * R + orr] = S[lx * 65 + ly];
    }
}

// ============================ LayerNorm over E (in-place) ============================
__global__ __launch_bounds__(256) void ln_kernel(
    float* __restrict__ h, const float* __restrict__ gam, const float* __restrict__ bet)
{
    __shared__ float r1[4][64], r2[4][64];
    int blk = blockIdx.x, t = threadIdx.x;
    int lane = t & 63, og = t >> 6;
    int n = (blk << 6) + lane;
    float s1 = 0.f, s2 = 0.f;
    for (int o = og; o < 512; o += 4) { float v = h[(size_t)o * NBL + n]; s1 += v; s2 += v * v; }
    r1[og][lane] = s1; r2[og][lane] = s2;
    __syncthreads();
    float mu = (r1[0][lane] + r1[1][lane] + r1[2][lane] + r1[3][lane]) * (1.f / 512.f);
    float m2 = (r2[0][lane] + r2[1][lane] + r2[2][lane] + r2[3][lane]) * (1.f / 512.f);
    float rstd = rsqrtf(m2 - mu * mu + 1e-5f);
    for (int o = og; o < 512; o += 4) {
        size_t idx = (size_t)o * NBL + n;
        h[idx] = (h[idx] - mu) * rstd * gam[o] + bet[o];
    }
}

// ============================ FFT: 4096-pt, radix-16, 3 stages, register DFT-16 ============================
// Padded 3-level layout: i = 256B + 16c + d -> slot = 273B + 17c + d (injective; 4 lanes/bank-pair
// = b64 floor on all stages). DIF fwd leaves digit-reversed order; DIT inv consumes it.

__device__ __forceinline__ void dft4(float& r0, float& i0, float& r1, float& i1,
                                     float& r2, float& i2, float& r3, float& i3, float sg) {
    float t0r = r0 + r2, t0i = i0 + i2, t1r = r0 - r2, t1i = i0 - i2;
    float t2r = r1 + r3, t2i = i1 + i3, t3r = r1 - r3, t3i = i1 - i3;
    r0 = t0r + t2r; i0 = t0i + t2i;
    r2 = t0r - t2r; i2 = t0i - t2i;
    r1 = t1r - sg * t3i; i1 = t1i + sg * t3r;
    r3 = t1r + sg * t3i; i3 = t1i - sg * t3r;
}

template<int SGN>   // -1 forward (e^{-i}), +1 inverse (e^{+i})
__device__ __forceinline__ void dft16(float* xr, float* xi) {
    const float sg = (float)SGN;
    const float C16[10] = {1.f, 0.92387953f, 0.70710678f, 0.38268343f, 0.f,
                           -0.38268343f, -0.70710678f, -0.92387953f, -1.f, -0.92387953f};
    const float S16[10] = {0.f, 0.38268343f, 0.70710678f, 0.92387953f, 1.f,
                           0.92387953f, 0.70710678f, 0.38268343f, 0.f, -0.38268343f};
    #pragma unroll
    for (int r = 0; r < 4; ++r)
        dft4(xr[r], xi[r], xr[4 + r], xi[4 + r], xr[8 + r], xi[8 + r], xr[12 + r], xi[12 + r], sg);
    #pragma unroll
    for (int s = 1; s < 4; ++s) {
        #pragma unroll
        for (int r = 1; r < 4; ++r) {
            int e = s * r;
            float c = C16[e], si = sg * S16[e];
            int idx = 4 * s + r;
            float nr = xr[idx] * c - xi[idx] * si;
            float ni = xr[idx] * si + xi[idx] * c;
            xr[idx] = nr; xi[idx] = ni;
        }
    }
    #pragma unroll
    for (int s = 0; s < 4; ++s)
        dft4(xr[4 * s], xi[4 * s], xr[4 * s + 1], xi[4 * s + 1],
             xr[4 * s + 2], xi[4 * s + 2], xr[4 * s + 3], xi[4 * s + 3], sg);
}
// output bin m lives at register slot perm(m) = ((m&3)<<2)|(m>>2)

template<int SGN, bool TWB>
__device__ __forceinline__ void fft_stage(float2* S, int base, int stride, int p, float invQ) {
    float xr[16], xi[16];
    #pragma unroll
    for (int j = 0; j < 16; ++j) { float2 v = S[base + j * stride]; xr[j] = v.x; xi[j] = v.y; }
    if (invQ != 0.f) {
        float ang = (float)SGN * 6.283185307179586f * (float)p * invQ;
        float s1, c1; __sincosf(ang, &s1, &c1);
        if (TWB) {
            float wr = c1, wi = s1;
            #pragma unroll
            for (int j = 1; j < 16; ++j) {
                float nr = xr[j] * wr - xi[j] * wi;
                float ni = xr[j] * wi + xi[j] * wr;
                xr[j] = nr; xi[j] = ni;
                float ar = wr * c1 - wi * s1, ai = wr * s1 + wi * c1;
                wr = ar; wi = ai;
            }
            dft16<SGN>(xr, xi);
        } else {
            dft16<SGN>(xr, xi);
            float wr = c1, wi = s1;
            #pragma unroll
            for (int m = 1; m < 16; ++m) {
                int idx = ((m & 3) << 2) | (m >> 2);
                float nr = xr[idx] * wr - xi[idx] * wi;
                float ni = xr[idx] * wi + xi[idx] * wr;
                xr[idx] = nr; xi[idx] = ni;
                float ar = wr * c1 - wi * s1, ai = wr * s1 + wi * c1;
                wr = ar; wi = ai;
            }
        }
    } else {
        dft16<SGN>(xr, xi);
    }
    #pragma unroll
    for (int m = 0; m < 16; ++m) {
        int idx = ((m & 3) << 2) | (m >> 2);
        S[base + m * stride] = make_float2(xr[idx], xi[idx]);
    }
}

__global__ __launch_bounds__(256) void fft_fwd_kernel(
    const float* __restrict__ u, const float* __restrict__ s4k,
    unsigned int* __restrict__ uf, unsigned int* __restrict__ kf)
{
    __shared__ float2 S[4368];
    int wg = blockIdx.x, t = threadIdx.x;
    int tb = t + (t >> 4);
    if (wg < 2048) {
        int bp = wg >> 9, e = wg & 511;
        const float* p0 = u + (size_t)e * NBL + (size_t)bp * 4096;
        #pragma unroll
        for (int it = 0; it < 16; ++it) {
            int i = it * 256 + t;
            float re = 0.f, im = 0.f;
            if (i < 2048) { re = p0[i]; im = p0[i + 2048]; }
            S[it * 273 + tb] = make_float2(re, im);
        }
    } else {
        const float* p0 = s4k + (size_t)(wg - 2048) * 2048;
        #pragma unroll
        for (int it = 0; it < 16; ++it) {
            int i = it * 256 + t;
            float re = (i < 2048) ? p0[i] : 0.f;
            S[it * 273 + tb] = make_float2(re, 0.f);
        }
    }
    __syncthreads();
    fft_stage<-1, false>(S, tb, 273, t, 1.f / 4096.f);
    __syncthreads();
    fft_stage<-1, false>(S, (t >> 4) * 273 + (t & 15), 17, t & 15, 1.f / 256.f);
    __syncthreads();
    fft_stage<-1, false>(S, (t >> 4) * 273 + (t & 15) * 17, 1, 0, 0.f);
    __syncthreads();
    unsigned int* dst = (wg < 2048) ? (uf + (size_t)wg * 4096) : (kf + (size_t)(wg - 2048) * 4096);
    #pragma unroll
    for (int it = 0; it < 16; ++it) {
        float2 v = S[it * 273 + tb];
        dst[it * 256 + t] = pack_bf2(v.x, v.y);
    }
}

__global__ __launch_bounds__(256) void fft_inv_kernel(
    const unsigned int* __restrict__ uf, const unsigned int* __restrict__ kf,
    const float* __restrict__ u, const float* __restrict__ s4D, ushort_t* __restrict__ g)
{
    __shared__ float2 S[4368];
    int wg = blockIdx.x, t = threadIdx.x;
    int bp = wg >> 11, ch = (wg >> 9) & 3, e = wg & 511;
    int tb = t + (t >> 4);
    const unsigned int* zr = uf + (size_t)(bp * 512 + e) * 4096;
    const unsigned int* kr = kf + (size_t)(ch * 512 + e) * 4096;
    #pragma unroll
    for (int it = 0; it < 16; ++it) {
        int i = it * 256 + t;
        float2 a = unpack_bf2(zr[i]), b = unpack_bf2(kr[i]);
        S[it * 273 + tb] = make_float2(a.x * b.x - a.y * b.y, a.x * b.y + a.y * b.x);
    }
    __syncthreads();
    fft_stage<1, true>(S, (t >> 4) * 273 + (t & 15) * 17, 1, 0, 0.f);
    __syncthreads();
    fft_stage<1, true>(S, (t >> 4) * 273 + (t & 15), 17, t & 15, 1.f / 256.f);
    __syncthreads();
    fft_stage<1, true>(S, tb, 273, t, 1.f / 4096.f);
    __syncthreads();
    float d = s4D[ch * 512 + e];
    const float* ub = u + (size_t)e * NBL + (size_t)bp * 4096;
    __hip_bfloat16* go = (__hip_bfloat16*)g + ((size_t)(ch * 512 + e) * NBL + (size_t)bp * 4096);
    const float inv = 1.0f / 4096.0f;
    #pragma unroll
    for (int it = 0; it < 8; ++it) {
        int l = it * 256 + t;
        float2 w = S[it * 273 + tb];
        float y1 = w.x * inv + d * ub[l];
        float y2 = w.y * inv + d * ub[l + 2048];
        go[l]        = __float2bfloat16(gelu_f(y1));
        go[l + 2048] = __float2bfloat16(gelu_f(y2));
    }
}

// ============================ bf16 MFMA GEMM, both operands k-major ============================
// C[M][N] = A[M][K] * B[K][N]; A is [M][K] k-contig, B supplied TRANSPOSED [N][K] k-contig.
// 128x128 tile, BK=32, 4 waves (2x2), 16x16x32 MFMA. No transpose staging; both tiles
// staged with 2x b128 per thread into stride-40 LDS.
// BSRC 0: Bm = B^T [N][K].  BSRC 1: im2col rows from h0pT (K reordered k'=dk*256+c).
// EPI: 0 gelu(acc+bias)->f32 | 1 acc+I->bf16 | 2 acc->bf16 | 3 acc+bias->bf16 | 4 final outputs
template<int BSRC, int EPI>
__global__ __launch_bounds__(256) void gemm_kernel(
    const ushort_t* __restrict__ A, const ushort_t* __restrict__ Bm,
    ushort_t* __restrict__ Cb, float* __restrict__ Cf,
    int M, int N, int K,
    const float* __restrict__ bias, const float* __restrict__ bias2,
    const float* __restrict__ xn, float* __restrict__ dout)
{
    __shared__ ushort_t Alds[128 * 40];
    __shared__ ushort_t Blds[128 * 40];
    const int t = threadIdx.x;
    const int n0 = blockIdx.x * 128, m0 = blockIdx.y * 128;
    const int w = t >> 6, lane = t & 63, quad = lane >> 4, lr = lane & 15;
    const int wm = (w >> 1) * 64, wn = (w & 1) * 64;

    // per-thread staging coords: row i, 16-short chunk j0
    const int i_s = t >> 1, j0 = (t & 1) * 16;
    // BSRC1 precompute: n -> (b,l)
    int bI = 0, lI = 0;
    if (BSRC == 1) { int n = n0 + i_s; bI = n >> 11; lI = n & 2047; }

    float4_t acc[4][4];
    #pragma unroll
    for (int i = 0; i < 4; ++i)
        #pragma unroll
        for (int j = 0; j < 4; ++j) { float4_t z = {0.f, 0.f, 0.f, 0.f}; acc[i][j] = z; }

    for (int kt = 0; kt < K; kt += 32) {
        __syncthreads();
        {   // stage A tile 128x32
            const short8* src = (const short8*)(A + (size_t)(m0 + i_s) * K + kt + j0);
            short8 v0 = src[0], v1 = src[1];
            *(short8*)&Alds[i_s * 40 + j0] = v0;
            *(short8*)&Alds[i_s * 40 + j0 + 8] = v1;
        }
        {   // stage B^T tile 128x32 (k-contig source, no transpose)
            const ushort_t* srcp;
            if (BSRC == 0) {
                srcp = Bm + (size_t)(n0 + i_s) * K + kt + j0;
            } else {
                int dk = kt >> 8, cb = kt & 255;
                srcp = Bm + (size_t)(bI * 2050 + lI + dk) * 256 + cb + j0;
            }
            const short8* src = (const short8*)srcp;
            short8 v0 = src[0], v1 = src[1];
            *(short8*)&Blds[i_s * 40 + j0] = v0;
            *(short8*)&Blds[i_s * 40 + j0 + 8] = v1;
        }
        __syncthreads();
        short8 af[4], bfr[4];
        #pragma unroll
        for (int im = 0; im < 4; ++im)
            af[im] = *(const short8*)&Alds[(wm + im * 16 + lr) * 40 + quad * 8];
        #pragma unroll
        for (int in_ = 0; in_ < 4; ++in_)
            bfr[in_] = *(const short8*)&Blds[(wn + in_ * 16 + lr) * 40 + quad * 8];
        #pragma unroll
        for (int im = 0; im < 4; ++im)
            #pragma unroll
            for (int in_ = 0; in_ < 4; ++in_)
                acc[im][in_] = __builtin_amdgcn_mfma_f32_16x16x32_bf16(af[im], bfr[in_], acc[im][in_], 0, 0, 0);
    }

    #pragma unroll
    for (int im = 0; im < 4; ++im) {
        #pragma unroll
        for (int in_ = 0; in_ < 4; ++in_) {
            int n = n0 + wn + in_ * 16 + lr;
            int mb = m0 + wm + im * 16 + quad * 4;
            #pragma unroll
            for (int r = 0; r < 4; ++r) {
                int m = mb + r;
                float v = acc[im][in_][r];
                if (EPI == 0) {
                    v += bias[m];
                    Cf[(size_t)m * N + n] = gelu_f(v);
                } else if (EPI == 1) {
                    v += (m == n) ? 1.0f : 0.0f;
                    ((__hip_bfloat16*)Cb)[(size_t)m * N + n] = __float2bfloat16(v);
                } else if (EPI == 2) {
                    ((__hip_bfloat16*)Cb)[(size_t)m * N + n] = __float2bfloat16(v);
                } else if (EPI == 3) {
                    v += bias[m];
                    ((__hip_bfloat16*)Cb)[(size_t)m * N + n] = __float2bfloat16(v);
                } else {
                    int bb = n >> 11, ll = n & 2047;
                    if (m < 256) {
                        v += bias[m];
                        int idx = (bb << 19) + (m << 11) + ll;
                        dout[idx] = (xn[idx] + v) * 0.70710678118654752f;
                    } else {
                        v += bias2[m - 256];
                        dout[4194304 + (bb << 19) + ((m - 256) << 11) + ll] = v;
                    }
                }
            }
        }
    }
}

// ============================ gate ============================
__global__ __launch_bounds__(256) void gate_kernel(
    const ushort_t* __restrict__ h2, ushort_t* __restrict__ gout)
{
    const __hip_bfloat16* h2b = (const __hip_bfloat16*)h2;
    __hip_bfloat16* gb = (__hip_bfloat16*)gout;
    for (int i = blockIdx.x * 256 + threadIdx.x; i < 256 * NBL; i += gridDim.x * 256) {
        float a = __bfloat162float(h2b[i]);
        float bgt = __bfloat162float(h2b[i + 256 * NBL]);
        gb[i] = __float2bfloat16(tanhf(a) * (1.0f / (1.0f + __expf(-bgt))));
    }
}

// ============================ launch ============================
extern "C" void kernel_launch(void* const* d_in, const int* in_sizes, int n_in,
                              void* d_out, int out_size, void* d_ws, size_t ws_size,
                              hipStream_t stream)
{
    const float* x         = (const float*)d_in[0];
    const float* original  = (const float*)d_in[1];
    const float* sn_scale  = (const float*)d_in[2];
    const float* conv_w    = (const float*)d_in[3];
    const float* conv_b    = (const float*)d_in[4];
    const float* s4_ln_g   = (const float*)d_in[5];
    const float* s4_ln_b   = (const float*)d_in[6];
    const float* s4_kernel = (const float*)d_in[7];
    const float* s4_D      = (const float*)d_in[8];
    const float* s4_out_w  = (const float*)d_in[9];
    const float* s4_out_b  = (const float*)d_in[10];
    const float* attn_v_w  = (const float*)d_in[11];
    const float* attn_v_b  = (const float*)d_in[12];
    const float* attn_o_w  = (const float*)d_in[13];
    const float* attn_o_b  = (const float*)d_in[14];
    const float* res_w     = (const float*)d_in[15];
    const float* res_b     = (const float*)d_in[16];
    const float* skip_w    = (const float*)d_in[17];
    const float* skip_b    = (const float*)d_in[18];

    char* ws = (char*)d_ws;
    __hip_bfloat16* convA = (__hip_bfloat16*)(ws + WS_CONVA);
    __hip_bfloat16* WvT   = (__hip_bfloat16*)(ws + WS_WV);
    __hip_bfloat16* WoBf  = (__hip_bfloat16*)(ws + WS_WO);
    __hip_bfloat16* W1T   = (__hip_bfloat16*)(ws + WS_W1);
    __hip_bfloat16* Wcat  = (__hip_bfloat16*)(ws + WS_WCAT);
    ushort_t* A2    = (ushort_t*)(ws + WS_A2);
    ushort_t* Acomb = (ushort_t*)(ws + WS_ACOMB);
    float* bcombp = (float*)(ws + WS_BCOMB);
    float* xnp    = (float*)(ws + WS_XN);
    ushort_t* h0p = (ushort_t*)(ws + WS_H0P);
    ushort_t* h0pT = (ushort_t*)(ws + WS_H0PT);
    float* uP     = (float*)(ws + WS_U);
    unsigned int* ufP = (unsigned int*)(ws + WS_UF);
    unsigned int* kfP = (unsigned int*)(ws + WS_KF);
    ushort_t* gP   = (ushort_t*)(ws + WS_G);
    ushort_t* gT   = (ushort_t*)(ws + WS_GT);
    ushort_t* h2P  = (ushort_t*)(ws + WS_H2);
    ushort_t* gateP  = (ushort_t*)(ws + WS_GATE);
    ushort_t* gateT  = (ushort_t*)(ws + WS_GATET);

    // weight prep + attention-fold precompute
    wprep_kernel<<<dim3(4096), dim3(256), 0, stream>>>(conv_w, attn_v_w, attn_o_w, s4_out_w,
        res_w, skip_w, convA, WvT, WoBf, W1T, Wcat);
    gemm_kernel<0, 1><<<dim3(4, 4), dim3(256), 0, stream>>>(
        (const ushort_t*)WoBf, (const ushort_t*)WvT, A2, nullptr, 512, 512, 512,
        nullptr, nullptr, nullptr, nullptr);
    bias2_kernel<<<dim3(512), dim3(256), 0, stream>>>(
        (const __hip_bfloat16*)A2, s4_out_b, attn_o_w, attn_v_b, attn_o_b, bcombp);
    gemm_kernel<0, 2><<<dim3(16, 4), dim3(256), 0, stream>>>(
        A2, (const ushort_t*)W1T, Acomb, nullptr, 512, 2048, 512,
        nullptr, nullptr, nullptr, nullptr);

    // main pipeline
    prep_kernel<<<dim3(256), dim3(256), 0, stream>>>(x, original, sn_scale, xnp, h0p);
    transpose_kernel<<<dim3(257, 4), dim3(256), 0, stream>>>(h0p, h0pT, 256, 16400);
    gemm_kernel<1, 0><<<dim3(128, 4), dim3(256), 0, stream>>>(
        (const ushort_t*)convA, h0pT, nullptr, uP, 512, NBL, 768,
        conv_b, nullptr, nullptr, nullptr);
    ln_kernel<<<dim3(256), dim3(256), 0, stream>>>(uP, s4_ln_g, s4_ln_b);
    fft_fwd_kernel<<<dim3(4096), dim3(256), 0, stream>>>(uP, s4_kernel, ufP, kfP);
    fft_inv_kernel<<<dim3(8192), dim3(256), 0, stream>>>(ufP, kfP, uP, s4_D, gP);
    transpose_kernel<<<dim3(256, 32), dim3(256), 0, stream>>>(gP, gT, 2048, 16384);
    gemm_kernel<0, 3><<<dim3(128, 4), dim3(256), 0, stream>>>(
        (const ushort_t*)Acomb, gT, h2P, nullptr, 512, NBL, 2048,
        bcombp, nullptr, nullptr, nullptr);
    gate_kernel<<<dim3(4096), dim3(256), 0, stream>>>(h2P, gateP);
    transpose_kernel<<<dim3(256, 4), dim3(256), 0, stream>>>(gateP, gateT, 256, 16384);
    gemm_kernel<0, 4><<<dim3(128, 4), dim3(256), 0, stream>>>(
        (const ushort_t*)Wcat, gateT, nullptr, nullptr, 512, NBL, 256,
        res_b, skip_b, xnp, (float*)d_out);
}

// Round 5
// 552.919 us; speedup vs baseline: 1.5930x; 1.0556x over previous
//
#include <hip/hip_runtime.h>
#include <hip/hip_bf16.h>
#include <math.h>

typedef __attribute__((ext_vector_type(8))) short short8;
typedef __attribute__((ext_vector_type(4))) float float4_t;
typedef unsigned short ushort_t;
typedef unsigned int uint_t;

// Problem constants: B=8, C=256, L=2048, E=512, CH=4
#define NBL 16384          // B*L

// ---------------- workspace layout (bytes). total 224,940,032 (<= 233.5 MB verified) ----------------
#define WS_CONVA   ((size_t)0)          // bf16 [512][768]  K reordered: k' = dk*256 + c
#define WS_WV      ((size_t)786432)     // bf16 [512][512]  Wv^T
#define WS_WO      ((size_t)1310720)    // bf16 [512][512]  Wo natural
#define WS_W1      ((size_t)1835008)    // bf16 [2048][512] s4_out_w^T
#define WS_WCAT    ((size_t)3932160)    // bf16 [512][256]
#define WS_A2      ((size_t)4194304)    // bf16 [512][512]  I + Wo@Wv
#define WS_ACOMB   ((size_t)4718592)    // bf16 [512][2048] A2 @ s4_out_w
#define WS_BCOMB   ((size_t)6815744)    // f32 [512]
#define WS_XN      ((size_t)6819840)    // f32 [8][256][2048]
#define WS_H0P     ((size_t)23597056)   // bf16 [256][8][2050]  padded x+orig
#define WS_U       ((size_t)31993856)   // f32 [512][16384]   conv+gelu output h
#define WS_UF      ((size_t)65548288)   // bf162 [2048][4096] packed u-pair spectra
#define WS_KF      ((size_t)99102720)   // bf162 [2048][4096] kernel spectra (pre-scaled 1/4096)
#define WS_G       ((size_t)132657152)  // bf16 [2048][16384] gelu(y + D*u)   end 199766016
#define WS_H0PT    ((size_t)199766016)  // bf16 [16400][256]  h0p transposed
#define WS_UB      ((size_t)208162816)  // bf16 [512][16384]  LN output u (bf16) end 224940032
#define WS_GT      WS_UF                // bf16 [16384][2048] g^T (UF+KF dead by then)
#define WS_H2      WS_G                 // bf16 [512][16384]  (g dead after transpose)
#define WS_GATET   (WS_G + 25165824)    // bf16 [16384][256]

// ---------------- fast transcendental helpers ----------------
__device__ __forceinline__ float gelu_f(float x) {
    // tanh-form gelu == x * sigmoid(1.595769*(x + 0.044715 x^3)); max abs err ~3e-4
    float t = x * x;
    float a2 = x * fmaf(0.07135481627f, t, 1.59576912161f);
    return x / (1.f + __expf(-a2));
}
__device__ __forceinline__ float tanh_f(float a) {
    return 1.f - 2.f / (1.f + __expf(2.f * a));
}
__device__ __forceinline__ float sigmoid_f(float b) {
    return 1.f / (1.f + __expf(-b));
}

__device__ __forceinline__ unsigned int pack_bf2(float a, float b) {
    __hip_bfloat16 ha = __float2bfloat16(a), hb = __float2bfloat16(b);
    unsigned short ua = *(unsigned short*)&ha, ub = *(unsigned short*)&hb;
    return (unsigned int)ua | ((unsigned int)ub << 16);
}
__device__ __forceinline__ float2 unpack_bf2(unsigned int v) {
    float2 r;
    r.x = __uint_as_float(v << 16);
    r.y = __uint_as_float(v & 0xffff0000u);
    return r;
}
__device__ __forceinline__ float bf2f(ushort_t u) {
    return __uint_as_float(((unsigned int)u) << 16);
}

// ============================ weight prep ============================
__global__ __launch_bounds__(256) void wprep_kernel(
    const float* __restrict__ conv_w, const float* __restrict__ attn_v_w,
    const float* __restrict__ attn_o_w, const float* __restrict__ s4_out_w,
    const float* __restrict__ res_w, const float* __restrict__ skip_w,
    __hip_bfloat16* __restrict__ convA, __hip_bfloat16* __restrict__ WvT,
    __hip_bfloat16* __restrict__ WoBf, __hip_bfloat16* __restrict__ W1T,
    __hip_bfloat16* __restrict__ Wcat)
{
    const int N0 = 393216, N1 = 655360, N2c = 917504, N3 = 1966080, N4 = 2097152;
    for (int i = blockIdx.x * 256 + threadIdx.x; i < N4; i += gridDim.x * 256) {
        if (i < N0) {
            int m = i / 768, r = i - m * 768, dk = r >> 8, c = r & 255;
            convA[i] = __float2bfloat16(conv_w[m * 768 + c * 3 + dk]);
        } else if (i < N1) {
            int j = i - N0; int row = j >> 9, e = j & 511;
            WvT[j] = __float2bfloat16(attn_v_w[e * 512 + row]);
        } else if (i < N2c) {
            WoBf[i - N1] = __float2bfloat16(attn_o_w[i - N1]);
        } else if (i < N3) {
            int j = i - N2c; int ck = j >> 9, e = j & 511;
            W1T[j] = __float2bfloat16(s4_out_w[e * 2048 + ck]);
        } else {
            int j = i - N3; int m = j >> 8, c = j & 255;
            float v = (m < 256) ? res_w[m * 256 + c] : skip_w[(m - 256) * 256 + c];
            Wcat[j] = __float2bfloat16(v);
        }
    }
}

__global__ __launch_bounds__(256) void bias2_kernel(
    const __hip_bfloat16* __restrict__ A2, const float* __restrict__ s4_out_b,
    const float* __restrict__ attn_o_w, const float* __restrict__ attn_v_b,
    const float* __restrict__ attn_o_b, float* __restrict__ bcomb)
{
    __shared__ float red[256];
    int o = blockIdx.x, t = threadIdx.x;
    float s = 0.f;
    for (int e = t; e < 512; e += 256)
        s += __bfloat162float(A2[o * 512 + e]) * s4_out_b[e] + attn_o_w[o * 512 + e] * attn_v_b[e];
    red[t] = s; __syncthreads();
    for (int k = 128; k > 0; k >>= 1) { if (t < k) red[t] += red[t + k]; __syncthreads(); }
    if (t == 0) bcomb[o] = red[0] + attn_o_b[o];
}

// ============================ prep: RMSNorm(x) + padded bf16 (x+orig) ============================
__global__ __launch_bounds__(256) void prep_kernel(
    const float* __restrict__ x, const float* __restrict__ orig,
    const float* __restrict__ sn, float* __restrict__ xn, ushort_t* __restrict__ h0p)
{
    __shared__ float red[4][64];
    int blk = blockIdx.x, t = threadIdx.x;
    int lane = t & 63, cg = t >> 6;
    int b = blk >> 5, l = ((blk & 31) << 6) + lane;
    size_t basein = (size_t)b * 524288 + l;
    float ss = 0.f;
    for (int c = cg; c < 256; c += 4) { float v = x[basein + (size_t)c * 2048]; ss += v * v; }
    red[cg][lane] = ss;
    __syncthreads();
    float tot = red[0][lane] + red[1][lane] + red[2][lane] + red[3][lane];
    float inv = 1.0f / (sqrtf(tot) * 0.0625f + 1e-8f);
    __hip_bfloat16* hp = (__hip_bfloat16*)h0p;
    for (int c = cg; c < 256; c += 4) {
        size_t idx = basein + (size_t)c * 2048;
        float xv = x[idx];
        xn[idx] = sn[c] * xv * inv;
        hp[(size_t)c * 16400 + b * 2050 + 1 + l] = __float2bfloat16(xv + orig[idx]);
    }
    if ((blk & 31) == 0) {
        hp[(size_t)t * 16400 + b * 2050]        = __float2bfloat16(0.f);
        hp[(size_t)t * 16400 + b * 2050 + 2049] = __float2bfloat16(0.f);
    }
}

// ============================ generic bf16 transpose ============================
__global__ __launch_bounds__(256) void transpose_kernel(
    const ushort_t* __restrict__ in, ushort_t* __restrict__ out, int R, int C)
{
    __shared__ ushort_t S[64 * 65];
    int c0 = blockIdx.x * 64, r0 = blockIdx.y * 64;
    int t = threadIdx.x, lx = t & 63, ly0 = t >> 6;
    #pragma unroll
    for (int ly = ly0; ly < 64; ly += 4) {
        int r = r0 + ly, c = c0 + lx;
        S[ly * 65 + lx] = (r < R && c < C) ? in[(size_t)r * C + c] : (ushort_t)0;
    }
    __syncthreads();
    #pragma unroll
    for (int ly = ly0; ly < 64; ly += 4) {
        int oc = c0 + ly, orr = r0 + lx;
        if (oc < C && orr < R) out[(size_t)oc * R + orr] = S[lx * 65 + ly];
    }
}

// ============================ LayerNorm over E -> bf16 u ============================
__global__ __launch_bounds__(256) void ln_kernel(
    const float* __restrict__ h, ushort_t* __restrict__ ub,
    const float* __restrict__ gam, const float* __restrict__ bet)
{
    __shared__ float r1[4][64], r2[4][64];
    int blk = blockIdx.x, t = threadIdx.x;
    int lane = t & 63, og = t >> 6;
    int n = (blk << 6) + lane;
    float s1 = 0.f, s2 = 0.f;
    for (int o = og; o < 512; o += 4) { float v = h[(size_t)o * NBL + n]; s1 += v; s2 += v * v; }
    r1[og][lane] = s1; r2[og][lane] = s2;
    __syncthreads();
    float mu = (r1[0][lane] + r1[1][lane] + r1[2][lane] + r1[3][lane]) * (1.f / 512.f);
    float m2 = (r2[0][lane] + r2[1][lane] + r2[2][lane] + r2[3][lane]) * (1.f / 512.f);
    float rstd = rsqrtf(m2 - mu * mu + 1e-5f);
    __hip_bfloat16* ubb = (__hip_bfloat16*)ub;
    for (int o = og; o < 512; o += 4) {
        size_t idx = (size_t)o * NBL + n;
        ubb[idx] = __float2bfloat16((h[idx] - mu) * rstd * gam[o] + bet[o]);
    }
}

// ============================ FFT: 4096-pt radix-16, LDS slot(i)=273B+17c+d ============================
// (injective, 4 lanes/bank-pair on every phase — verified round 3). Stage 1 fused with
// load (stride-1 inputs = 16 consecutive elements/thread), stage 3 fused with store/epilogue.
#define PERM(m) ((((m) & 3) << 2) | ((m) >> 2))

__device__ __forceinline__ float2 cmulv(float2 a, float2 b) {
    return make_float2(fmaf(-a.y, b.y, a.x * b.x), fmaf(a.y, b.x, a.x * b.y));
}

template<int SGN>
__device__ __forceinline__ void dft4v(float2& a0, float2& a1, float2& a2, float2& a3) {
    const float sg = (float)SGN;
    float2 t0 = make_float2(a0.x + a2.x, a0.y + a2.y);
    float2 t1 = make_float2(a0.x - a2.x, a0.y - a2.y);
    float2 t2 = make_float2(a1.x + a3.x, a1.y + a3.y);
    float2 t3 = make_float2(a1.x - a3.x, a1.y - a3.y);
    a0 = make_float2(t0.x + t2.x, t0.y + t2.y);
    a2 = make_float2(t0.x - t2.x, t0.y - t2.y);
    a1 = make_float2(t1.x - sg * t3.y, t1.y + sg * t3.x);
    a3 = make_float2(t1.x + sg * t3.y, t1.y - sg * t3.x);
}
template<int SGN>   // inputs a2,a3 implicitly zero (write-only)
__device__ __forceinline__ void dft4v_half(float2& a0, float2& a1, float2& a2, float2& a3) {
    const float sg = (float)SGN;
    float2 u0 = a0, u1 = a1;
    a0 = make_float2(u0.x + u1.x, u0.y + u1.y);
    a2 = make_float2(u0.x - u1.x, u0.y - u1.y);
    a1 = make_float2(u0.x - sg * u1.y, u0.y + sg * u1.x);
    a3 = make_float2(u0.x + sg * u1.y, u0.y - sg * u1.x);
}
template<int SGN>   // only outputs 0,1 (bins m=s, m=4+s)
__device__ __forceinline__ void dft4v_out01(float2 a0, float2 a1, float2 a2, float2 a3,
                                            float2& o0, float2& o1) {
    const float sg = (float)SGN;
    float2 t0 = make_float2(a0.x + a2.x, a0.y + a2.y);
    float2 t1 = make_float2(a0.x - a2.x, a0.y - a2.y);
    float2 t2 = make_float2(a1.x + a3.x, a1.y + a3.y);
    float2 t3 = make_float2(a1.x - a3.x, a1.y - a3.y);
    o0 = make_float2(t0.x + t2.x, t0.y + t2.y);
    o1 = make_float2(t1.x - sg * t3.y, t1.y + sg * t3.x);
}

template<int SGN>
__device__ __forceinline__ void dft16_stepB(float2* x) {
    const float sg = (float)SGN;
    const float C16[10] = {1.f, 0.92387953f, 0.70710678f, 0.38268343f, 0.f,
                           -0.38268343f, -0.70710678f, -0.92387953f, -1.f, -0.92387953f};
    const float S16[10] = {0.f, 0.38268343f, 0.70710678f, 0.92387953f, 1.f,
                           0.92387953f, 0.70710678f, 0.38268343f, 0.f, -0.38268343f};
    #pragma unroll
    for (int s = 1; s < 4; ++s)
        #pragma unroll
        for (int r = 1; r < 4; ++r) {
            int e = s * r;
            x[4 * s + r] = cmulv(x[4 * s + r], make_float2(C16[e], sg * S16[e]));
        }
}
template<int SGN>
__device__ __forceinline__ void dft16v(float2* x) {
    #pragma unroll
    for (int r = 0; r < 4; ++r) dft4v<SGN>(x[r], x[4 + r], x[8 + r], x[12 + r]);
    dft16_stepB<SGN>(x);
    #pragma unroll
    for (int s = 0; s < 4; ++s) dft4v<SGN>(x[4 * s], x[4 * s + 1], x[4 * s + 2], x[4 * s + 3]);
}
template<int SGN>
__device__ __forceinline__ void dft16_halfin(float2* x) {
    #pragma unroll
    for (int r = 0; r < 4; ++r) dft4v_half<SGN>(x[r], x[4 + r], x[8 + r], x[12 + r]);
    dft16_stepB<SGN>(x);
    #pragma unroll
    for (int s = 0; s < 4; ++s) dft4v<SGN>(x[4 * s], x[4 * s + 1], x[4 * s + 2], x[4 * s + 3]);
}
template<int SGN>   // y[m] = bin m, m=0..7
__device__ __forceinline__ void dft16_halfout(float2* x, float2* y) {
    #pragma unroll
    for (int r = 0; r < 4; ++r) dft4v<SGN>(x[r], x[4 + r], x[8 + r], x[12 + r]);
    dft16_stepB<SGN>(x);
    #pragma unroll
    for (int s = 0; s < 4; ++s)
        dft4v_out01<SGN>(x[4 * s], x[4 * s + 1], x[4 * s + 2], x[4 * s + 3], y[s], y[4 + s]);
}

// twiddle chain: DIF applies after (bins, perm order), DIT applies before (inputs, linear)
template<int SGN>
__device__ __forceinline__ void tw_after(float2* x, float p, float invQ) {
    float s1, c1; __sincosf((float)SGN * 6.283185307179586f * p * invQ, &s1, &c1);
    float2 w1 = make_float2(c1, s1), w = w1;
    #pragma unroll
    for (int m = 1; m < 16; ++m) { x[PERM(m)] = cmulv(x[PERM(m)], w); w = cmulv(w, w1); }
}
template<int SGN>
__device__ __forceinline__ void tw_before(float2* x, float p, float invQ) {
    float s1, c1; __sincosf((float)SGN * 6.283185307179586f * p * invQ, &s1, &c1);
    float2 w1 = make_float2(c1, s1), w = w1;
    #pragma unroll
    for (int j = 1; j < 16; ++j) { x[j] = cmulv(x[j], w); w = cmulv(w, w1); }
}

// forward: wg<2048 -> packed u-pair rows (bf16 u); wg>=2048 -> kernel rows (f32, pre-scale 1/4096)
__global__ __launch_bounds__(256) void fft_fwd_kernel(
    const ushort_t* __restrict__ ubf, const float* __restrict__ s4k,
    uint4* __restrict__ uf, uint4* __restrict__ kf)
{
    __shared__ float2 S[4368];
    int wg = blockIdx.x, t = threadIdx.x;
    float2 x[16];
    if (wg < 2048) {
        int bp = wg >> 9, e = wg & 511;
        const ushort_t* p0 = ubf + (size_t)e * NBL + (size_t)bp * 4096;
        #pragma unroll
        for (int j = 0; j < 8; ++j) {
            int i = j * 256 + t;
            x[j] = make_float2(bf2f(p0[i]), bf2f(p0[i + 2048]));
        }
    } else {
        const float* p0 = s4k + (size_t)(wg - 2048) * 2048;
        #pragma unroll
        for (int j = 0; j < 8; ++j) x[j] = make_float2(p0[j * 256 + t], 0.f);
    }
    // stage 1: digit B, half-in, twiddle-after W4096^{-t m}
    dft16_halfin<-1>(x);
    tw_after<-1>(x, (float)t, 1.f / 4096.f);
    int tb = 17 * (t >> 4) + (t & 15);
    #pragma unroll
    for (int m = 0; m < 16; ++m) S[tb + 273 * m] = x[PERM(m)];
    __syncthreads();
    // stage 2: digit c, twiddle-after W256^{-(t&15) m}
    int b2 = 273 * (t >> 4) + (t & 15);
    #pragma unroll
    for (int j = 0; j < 16; ++j) x[j] = S[b2 + 17 * j];
    dft16v<-1>(x);
    tw_after<-1>(x, (float)(t & 15), 1.f / 256.f);
    #pragma unroll
    for (int m = 0; m < 16; ++m) S[b2 + 17 * m] = x[PERM(m)];
    __syncthreads();
    // stage 3: digit d, no twiddle, direct pack+store (thread owns spectra i = 16t..16t+15)
    int b3 = 273 * (t >> 4) + 17 * (t & 15);
    #pragma unroll
    for (int j = 0; j < 16; ++j) x[j] = S[b3 + j];
    dft16v<-1>(x);
    const float sc = (wg < 2048) ? 1.f : (1.f / 4096.f);
    uint4* dst = ((wg < 2048) ? (uf + (size_t)wg * 1024) : (kf + (size_t)(wg - 2048) * 1024)) + 4 * t;
    #pragma unroll
    for (int q = 0; q < 4; ++q) {
        uint4 o;
        float2 v0 = x[PERM(4 * q)], v1 = x[PERM(4 * q + 1)];
        float2 v2 = x[PERM(4 * q + 2)], v3 = x[PERM(4 * q + 3)];
        o.x = pack_bf2(v0.x * sc, v0.y * sc);
        o.y = pack_bf2(v1.x * sc, v1.y * sc);
        o.z = pack_bf2(v2.x * sc, v2.y * sc);
        o.w = pack_bf2(v3.x * sc, v3.y * sc);
        dst[q] = o;
    }
}

// inverse: product in registers (stage-1 inputs are each thread's 16 consecutive elements),
// DIT stages, half-out final stage fused with D-skip + gelu epilogue.
__global__ __launch_bounds__(256) void fft_inv_kernel(
    const uint4* __restrict__ uf, const uint4* __restrict__ kf,
    const ushort_t* __restrict__ ubf, const float* __restrict__ s4D,
    ushort_t* __restrict__ g)
{
    __shared__ float2 S[4368];
    int wg = blockIdx.x, t = threadIdx.x;
    int bp = wg >> 11, ch = (wg >> 9) & 3, e = wg & 511;
    const uint4* zr = uf + (size_t)(bp * 512 + e) * 1024 + 4 * t;
    const uint4* kr = kf + (size_t)(ch * 512 + e) * 1024 + 4 * t;
    float2 x[16];
    #pragma unroll
    for (int q = 0; q < 4; ++q) {
        uint4 a4 = zr[q], b4 = kr[q];
        x[4 * q + 0] = cmulv(unpack_bf2(a4.x), unpack_bf2(b4.x));
        x[4 * q + 1] = cmulv(unpack_bf2(a4.y), unpack_bf2(b4.y));
        x[4 * q + 2] = cmulv(unpack_bf2(a4.z), unpack_bf2(b4.z));
        x[4 * q + 3] = cmulv(unpack_bf2(a4.w), unpack_bf2(b4.w));
    }
    // stage 1: digit d (stride 1), no twiddle
    dft16v<1>(x);
    int b1 = 273 * (t >> 4) + 17 * (t & 15);
    #pragma unroll
    for (int m = 0; m < 16; ++m) S[b1 + m] = x[PERM(m)];
    __syncthreads();
    // stage 2: digit c, twiddle-before W256^{+(t&15) j}
    int b2 = 273 * (t >> 4) + (t & 15);
    #pragma unroll
    for (int j = 0; j < 16; ++j) x[j] = S[b2 + 17 * j];
    tw_before<1>(x, (float)(t & 15), 1.f / 256.f);
    dft16v<1>(x);
    #pragma unroll
    for (int m = 0; m < 16; ++m) S[b2 + 17 * m] = x[PERM(m)];
    __syncthreads();
    // stage 3: digit B, twiddle-before W4096^{+t j}, half-out, fused epilogue (l = 256m + t)
    int b3 = 17 * (t >> 4) + (t & 15);
    #pragma unroll
    for (int j = 0; j < 16; ++j) x[j] = S[b3 + 273 * j];
    tw_before<1>(x, (float)t, 1.f / 4096.f);
    float2 y[8];
    dft16_halfout<1>(x, y);
    float dD = s4D[ch * 512 + e];
    const ushort_t* ub = ubf + (size_t)e * NBL + (size_t)bp * 4096;
    __hip_bfloat16* go = (__hip_bfloat16*)g + ((size_t)(ch * 512 + e) * NBL + (size_t)bp * 4096);
    #pragma unroll
    for (int m = 0; m < 8; ++m) {
        int l = m * 256 + t;
        go[l]        = __float2bfloat16(gelu_f(fmaf(dD, bf2f(ub[l]), y[m].x)));
        go[l + 2048] = __float2bfloat16(gelu_f(fmaf(dD, bf2f(ub[l + 2048]), y[m].y)));
    }
}

// ============================ bf16 MFMA GEMM, both operands k-major ============================
// BSRC 0: Bm = B^T [N][K].  BSRC 1: im2col rows from h0pT (K reordered k'=dk*256+c).
// EPI: 0 gelu(acc+bias)->f32 | 1 acc+I->bf16 | 2 acc->bf16 | 3 acc+bias->bf16 | 4 final outputs
template<int BSRC, int EPI>
__global__ __launch_bounds__(256) void gemm_kernel(
    const ushort_t* __restrict__ A, const ushort_t* __restrict__ Bm,
    ushort_t* __restrict__ Cb, float* __restrict__ Cf,
    int M, int N, int K,
    const float* __restrict__ bias, const float* __restrict__ bias2,
    const float* __restrict__ xn, float* __restrict__ dout)
{
    __shared__ ushort_t Alds[128 * 40];
    __shared__ ushort_t Blds[128 * 40];
    const int t = threadIdx.x;
    const int n0 = blockIdx.x * 128, m0 = blockIdx.y * 128;
    const int w = t >> 6, lane = t & 63, quad = lane >> 4, lr = lane & 15;
    const int wm = (w >> 1) * 64, wn = (w & 1) * 64;

    const int i_s = t >> 1, j0 = (t & 1) * 16;
    int bI = 0, lI = 0;
    if (BSRC == 1) { int n = n0 + i_s; bI = n >> 11; lI = n & 2047; }

    float4_t acc[4][4];
    #pragma unroll
    for (int i = 0; i < 4; ++i)
        #pragma unroll
        for (int j = 0; j < 4; ++j) { float4_t z = {0.f, 0.f, 0.f, 0.f}; acc[i][j] = z; }

    for (int kt = 0; kt < K; kt += 32) {
        __syncthreads();
        {
            const short8* src = (const short8*)(A + (size_t)(m0 + i_s) * K + kt + j0);
            short8 v0 = src[0], v1 = src[1];
            *(short8*)&Alds[i_s * 40 + j0] = v0;
            *(short8*)&Alds[i_s * 40 + j0 + 8] = v1;
        }
        {
            const ushort_t* srcp;
            if (BSRC == 0) {
                srcp = Bm + (size_t)(n0 + i_s) * K + kt + j0;
            } else {
                int dk = kt >> 8, cb = kt & 255;
                srcp = Bm + (size_t)(bI * 2050 + lI + dk) * 256 + cb + j0;
            }
            const short8* src = (const short8*)srcp;
            short8 v0 = src[0], v1 = src[1];
            *(short8*)&Blds[i_s * 40 + j0] = v0;
            *(short8*)&Blds[i_s * 40 + j0 + 8] = v1;
        }
        __syncthreads();
        short8 af[4], bfr[4];
        #pragma unroll
        for (int im = 0; im < 4; ++im)
            af[im] = *(const short8*)&Alds[(wm + im * 16 + lr) * 40 + quad * 8];
        #pragma unroll
        for (int in_ = 0; in_ < 4; ++in_)
            bfr[in_] = *(const short8*)&Blds[(wn + in_ * 16 + lr) * 40 + quad * 8];
        #pragma unroll
        for (int im = 0; im < 4; ++im)
            #pragma unroll
            for (int in_ = 0; in_ < 4; ++in_)
                acc[im][in_] = __builtin_amdgcn_mfma_f32_16x16x32_bf16(af[im], bfr[in_], acc[im][in_], 0, 0, 0);
    }

    #pragma unroll
    for (int im = 0; im < 4; ++im) {
        #pragma unroll
        for (int in_ = 0; in_ < 4; ++in_) {
            int n = n0 + wn + in_ * 16 + lr;
            int mb = m0 + wm + im * 16 + quad * 4;
            #pragma unroll
            for (int r = 0; r < 4; ++r) {
                int m = mb + r;
                float v = acc[im][in_][r];
                if (EPI == 0) {
                    v += bias[m];
                    Cf[(size_t)m * N + n] = gelu_f(v);
                } else if (EPI == 1) {
                    v += (m == n) ? 1.0f : 0.0f;
                    ((__hip_bfloat16*)Cb)[(size_t)m * N + n] = __float2bfloat16(v);
                } else if (EPI == 2) {
                    ((__hip_bfloat16*)Cb)[(size_t)m * N + n] = __float2bfloat16(v);
                } else if (EPI == 3) {
                    v += bias[m];
                    ((__hip_bfloat16*)Cb)[(size_t)m * N + n] = __float2bfloat16(v);
                } else {
                    int bb = n >> 11, ll = n & 2047;
                    if (m < 256) {
                        v += bias[m];
                        int idx = (bb << 19) + (m << 11) + ll;
                        dout[idx] = (xn[idx] + v) * 0.70710678118654752f;
                    } else {
                        v += bias2[m - 256];
                        dout[4194304 + (bb << 19) + ((m - 256) << 11) + ll] = v;
                    }
                }
            }
        }
    }
}

// ============================ fused gate + transpose: gateT[n][m] = tanh(h2[m][n])*sigmoid(h2[m+256][n]) ============================
__global__ __launch_bounds__(256) void gate_t_kernel(
    const ushort_t* __restrict__ h2, ushort_t* __restrict__ gateT)
{
    __shared__ ushort_t S[64 * 65];
    int n0 = blockIdx.x * 64, m0 = blockIdx.y * 64;
    int t = threadIdx.x, lx = t & 63, ly0 = t >> 6;
    const __hip_bfloat16* h2b = (const __hip_bfloat16*)h2;
    #pragma unroll
    for (int ly = ly0; ly < 64; ly += 4) {
        float a = __bfloat162float(h2b[(size_t)(m0 + ly) * NBL + n0 + lx]);
        float b = __bfloat162float(h2b[(size_t)(m0 + 256 + ly) * NBL + n0 + lx]);
        __hip_bfloat16 v = __float2bfloat16(tanh_f(a) * sigmoid_f(b));
        S[ly * 65 + lx] = *(ushort_t*)&v;
    }
    __syncthreads();
    #pragma unroll
    for (int ly = ly0; ly < 64; ly += 4)
        gateT[(size_t)(n0 + ly) * 256 + m0 + lx] = S[lx * 65 + ly];
}

// ============================ launch ============================
extern "C" void kernel_launch(void* const* d_in, const int* in_sizes, int n_in,
                              void* d_out, int out_size, void* d_ws, size_t ws_size,
                              hipStream_t stream)
{
    const float* x         = (const float*)d_in[0];
    const float* original  = (const float*)d_in[1];
    const float* sn_scale  = (const float*)d_in[2];
    const float* conv_w    = (const float*)d_in[3];
    const float* conv_b    = (const float*)d_in[4];
    const float* s4_ln_g   = (const float*)d_in[5];
    const float* s4_ln_b   = (const float*)d_in[6];
    const float* s4_kernel = (const float*)d_in[7];
    const float* s4_D      = (const float*)d_in[8];
    const float* s4_out_w  = (const float*)d_in[9];
    const float* s4_out_b  = (const float*)d_in[10];
    const float* attn_v_w  = (const float*)d_in[11];
    const float* attn_v_b  = (const float*)d_in[12];
    const float* attn_o_w  = (const float*)d_in[13];
    const float* attn_o_b  = (const float*)d_in[14];
    const float* res_w     = (const float*)d_in[15];
    const float* res_b     = (const float*)d_in[16];
    const float* skip_w    = (const float*)d_in[17];
    const float* skip_b    = (const float*)d_in[18];

    char* ws = (char*)d_ws;
    __hip_bfloat16* convA = (__hip_bfloat16*)(ws + WS_CONVA);
    __hip_bfloat16* WvT   = (__hip_bfloat16*)(ws + WS_WV);
    __hip_bfloat16* WoBf  = (__hip_bfloat16*)(ws + WS_WO);
    __hip_bfloat16* W1T   = (__hip_bfloat16*)(ws + WS_W1);
    __hip_bfloat16* Wcat  = (__hip_bfloat16*)(ws + WS_WCAT);
    ushort_t* A2    = (ushort_t*)(ws + WS_A2);
    ushort_t* Acomb = (ushort_t*)(ws + WS_ACOMB);
    float* bcombp = (float*)(ws + WS_BCOMB);
    float* xnp    = (float*)(ws + WS_XN);
    ushort_t* h0p  = (ushort_t*)(ws + WS_H0P);
    ushort_t* h0pT = (ushort_t*)(ws + WS_H0PT);
    float* uP      = (float*)(ws + WS_U);
    ushort_t* ubP  = (ushort_t*)(ws + WS_UB);
    uint4* ufP = (uint4*)(ws + WS_UF);
    uint4* kfP = (uint4*)(ws + WS_KF);
    ushort_t* gP    = (ushort_t*)(ws + WS_G);
    ushort_t* gT    = (ushort_t*)(ws + WS_GT);
    ushort_t* h2P   = (ushort_t*)(ws + WS_H2);
    ushort_t* gateT = (ushort_t*)(ws + WS_GATET);

    // weight prep + attention-fold precompute
    wprep_kernel<<<dim3(4096), dim3(256), 0, stream>>>(conv_w, attn_v_w, attn_o_w, s4_out_w,
        res_w, skip_w, convA, WvT, WoBf, W1T, Wcat);
    gemm_kernel<0, 1><<<dim3(4, 4), dim3(256), 0, stream>>>(
        (const ushort_t*)WoBf, (const ushort_t*)WvT, A2, nullptr, 512, 512, 512,
        nullptr, nullptr, nullptr, nullptr);
    bias2_kernel<<<dim3(512), dim3(256), 0, stream>>>(
        (const __hip_bfloat16*)A2, s4_out_b, attn_o_w, attn_v_b, attn_o_b, bcombp);
    gemm_kernel<0, 2><<<dim3(16, 4), dim3(256), 0, stream>>>(
        A2, (const ushort_t*)W1T, Acomb, nullptr, 512, 2048, 512,
        nullptr, nullptr, nullptr, nullptr);

    // main pipeline
    prep_kernel<<<dim3(256), dim3(256), 0, stream>>>(x, original, sn_scale, xnp, h0p);
    transpose_kernel<<<dim3(257, 4), dim3(256), 0, stream>>>(h0p, h0pT, 256, 16400);
    gemm_kernel<1, 0><<<dim3(128, 4), dim3(256), 0, stream>>>(
        (const ushort_t*)convA, h0pT, nullptr, uP, 512, NBL, 768,
        conv_b, nullptr, nullptr, nullptr);
    ln_kernel<<<dim3(256), dim3(256), 0, stream>>>(uP, ubP, s4_ln_g, s4_ln_b);
    fft_fwd_kernel<<<dim3(4096), dim3(256), 0, stream>>>(ubP, s4_kernel, ufP, kfP);
    fft_inv_kernel<<<dim3(8192), dim3(256), 0, stream>>>(ufP, kfP, ubP, s4_D, gP);
    transpose_kernel<<<dim3(256, 32), dim3(256), 0, stream>>>(gP, gT, 2048, 16384);
    gemm_kernel<0, 3><<<dim3(128, 4), dim3(256), 0, stream>>>(
        (const ushort_t*)Acomb, gT, h2P, nullptr, 512, NBL, 2048,
        bcombp, nullptr, nullptr, nullptr);
    gate_t_kernel<<<dim3(256, 4), dim3(256), 0, stream>>>(h2P, gateT);
    gemm_kernel<0, 4><<<dim3(128, 4), dim3(256), 0, stream>>>(
        (const ushort_t*)Wcat, gateT, nullptr, nullptr, 512, NBL, 256,
        res_b, skip_b, xnp, (float*)d_out);
}

// Round 6
// 524.574 us; speedup vs baseline: 1.6791x; 1.0540x over previous
//
#include <hip/hip_runtime.h>
#include <hip/hip_bf16.h>
#include <math.h>

typedef __attribute__((ext_vector_type(8))) short short8;
typedef __attribute__((ext_vector_type(4))) float float4_t;
typedef __attribute__((ext_vector_type(2))) float cf2;   // complex (re, im) -> v_pk_* ops
typedef unsigned short ushort_t;
typedef unsigned int uint_t;

// Problem constants: B=8, C=256, L=2048, E=512, CH=4
#define NBL 16384          // B*L

// ---------------- workspace layout (bytes) ----------------
#define WS_CONVA   ((size_t)0)          // bf16 [512][768]  K reordered: k' = dk*256 + c
#define WS_WV      ((size_t)786432)     // bf16 [512][512]  Wv^T
#define WS_WO      ((size_t)1310720)    // bf16 [512][512]  Wo natural
#define WS_W1      ((size_t)1835008)    // bf16 [2048][512] s4_out_w^T
#define WS_WCAT    ((size_t)3932160)    // bf16 [512][256]
#define WS_A2      ((size_t)4194304)    // bf16 [512][512]  I + Wo@Wv
#define WS_ACOMB   ((size_t)4718592)    // bf16 [512][2048] A2 @ s4_out_w
#define WS_BCOMB   ((size_t)6815744)    // f32 [512]
#define WS_XN      ((size_t)6819840)    // bf16 [8][256][2048]  (8.4 MB)
#define WS_H0PT    ((size_t)23597056)   // bf16 [16400][256]  padded x+orig, transposed
#define WS_U       ((size_t)31993856)   // bf16 [512][16384]  conv+gelu output h (16 MB)
#define WS_UF      ((size_t)65548288)   // bf162 [2048][4096] packed u-pair spectra
#define WS_KF      ((size_t)99102720)   // bf162 [2048][4096] kernel spectra (pre-scaled 1/4096)
#define WS_G       ((size_t)132657152)  // bf16 [2048][16384] gelu(y + D*u)   end 199766016
#define WS_UB      ((size_t)208162816)  // bf16 [512][16384]  LN output u end 224940032
#define WS_GT      WS_UF                // bf16 [16384][2048] g^T (UF+KF dead by then)
#define WS_H2      WS_G                 // bf16 [512][16384]  (g dead after transpose)
#define WS_GATET   (WS_G + 25165824)    // bf16 [16384][256]

// ---------------- fast transcendental helpers ----------------
__device__ __forceinline__ float gelu_f(float x) {
    float t = x * x;
    float a2 = x * fmaf(0.07135481627f, t, 1.59576912161f);
    return x / (1.f + __expf(-a2));
}
__device__ __forceinline__ float tanh_f(float a) {
    return 1.f - 2.f / (1.f + __expf(2.f * a));
}
__device__ __forceinline__ float sigmoid_f(float b) {
    return 1.f / (1.f + __expf(-b));
}

__device__ __forceinline__ unsigned int pack_bf2(float a, float b) {
    __hip_bfloat16 ha = __float2bfloat16(a), hb = __float2bfloat16(b);
    unsigned short ua = *(unsigned short*)&ha, ub = *(unsigned short*)&hb;
    return (unsigned int)ua | ((unsigned int)ub << 16);
}
__device__ __forceinline__ cf2 unpack_c(unsigned int v) {
    cf2 r;
    r.x = __uint_as_float(v << 16);
    r.y = __uint_as_float(v & 0xffff0000u);
    return r;
}
__device__ __forceinline__ float bf2f(ushort_t u) {
    return __uint_as_float(((unsigned int)u) << 16);
}

// ---------------- packed complex primitives ----------------
__device__ __forceinline__ cf2 cswap(cf2 a) { return __builtin_shufflevector(a, a, 1, 0); }
template<int SGN>
__device__ __forceinline__ cf2 cmuli(cf2 a) {        // a * (SGN * i)
    cf2 s = cswap(a);
    return s * cf2{(float)(-SGN), (float)SGN};
}
__device__ __forceinline__ cf2 cmul(cf2 a, cf2 b) {  // full complex mul
    cf2 t = cswap(a) * cf2{-b.y, b.y};
    return a * cf2{b.x, b.x} + t;
}
__device__ __forceinline__ cf2 cmulc(cf2 a, float wr, float wi) {  // a * (wr + i wi), w const
    cf2 t = cswap(a) * cf2{-wi, wi};
    return a * cf2{wr, wr} + t;
}

// ============================ weight prep ============================
__global__ __launch_bounds__(256) void wprep_kernel(
    const float* __restrict__ conv_w, const float* __restrict__ attn_v_w,
    const float* __restrict__ attn_o_w, const float* __restrict__ s4_out_w,
    const float* __restrict__ res_w, const float* __restrict__ skip_w,
    __hip_bfloat16* __restrict__ convA, __hip_bfloat16* __restrict__ WvT,
    __hip_bfloat16* __restrict__ WoBf, __hip_bfloat16* __restrict__ W1T,
    __hip_bfloat16* __restrict__ Wcat)
{
    const int N0 = 393216, N1 = 655360, N2c = 917504, N3 = 1966080, N4 = 2097152;
    for (int i = blockIdx.x * 256 + threadIdx.x; i < N4; i += gridDim.x * 256) {
        if (i < N0) {
            int m = i / 768, r = i - m * 768, dk = r >> 8, c = r & 255;
            convA[i] = __float2bfloat16(conv_w[m * 768 + c * 3 + dk]);
        } else if (i < N1) {
            int j = i - N0; int row = j >> 9, e = j & 511;
            WvT[j] = __float2bfloat16(attn_v_w[e * 512 + row]);
        } else if (i < N2c) {
            WoBf[i - N1] = __float2bfloat16(attn_o_w[i - N1]);
        } else if (i < N3) {
            int j = i - N2c; int ck = j >> 9, e = j & 511;
            W1T[j] = __float2bfloat16(s4_out_w[e * 2048 + ck]);
        } else {
            int j = i - N3; int m = j >> 8, c = j & 255;
            float v = (m < 256) ? res_w[m * 256 + c] : skip_w[(m - 256) * 256 + c];
            Wcat[j] = __float2bfloat16(v);
        }
    }
}

__global__ __launch_bounds__(256) void bias2_kernel(
    const __hip_bfloat16* __restrict__ A2, const float* __restrict__ s4_out_b,
    const float* __restrict__ attn_o_w, const float* __restrict__ attn_v_b,
    const float* __restrict__ attn_o_b, float* __restrict__ bcomb)
{
    __shared__ float red[256];
    int o = blockIdx.x, t = threadIdx.x;
    float s = 0.f;
    for (int e = t; e < 512; e += 256)
        s += __bfloat162float(A2[o * 512 + e]) * s4_out_b[e] + attn_o_w[o * 512 + e] * attn_v_b[e];
    red[t] = s; __syncthreads();
    for (int k = 128; k > 0; k >>= 1) { if (t < k) red[t] += red[t + k]; __syncthreads(); }
    if (t == 0) bcomb[o] = red[0] + attn_o_b[o];
}

// ============================ prep: RMSNorm(x)->bf16 xn, (x+orig)->h0pT directly ============================
__global__ __launch_bounds__(256) void prep_kernel(
    const float* __restrict__ x, const float* __restrict__ orig,
    const float* __restrict__ sn, ushort_t* __restrict__ xnb, ushort_t* __restrict__ h0pT)
{
    __shared__ float red[4][64];
    int blk = blockIdx.x, t = threadIdx.x;
    int lane = t & 63, cg = t >> 6;
    int b = blk >> 5, l = ((blk & 31) << 6) + lane;
    size_t basein = (size_t)b * 524288 + l;
    float ss = 0.f;
    for (int c = cg; c < 256; c += 4) { float v = x[basein + (size_t)c * 2048]; ss += v * v; }
    red[cg][lane] = ss;
    __syncthreads();
    float tot = red[0][lane] + red[1][lane] + red[2][lane] + red[3][lane];
    float inv = 1.0f / (sqrtf(tot) * 0.0625f + 1e-8f);
    __hip_bfloat16* xo = (__hip_bfloat16*)xnb;
    __hip_bfloat16* hT = (__hip_bfloat16*)h0pT;
    size_t rowb = (size_t)(b * 2050 + 1 + l) * 256;
    for (int c = cg; c < 256; c += 4) {
        size_t idx = basein + (size_t)c * 2048;
        float xv = x[idx];
        xo[idx] = __float2bfloat16(sn[c] * xv * inv);
        hT[rowb + c] = __float2bfloat16(xv + orig[idx]);
    }
    if ((blk & 31) == 0) {   // zero pad rows l=-1 and l=2048 (c = t)
        hT[(size_t)(b * 2050) * 256 + t]        = __float2bfloat16(0.f);
        hT[(size_t)(b * 2050 + 2049) * 256 + t] = __float2bfloat16(0.f);
    }
}

// ============================ generic bf16 transpose (used for g) ============================
__global__ __launch_bounds__(256) void transpose_kernel(
    const ushort_t* __restrict__ in, ushort_t* __restrict__ out, int R, int C)
{
    __shared__ ushort_t S[64 * 65];
    int c0 = blockIdx.x * 64, r0 = blockIdx.y * 64;
    int t = threadIdx.x, lx = t & 63, ly0 = t >> 6;
    #pragma unroll
    for (int ly = ly0; ly < 64; ly += 4) {
        int r = r0 + ly, c = c0 + lx;
        S[ly * 65 + lx] = (r < R && c < C) ? in[(size_t)r * C + c] : (ushort_t)0;
    }
    __syncthreads();
    #pragma unroll
    for (int ly = ly0; ly < 64; ly += 4) {
        int oc = c0 + ly, orr = r0 + lx;
        if (oc < C && orr < R) out[(size_t)oc * R + orr] = S[lx * 65 + ly];
    }
}

// ============================ LayerNorm over E: bf16 h -> bf16 u ============================
__global__ __launch_bounds__(256) void ln_kernel(
    const ushort_t* __restrict__ h, ushort_t* __restrict__ ub,
    const float* __restrict__ gam, const float* __restrict__ bet)
{
    __shared__ float r1[4][64], r2[4][64];
    int blk = blockIdx.x, t = threadIdx.x;
    int lane = t & 63, og = t >> 6;
    int n = (blk << 6) + lane;
    float s1 = 0.f, s2 = 0.f;
    for (int o = og; o < 512; o += 4) { float v = bf2f(h[(size_t)o * NBL + n]); s1 += v; s2 += v * v; }
    r1[og][lane] = s1; r2[og][lane] = s2;
    __syncthreads();
    float mu = (r1[0][lane] + r1[1][lane] + r1[2][lane] + r1[3][lane]) * (1.f / 512.f);
    float m2 = (r2[0][lane] + r2[1][lane] + r2[2][lane] + r2[3][lane]) * (1.f / 512.f);
    float rstd = rsqrtf(m2 - mu * mu + 1e-5f);
    __hip_bfloat16* ubb = (__hip_bfloat16*)ub;
    for (int o = og; o < 512; o += 4) {
        size_t idx = (size_t)o * NBL + n;
        ubb[idx] = __float2bfloat16((bf2f(h[idx]) - mu) * rstd * gam[o] + bet[o]);
    }
}

// ============================ FFT: 4096-pt radix-16, LDS slot(i)=273B+17c+d ============================
// (injective, 4 lanes/bank-pair on every phase — verified round 3). Stage 1 fused with
// load, stage 3 fused with store/epilogue. All arithmetic packed cf2 (v_pk_* fp32).
#define PERM(m) ((((m) & 3) << 2) | ((m) >> 2))

template<int SGN>
__device__ __forceinline__ void dft4p(cf2& a0, cf2& a1, cf2& a2, cf2& a3) {
    cf2 t0 = a0 + a2, t1 = a0 - a2, t2 = a1 + a3, t3 = a1 - a3;
    cf2 j3 = cmuli<SGN>(t3);
    a0 = t0 + t2; a2 = t0 - t2;
    a1 = t1 + j3; a3 = t1 - j3;
}
template<int SGN>   // inputs a2,a3 implicitly zero
__device__ __forceinline__ void dft4p_half(cf2& a0, cf2& a1, cf2& a2, cf2& a3) {
    cf2 u0 = a0, u1 = a1;
    cf2 j1 = cmuli<SGN>(u1);
    a0 = u0 + u1; a2 = u0 - u1;
    a1 = u0 + j1; a3 = u0 - j1;
}
template<int SGN>   // only outputs bins m=s (o0) and m=4+s (o1)
__device__ __forceinline__ void dft4p_out01(cf2 a0, cf2 a1, cf2 a2, cf2 a3, cf2& o0, cf2& o1) {
    cf2 t0 = a0 + a2, t1 = a0 - a2, t2 = a1 + a3, t3 = a1 - a3;
    o0 = t0 + t2;
    o1 = t1 + cmuli<SGN>(t3);
}

template<int SGN>
__device__ __forceinline__ void dft16_stepB(cf2* x) {
    const float sg = (float)SGN;
    const float C16[10] = {1.f, 0.92387953f, 0.70710678f, 0.38268343f, 0.f,
                           -0.38268343f, -0.70710678f, -0.92387953f, -1.f, -0.92387953f};
    const float S16[10] = {0.f, 0.38268343f, 0.70710678f, 0.92387953f, 1.f,
                           0.92387953f, 0.70710678f, 0.38268343f, 0.f, -0.38268343f};
    #pragma unroll
    for (int s = 1; s < 4; ++s)
        #pragma unroll
        for (int r = 1; r < 4; ++r) {
            int e = s * r;
            x[4 * s + r] = cmulc(x[4 * s + r], C16[e], sg * S16[e]);
        }
}
template<int SGN>
__device__ __forceinline__ void dft16p(cf2* x) {
    #pragma unroll
    for (int r = 0; r < 4; ++r) dft4p<SGN>(x[r], x[4 + r], x[8 + r], x[12 + r]);
    dft16_stepB<SGN>(x);
    #pragma unroll
    for (int s = 0; s < 4; ++s) dft4p<SGN>(x[4 * s], x[4 * s + 1], x[4 * s + 2], x[4 * s + 3]);
}
template<int SGN>
__device__ __forceinline__ void dft16_halfin(cf2* x) {
    #pragma unroll
    for (int r = 0; r < 4; ++r) dft4p_half<SGN>(x[r], x[4 + r], x[8 + r], x[12 + r]);
    dft16_stepB<SGN>(x);
    #pragma unroll
    for (int s = 0; s < 4; ++s) dft4p<SGN>(x[4 * s], x[4 * s + 1], x[4 * s + 2], x[4 * s + 3]);
}
template<int SGN>   // y[m] = bin m, m=0..7
__device__ __forceinline__ void dft16_halfout(cf2* x, cf2* y) {
    #pragma unroll
    for (int r = 0; r < 4; ++r) dft4p<SGN>(x[r], x[4 + r], x[8 + r], x[12 + r]);
    dft16_stepB<SGN>(x);
    #pragma unroll
    for (int s = 0; s < 4; ++s)
        dft4p_out01<SGN>(x[4 * s], x[4 * s + 1], x[4 * s + 2], x[4 * s + 3], y[s], y[4 + s]);
}

template<int SGN>
__device__ __forceinline__ void tw_after(cf2* x, float p, float invQ) {
    float s1, c1; __sincosf((float)SGN * 6.283185307179586f * p * invQ, &s1, &c1);
    cf2 w1 = {c1, s1}, w = w1;
    #pragma unroll
    for (int m = 1; m < 16; ++m) { x[PERM(m)] = cmul(x[PERM(m)], w); w = cmul(w, w1); }
}
template<int SGN>
__device__ __forceinline__ void tw_before(cf2* x, float p, float invQ) {
    float s1, c1; __sincosf((float)SGN * 6.283185307179586f * p * invQ, &s1, &c1);
    cf2 w1 = {c1, s1}, w = w1;
    #pragma unroll
    for (int j = 1; j < 16; ++j) { x[j] = cmul(x[j], w); w = cmul(w, w1); }
}

// forward: wg<2048 -> packed u-pair rows (bf16 u); wg>=2048 -> kernel rows (f32, pre-scale 1/4096)
__global__ __launch_bounds__(256) void fft_fwd_kernel(
    const ushort_t* __restrict__ ubf, const float* __restrict__ s4k,
    uint4* __restrict__ uf, uint4* __restrict__ kf)
{
    __shared__ cf2 S[4368];
    int wg = blockIdx.x, t = threadIdx.x;
    cf2 x[16];
    if (wg < 2048) {
        int bp = wg >> 9, e = wg & 511;
        const ushort_t* p0 = ubf + (size_t)e * NBL + (size_t)bp * 4096;
        #pragma unroll
        for (int j = 0; j < 8; ++j) {
            int i = j * 256 + t;
            x[j] = cf2{bf2f(p0[i]), bf2f(p0[i + 2048])};
        }
    } else {
        const float* p0 = s4k + (size_t)(wg - 2048) * 2048;
        #pragma unroll
        for (int j = 0; j < 8; ++j) x[j] = cf2{p0[j * 256 + t], 0.f};
    }
    dft16_halfin<-1>(x);
    tw_after<-1>(x, (float)t, 1.f / 4096.f);
    int tb = 17 * (t >> 4) + (t & 15);
    #pragma unroll
    for (int m = 0; m < 16; ++m) S[tb + 273 * m] = x[PERM(m)];
    __syncthreads();
    int b2 = 273 * (t >> 4) + (t & 15);
    #pragma unroll
    for (int j = 0; j < 16; ++j) x[j] = S[b2 + 17 * j];
    dft16p<-1>(x);
    tw_after<-1>(x, (float)(t & 15), 1.f / 256.f);
    #pragma unroll
    for (int m = 0; m < 16; ++m) S[b2 + 17 * m] = x[PERM(m)];
    __syncthreads();
    int b3 = 273 * (t >> 4) + 17 * (t & 15);
    #pragma unroll
    for (int j = 0; j < 16; ++j) x[j] = S[b3 + j];
    dft16p<-1>(x);
    const float sc = (wg < 2048) ? 1.f : (1.f / 4096.f);
    uint4* dst = ((wg < 2048) ? (uf + (size_t)wg * 1024) : (kf + (size_t)(wg - 2048) * 1024)) + 4 * t;
    #pragma unroll
    for (int q = 0; q < 4; ++q) {
        uint4 o;
        cf2 v0 = x[PERM(4 * q)] * sc, v1 = x[PERM(4 * q + 1)] * sc;
        cf2 v2 = x[PERM(4 * q + 2)] * sc, v3 = x[PERM(4 * q + 3)] * sc;
        o.x = pack_bf2(v0.x, v0.y);
        o.y = pack_bf2(v1.x, v1.y);
        o.z = pack_bf2(v2.x, v2.y);
        o.w = pack_bf2(v3.x, v3.y);
        dst[q] = o;
    }
}

// inverse: spectra product in registers, DIT stages, half-out final stage fused with D-skip + gelu.
__global__ __launch_bounds__(256) void fft_inv_kernel(
    const uint4* __restrict__ uf, const uint4* __restrict__ kf,
    const ushort_t* __restrict__ ubf, const float* __restrict__ s4D,
    ushort_t* __restrict__ g)
{
    __shared__ cf2 S[4368];
    int wg = blockIdx.x, t = threadIdx.x;
    int bp = wg >> 11, ch = (wg >> 9) & 3, e = wg & 511;
    const uint4* zr = uf + (size_t)(bp * 512 + e) * 1024 + 4 * t;
    const uint4* kr = kf + (size_t)(ch * 512 + e) * 1024 + 4 * t;
    cf2 x[16];
    #pragma unroll
    for (int q = 0; q < 4; ++q) {
        uint4 a4 = zr[q], b4 = kr[q];
        x[4 * q + 0] = cmul(unpack_c(a4.x), unpack_c(b4.x));
        x[4 * q + 1] = cmul(unpack_c(a4.y), unpack_c(b4.y));
        x[4 * q + 2] = cmul(unpack_c(a4.z), unpack_c(b4.z));
        x[4 * q + 3] = cmul(unpack_c(a4.w), unpack_c(b4.w));
    }
    dft16p<1>(x);
    int b1 = 273 * (t >> 4) + 17 * (t & 15);
    #pragma unroll
    for (int m = 0; m < 16; ++m) S[b1 + m] = x[PERM(m)];
    __syncthreads();
    int b2 = 273 * (t >> 4) + (t & 15);
    #pragma unroll
    for (int j = 0; j < 16; ++j) x[j] = S[b2 + 17 * j];
    tw_before<1>(x, (float)(t & 15), 1.f / 256.f);
    dft16p<1>(x);
    #pragma unroll
    for (int m = 0; m < 16; ++m) S[b2 + 17 * m] = x[PERM(m)];
    __syncthreads();
    int b3 = 17 * (t >> 4) + (t & 15);
    #pragma unroll
    for (int j = 0; j < 16; ++j) x[j] = S[b3 + 273 * j];
    tw_before<1>(x, (float)t, 1.f / 4096.f);
    cf2 y[8];
    dft16_halfout<1>(x, y);
    float dD = s4D[ch * 512 + e];
    const ushort_t* ub = ubf + (size_t)e * NBL + (size_t)bp * 4096;
    __hip_bfloat16* go = (__hip_bfloat16*)g + ((size_t)(ch * 512 + e) * NBL + (size_t)bp * 4096);
    #pragma unroll
    for (int m = 0; m < 8; ++m) {
        int l = m * 256 + t;
        go[l]        = __float2bfloat16(gelu_f(fmaf(dD, bf2f(ub[l]), y[m].x)));
        go[l + 2048] = __float2bfloat16(gelu_f(fmaf(dD, bf2f(ub[l + 2048]), y[m].y)));
    }
}

// ============================ bf16 MFMA GEMM, both operands k-major ============================
// BSRC 0: Bm = B^T [N][K].  BSRC 1: im2col rows from h0pT (K reordered k'=dk*256+c).
// EPI: 0 gelu(acc+bias)->bf16 | 1 acc+I->bf16 | 2 acc->bf16 | 3 acc+bias->bf16 | 4 final outputs
template<int BSRC, int EPI>
__global__ __launch_bounds__(256) void gemm_kernel(
    const ushort_t* __restrict__ A, const ushort_t* __restrict__ Bm,
    ushort_t* __restrict__ Cb, float* __restrict__ Cf,
    int M, int N, int K,
    const float* __restrict__ bias, const float* __restrict__ bias2,
    const ushort_t* __restrict__ xnb, float* __restrict__ dout)
{
    __shared__ ushort_t Alds[128 * 40];
    __shared__ ushort_t Blds[128 * 40];
    const int t = threadIdx.x;
    const int n0 = blockIdx.x * 128, m0 = blockIdx.y * 128;
    const int w = t >> 6, lane = t & 63, quad = lane >> 4, lr = lane & 15;
    const int wm = (w >> 1) * 64, wn = (w & 1) * 64;

    const int i_s = t >> 1, j0 = (t & 1) * 16;
    int bI = 0, lI = 0;
    if (BSRC == 1) { int n = n0 + i_s; bI = n >> 11; lI = n & 2047; }

    float4_t acc[4][4];
    #pragma unroll
    for (int i = 0; i < 4; ++i)
        #pragma unroll
        for (int j = 0; j < 4; ++j) { float4_t z = {0.f, 0.f, 0.f, 0.f}; acc[i][j] = z; }

    for (int kt = 0; kt < K; kt += 32) {
        __syncthreads();
        {
            const short8* src = (const short8*)(A + (size_t)(m0 + i_s) * K + kt + j0);
            short8 v0 = src[0], v1 = src[1];
            *(short8*)&Alds[i_s * 40 + j0] = v0;
            *(short8*)&Alds[i_s * 40 + j0 + 8] = v1;
        }
        {
            const ushort_t* srcp;
            if (BSRC == 0) {
                srcp = Bm + (size_t)(n0 + i_s) * K + kt + j0;
            } else {
                int dk = kt >> 8, cb = kt & 255;
                srcp = Bm + (size_t)(bI * 2050 + lI + dk) * 256 + cb + j0;
            }
            const short8* src = (const short8*)srcp;
            short8 v0 = src[0], v1 = src[1];
            *(short8*)&Blds[i_s * 40 + j0] = v0;
            *(short8*)&Blds[i_s * 40 + j0 + 8] = v1;
        }
        __syncthreads();
        short8 af[4], bfr[4];
        #pragma unroll
        for (int im = 0; im < 4; ++im)
            af[im] = *(const short8*)&Alds[(wm + im * 16 + lr) * 40 + quad * 8];
        #pragma unroll
        for (int in_ = 0; in_ < 4; ++in_)
            bfr[in_] = *(const short8*)&Blds[(wn + in_ * 16 + lr) * 40 + quad * 8];
        #pragma unroll
        for (int im = 0; im < 4; ++im)
            #pragma unroll
            for (int in_ = 0; in_ < 4; ++in_)
                acc[im][in_] = __builtin_amdgcn_mfma_f32_16x16x32_bf16(af[im], bfr[in_], acc[im][in_], 0, 0, 0);
    }

    #pragma unroll
    for (int im = 0; im < 4; ++im) {
        #pragma unroll
        for (int in_ = 0; in_ < 4; ++in_) {
            int n = n0 + wn + in_ * 16 + lr;
            int mb = m0 + wm + im * 16 + quad * 4;
            #pragma unroll
            for (int r = 0; r < 4; ++r) {
                int m = mb + r;
                float v = acc[im][in_][r];
                if (EPI == 0) {
                    v += bias[m];
                    ((__hip_bfloat16*)Cb)[(size_t)m * N + n] = __float2bfloat16(gelu_f(v));
                } else if (EPI == 1) {
                    v += (m == n) ? 1.0f : 0.0f;
                    ((__hip_bfloat16*)Cb)[(size_t)m * N + n] = __float2bfloat16(v);
                } else if (EPI == 2) {
                    ((__hip_bfloat16*)Cb)[(size_t)m * N + n] = __float2bfloat16(v);
                } else if (EPI == 3) {
                    v += bias[m];
                    ((__hip_bfloat16*)Cb)[(size_t)m * N + n] = __float2bfloat16(v);
                } else {
                    int bb = n >> 11, ll = n & 2047;
                    if (m < 256) {
                        v += bias[m];
                        int idx = (bb << 19) + (m << 11) + ll;
                        dout[idx] = (bf2f(xnb[idx]) + v) * 0.70710678118654752f;
                    } else {
                        v += bias2[m - 256];
                        dout[4194304 + (bb << 19) + ((m - 256) << 11) + ll] = v;
                    }
                }
            }
        }
    }
}

// ============================ fused gate + transpose ============================
__global__ __launch_bounds__(256) void gate_t_kernel(
    const ushort_t* __restrict__ h2, ushort_t* __restrict__ gateT)
{
    __shared__ ushort_t S[64 * 65];
    int n0 = blockIdx.x * 64, m0 = blockIdx.y * 64;
    int t = threadIdx.x, lx = t & 63, ly0 = t >> 6;
    const __hip_bfloat16* h2b = (const __hip_bfloat16*)h2;
    #pragma unroll
    for (int ly = ly0; ly < 64; ly += 4) {
        float a = __bfloat162float(h2b[(size_t)(m0 + ly) * NBL + n0 + lx]);
        float b = __bfloat162float(h2b[(size_t)(m0 + 256 + ly) * NBL + n0 + lx]);
        __hip_bfloat16 v = __float2bfloat16(tanh_f(a) * sigmoid_f(b));
        S[ly * 65 + lx] = *(ushort_t*)&v;
    }
    __syncthreads();
    #pragma unroll
    for (int ly = ly0; ly < 64; ly += 4)
        gateT[(size_t)(n0 + ly) * 256 + m0 + lx] = S[lx * 65 + ly];
}

// ============================ launch ============================
extern "C" void kernel_launch(void* const* d_in, const int* in_sizes, int n_in,
                              void* d_out, int out_size, void* d_ws, size_t ws_size,
                              hipStream_t stream)
{
    const float* x         = (const float*)d_in[0];
    const float* original  = (const float*)d_in[1];
    const float* sn_scale  = (const float*)d_in[2];
    const float* conv_w    = (const float*)d_in[3];
    const float* conv_b    = (const float*)d_in[4];
    const float* s4_ln_g   = (const float*)d_in[5];
    const float* s4_ln_b   = (const float*)d_in[6];
    const float* s4_kernel = (const float*)d_in[7];
    const float* s4_D      = (const float*)d_in[8];
    const float* s4_out_w  = (const float*)d_in[9];
    const float* s4_out_b  = (const float*)d_in[10];
    const float* attn_v_w  = (const float*)d_in[11];
    const float* attn_v_b  = (const float*)d_in[12];
    const float* attn_o_w  = (const float*)d_in[13];
    const float* attn_o_b  = (const float*)d_in[14];
    const float* res_w     = (const float*)d_in[15];
    const float* res_b     = (const float*)d_in[16];
    const float* skip_w    = (const float*)d_in[17];
    const float* skip_b    = (const float*)d_in[18];

    char* ws = (char*)d_ws;
    __hip_bfloat16* convA = (__hip_bfloat16*)(ws + WS_CONVA);
    __hip_bfloat16* WvT   = (__hip_bfloat16*)(ws + WS_WV);
    __hip_bfloat16* WoBf  = (__hip_bfloat16*)(ws + WS_WO);
    __hip_bfloat16* W1T   = (__hip_bfloat16*)(ws + WS_W1);
    __hip_bfloat16* Wcat  = (__hip_bfloat16*)(ws + WS_WCAT);
    ushort_t* A2    = (ushort_t*)(ws + WS_A2);
    ushort_t* Acomb = (ushort_t*)(ws + WS_ACOMB);
    float* bcombp  = (float*)(ws + WS_BCOMB);
    ushort_t* xnb  = (ushort_t*)(ws + WS_XN);
    ushort_t* h0pT = (ushort_t*)(ws + WS_H0PT);
    ushort_t* hP   = (ushort_t*)(ws + WS_U);
    ushort_t* ubP  = (ushort_t*)(ws + WS_UB);
    uint4* ufP = (uint4*)(ws + WS_UF);
    uint4* kfP = (uint4*)(ws + WS_KF);
    ushort_t* gP    = (ushort_t*)(ws + WS_G);
    ushort_t* gT    = (ushort_t*)(ws + WS_GT);
    ushort_t* h2P   = (ushort_t*)(ws + WS_H2);
    ushort_t* gateT = (ushort_t*)(ws + WS_GATET);

    // weight prep + attention-fold precompute
    wprep_kernel<<<dim3(4096), dim3(256), 0, stream>>>(conv_w, attn_v_w, attn_o_w, s4_out_w,
        res_w, skip_w, convA, WvT, WoBf, W1T, Wcat);
    gemm_kernel<0, 1><<<dim3(4, 4), dim3(256), 0, stream>>>(
        (const ushort_t*)WoBf, (const ushort_t*)WvT, A2, nullptr, 512, 512, 512,
        nullptr, nullptr, nullptr, nullptr);
    bias2_kernel<<<dim3(512), dim3(256), 0, stream>>>(
        (const __hip_bfloat16*)A2, s4_out_b, attn_o_w, attn_v_b, attn_o_b, bcombp);
    gemm_kernel<0, 2><<<dim3(16, 4), dim3(256), 0, stream>>>(
        A2, (const ushort_t*)W1T, Acomb, nullptr, 512, 2048, 512,
        nullptr, nullptr, nullptr, nullptr);

    // main pipeline
    prep_kernel<<<dim3(256), dim3(256), 0, stream>>>(x, original, sn_scale, xnb, h0pT);
    gemm_kernel<1, 0><<<dim3(128, 4), dim3(256), 0, stream>>>(
        (const ushort_t*)convA, h0pT, hP, nullptr, 512, NBL, 768,
        conv_b, nullptr, nullptr, nullptr);
    ln_kernel<<<dim3(256), dim3(256), 0, stream>>>(hP, ubP, s4_ln_g, s4_ln_b);
    fft_fwd_kernel<<<dim3(4096), dim3(256), 0, stream>>>(ubP, s4_kernel, ufP, kfP);
    fft_inv_kernel<<<dim3(8192), dim3(256), 0, stream>>>(ufP, kfP, ubP, s4_D, gP);
    transpose_kernel<<<dim3(256, 32), dim3(256), 0, stream>>>(gP, gT, 2048, 16384);
    gemm_kernel<0, 3><<<dim3(128, 4), dim3(256), 0, stream>>>(
        (const ushort_t*)Acomb, gT, h2P, nullptr, 512, NBL, 2048,
        bcombp, nullptr, nullptr, nullptr);
    gate_t_kernel<<<dim3(256, 4), dim3(256), 0, stream>>>(h2P, gateT);
    gemm_kernel<0, 4><<<dim3(128, 4), dim3(256), 0, stream>>>(
        (const ushort_t*)Wcat, gateT, nullptr, nullptr, 512, NBL, 256,
        res_b, skip_b, xnb, (float*)d_out);
}

// Round 7
// 440.788 us; speedup vs baseline: 1.9983x; 1.1901x over previous
//
#include <hip/hip_runtime.h>
#include <hip/hip_bf16.h>
#include <math.h>

typedef __attribute__((ext_vector_type(8))) short short8;
typedef __attribute__((ext_vector_type(4))) float float4_t;
typedef __attribute__((ext_vector_type(2))) float cf2;   // complex (re, im) -> v_pk_* ops
typedef unsigned short ushort_t;

// Problem constants: B=8, C=256, L=2048, E=512, CH=4
#define NBL 16384          // B*L

// ---------------- workspace layout (bytes) ----------------
#define WS_CONVA   ((size_t)0)          // bf16 [512][768]  K reordered: k' = dk*256 + c
#define WS_WV      ((size_t)786432)     // bf16 [512][512]  Wv^T
#define WS_WO      ((size_t)1310720)    // bf16 [512][512]  Wo natural
#define WS_W1      ((size_t)1835008)    // bf16 [2048][512] s4_out_w^T
#define WS_WCAT    ((size_t)3932160)    // bf16 [512][256]
#define WS_A2      ((size_t)4194304)    // bf16 [512][512]  I + Wo@Wv
#define WS_ACOMB   ((size_t)4718592)    // bf16 [512][2048] A2 @ s4_out_w
#define WS_BCOMB   ((size_t)6815744)    // f32 [512]
#define WS_XN      ((size_t)6819840)    // bf16 [8][256][2048]  (8.4 MB)
#define WS_H0PT    ((size_t)23597056)   // bf16 [16400][256]  padded x+orig, transposed
#define WS_U       ((size_t)31993856)   // bf16 [512][16384]  conv+gelu output h (16 MB)
#define WS_UF      ((size_t)65548288)   // bf162 [2048][4096] packed u-pair spectra
#define WS_KF      ((size_t)99102720)   // bf162 [2048][4096] kernel spectra (pre-scaled 1/4096)
#define WS_G       ((size_t)132657152)  // bf16 [2048][16384] gelu(y + D*u)   end 199766016
#define WS_UB      ((size_t)208162816)  // bf16 [512][16384]  LN output u end 224940032
#define WS_GT      WS_UF                // bf16 [16384][2048] g^T (UF+KF dead by then)
#define WS_H2      WS_G                 // bf16 [512][16384]  (g dead after transpose)
#define WS_GATET   (WS_G + 25165824)    // bf16 [16384][256]

// ---------------- fast transcendental helpers ----------------
__device__ __forceinline__ float gelu_f(float x) {
    float t = x * x;
    float a2 = x * fmaf(0.07135481627f, t, 1.59576912161f);
    return x / (1.f + __expf(-a2));
}
__device__ __forceinline__ float tanh_f(float a) {
    return 1.f - 2.f / (1.f + __expf(2.f * a));
}
__device__ __forceinline__ float sigmoid_f(float b) {
    return 1.f / (1.f + __expf(-b));
}

__device__ __forceinline__ unsigned int pack_bf2(float a, float b) {
    __hip_bfloat16 ha = __float2bfloat16(a), hb = __float2bfloat16(b);
    unsigned short ua = *(unsigned short*)&ha, ub = *(unsigned short*)&hb;
    return (unsigned int)ua | ((unsigned int)ub << 16);
}
__device__ __forceinline__ cf2 unpack_c(unsigned int v) {
    cf2 r;
    r.x = __uint_as_float(v << 16);
    r.y = __uint_as_float(v & 0xffff0000u);
    return r;
}
__device__ __forceinline__ float bf2f(ushort_t u) {
    return __uint_as_float(((unsigned int)u) << 16);
}

// ---------------- packed complex primitives ----------------
__device__ __forceinline__ cf2 cswap(cf2 a) { return __builtin_shufflevector(a, a, 1, 0); }
template<int SGN>
__device__ __forceinline__ cf2 cmuli(cf2 a) {        // a * (SGN * i)
    cf2 s = cswap(a);
    return s * cf2{(float)(-SGN), (float)SGN};
}
__device__ __forceinline__ cf2 cmul(cf2 a, cf2 b) {  // full complex mul
    cf2 t = cswap(a) * cf2{-b.y, b.y};
    return a * cf2{b.x, b.x} + t;
}
__device__ __forceinline__ cf2 cmulc(cf2 a, float wr, float wi) {  // a * (wr + i wi), w const
    cf2 t = cswap(a) * cf2{-wi, wi};
    return a * cf2{wr, wr} + t;
}

// ============================ weight prep ============================
__global__ __launch_bounds__(256) void wprep_kernel(
    const float* __restrict__ conv_w, const float* __restrict__ attn_v_w,
    const float* __restrict__ attn_o_w, const float* __restrict__ s4_out_w,
    const float* __restrict__ res_w, const float* __restrict__ skip_w,
    __hip_bfloat16* __restrict__ convA, __hip_bfloat16* __restrict__ WvT,
    __hip_bfloat16* __restrict__ WoBf, __hip_bfloat16* __restrict__ W1T,
    __hip_bfloat16* __restrict__ Wcat)
{
    const int N0 = 393216, N1 = 655360, N2c = 917504, N3 = 1966080, N4 = 2097152;
    for (int i = blockIdx.x * 256 + threadIdx.x; i < N4; i += gridDim.x * 256) {
        if (i < N0) {
            int m = i / 768, r = i - m * 768, dk = r >> 8, c = r & 255;
            convA[i] = __float2bfloat16(conv_w[m * 768 + c * 3 + dk]);
        } else if (i < N1) {
            int j = i - N0; int row = j >> 9, e = j & 511;
            WvT[j] = __float2bfloat16(attn_v_w[e * 512 + row]);
        } else if (i < N2c) {
            WoBf[i - N1] = __float2bfloat16(attn_o_w[i - N1]);
        } else if (i < N3) {
            int j = i - N2c; int ck = j >> 9, e = j & 511;
            W1T[j] = __float2bfloat16(s4_out_w[e * 2048 + ck]);
        } else {
            int j = i - N3; int m = j >> 8, c = j & 255;
            float v = (m < 256) ? res_w[m * 256 + c] : skip_w[(m - 256) * 256 + c];
            Wcat[j] = __float2bfloat16(v);
        }
    }
}

__global__ __launch_bounds__(256) void bias2_kernel(
    const __hip_bfloat16* __restrict__ A2, const float* __restrict__ s4_out_b,
    const float* __restrict__ attn_o_w, const float* __restrict__ attn_v_b,
    const float* __restrict__ attn_o_b, float* __restrict__ bcomb)
{
    __shared__ float red[256];
    int o = blockIdx.x, t = threadIdx.x;
    float s = 0.f;
    for (int e = t; e < 512; e += 256)
        s += __bfloat162float(A2[o * 512 + e]) * s4_out_b[e] + attn_o_w[o * 512 + e] * attn_v_b[e];
    red[t] = s; __syncthreads();
    for (int k = 128; k > 0; k >>= 1) { if (t < k) red[t] += red[t + k]; __syncthreads(); }
    if (t == 0) bcomb[o] = red[0] + attn_o_b[o];
}

// ============================ prep: RMSNorm->xn bf16, (x+orig)->h0pT via LDS tile ============================
// 512 threads (8 waves). LDS tile T[256 c][66] bf16 (stride 66 shorts: all phases 2-lane/bank = free).
__global__ __launch_bounds__(512) void prep_kernel(
    const float* __restrict__ x, const float* __restrict__ orig,
    const float* __restrict__ sn, ushort_t* __restrict__ xnb, ushort_t* __restrict__ h0pT)
{
    __shared__ float red[8][64];
    __shared__ ushort_t T[256 * 66];
    int blk = blockIdx.x, t = threadIdx.x;
    int lane = t & 63, cg = t >> 6;          // cg 0..7
    int b = blk >> 5, l0 = (blk & 31) << 6;
    size_t basein = (size_t)b * 524288 + l0 + lane;
    float ss = 0.f;
    for (int c = cg; c < 256; c += 8) {
        size_t idx = basein + (size_t)c * 2048;
        float xv = x[idx], ov = orig[idx];
        ss += xv * xv;
        __hip_bfloat16 hv = __float2bfloat16(xv + ov);
        T[c * 66 + lane] = *(ushort_t*)&hv;
    }
    red[cg][lane] = ss;
    __syncthreads();
    float tot = 0.f;
    #pragma unroll
    for (int k = 0; k < 8; ++k) tot += red[k][lane];
    float inv = 1.0f / (sqrtf(tot) * 0.0625f + 1e-8f);
    __hip_bfloat16* xo = (__hip_bfloat16*)xnb;
    for (int c = cg; c < 256; c += 8) {
        size_t idx = basein + (size_t)c * 2048;
        xo[idx] = __float2bfloat16(sn[c] * x[idx] * inv);   // x reread: L2-hot
    }
    // phase B: coalesced h0pT rows (row = b*2050+1+l0+r, 256 c contiguous)
    int c2 = t & 255, half = t >> 8;
    size_t rowbase = (size_t)(b * 2050 + 1 + l0);
    for (int r = half; r < 64; r += 2)
        h0pT[(rowbase + r) * 256 + c2] = T[c2 * 66 + r];
    if ((blk & 31) == 0) {   // zero pad rows
        if (t < 256) h0pT[(size_t)(b * 2050) * 256 + t] = 0;
        else         h0pT[(size_t)(b * 2050 + 2049) * 256 + (t - 256)] = 0;
    }
}

// ============================ generic bf16 transpose (used for g) ============================
__global__ __launch_bounds__(256) void transpose_kernel(
    const ushort_t* __restrict__ in, ushort_t* __restrict__ out, int R, int C)
{
    __shared__ ushort_t S[64 * 65];
    int c0 = blockIdx.x * 64, r0 = blockIdx.y * 64;
    int t = threadIdx.x, lx = t & 63, ly0 = t >> 6;
    #pragma unroll
    for (int ly = ly0; ly < 64; ly += 4) {
        int r = r0 + ly, c = c0 + lx;
        S[ly * 65 + lx] = (r < R && c < C) ? in[(size_t)r * C + c] : (ushort_t)0;
    }
    __syncthreads();
    #pragma unroll
    for (int ly = ly0; ly < 64; ly += 4) {
        int oc = c0 + ly, orr = r0 + lx;
        if (oc < C && orr < R) out[(size_t)oc * R + orr] = S[lx * 65 + ly];
    }
}

// ============================ LayerNorm over E: bf16 h -> bf16 u (512 threads) ============================
__global__ __launch_bounds__(512) void ln_kernel(
    const ushort_t* __restrict__ h, ushort_t* __restrict__ ub,
    const float* __restrict__ gam, const float* __restrict__ bet)
{
    __shared__ float r1[8][64], r2[8][64];
    int blk = blockIdx.x, t = threadIdx.x;
    int lane = t & 63, og = t >> 6;
    int n = (blk << 6) + lane;
    float s1 = 0.f, s2 = 0.f;
    for (int o = og; o < 512; o += 8) { float v = bf2f(h[(size_t)o * NBL + n]); s1 += v; s2 += v * v; }
    r1[og][lane] = s1; r2[og][lane] = s2;
    __syncthreads();
    float mu = 0.f, m2 = 0.f;
    #pragma unroll
    for (int k = 0; k < 8; ++k) { mu += r1[k][lane]; m2 += r2[k][lane]; }
    mu *= (1.f / 512.f); m2 *= (1.f / 512.f);
    float rstd = rsqrtf(m2 - mu * mu + 1e-5f);
    __hip_bfloat16* ubb = (__hip_bfloat16*)ub;
    for (int o = og; o < 512; o += 8) {
        size_t idx = (size_t)o * NBL + n;
        ubb[idx] = __float2bfloat16((bf2f(h[idx]) - mu) * rstd * gam[o] + bet[o]);
    }
}

// ============================ FFT: 4096-pt radix-16, LDS slot(i)=273B+17c+d ============================
#define PERM(m) ((((m) & 3) << 2) | ((m) >> 2))

template<int SGN>
__device__ __forceinline__ void dft4p(cf2& a0, cf2& a1, cf2& a2, cf2& a3) {
    cf2 t0 = a0 + a2, t1 = a0 - a2, t2 = a1 + a3, t3 = a1 - a3;
    cf2 j3 = cmuli<SGN>(t3);
    a0 = t0 + t2; a2 = t0 - t2;
    a1 = t1 + j3; a3 = t1 - j3;
}
template<int SGN>
__device__ __forceinline__ void dft4p_half(cf2& a0, cf2& a1, cf2& a2, cf2& a3) {
    cf2 u0 = a0, u1 = a1;
    cf2 j1 = cmuli<SGN>(u1);
    a0 = u0 + u1; a2 = u0 - u1;
    a1 = u0 + j1; a3 = u0 - j1;
}
template<int SGN>
__device__ __forceinline__ void dft4p_out01(cf2 a0, cf2 a1, cf2 a2, cf2 a3, cf2& o0, cf2& o1) {
    cf2 t0 = a0 + a2, t1 = a0 - a2, t2 = a1 + a3, t3 = a1 - a3;
    o0 = t0 + t2;
    o1 = t1 + cmuli<SGN>(t3);
}

template<int SGN>
__device__ __forceinline__ void dft16_stepB(cf2* x) {
    const float sg = (float)SGN;
    const float C16[10] = {1.f, 0.92387953f, 0.70710678f, 0.38268343f, 0.f,
                           -0.38268343f, -0.70710678f, -0.92387953f, -1.f, -0.92387953f};
    const float S16[10] = {0.f, 0.38268343f, 0.70710678f, 0.92387953f, 1.f,
                           0.92387953f, 0.70710678f, 0.38268343f, 0.f, -0.38268343f};
    #pragma unroll
    for (int s = 1; s < 4; ++s)
        #pragma unroll
        for (int r = 1; r < 4; ++r) {
            int e = s * r;
            x[4 * s + r] = cmulc(x[4 * s + r], C16[e], sg * S16[e]);
        }
}
template<int SGN>
__device__ __forceinline__ void dft16p(cf2* x) {
    #pragma unroll
    for (int r = 0; r < 4; ++r) dft4p<SGN>(x[r], x[4 + r], x[8 + r], x[12 + r]);
    dft16_stepB<SGN>(x);
    #pragma unroll
    for (int s = 0; s < 4; ++s) dft4p<SGN>(x[4 * s], x[4 * s + 1], x[4 * s + 2], x[4 * s + 3]);
}
template<int SGN>
__device__ __forceinline__ void dft16_halfin(cf2* x) {
    #pragma unroll
    for (int r = 0; r < 4; ++r) dft4p_half<SGN>(x[r], x[4 + r], x[8 + r], x[12 + r]);
    dft16_stepB<SGN>(x);
    #pragma unroll
    for (int s = 0; s < 4; ++s) dft4p<SGN>(x[4 * s], x[4 * s + 1], x[4 * s + 2], x[4 * s + 3]);
}
template<int SGN>
__device__ __forceinline__ void dft16_halfout(cf2* x, cf2* y) {
    #pragma unroll
    for (int r = 0; r < 4; ++r) dft4p<SGN>(x[r], x[4 + r], x[8 + r], x[12 + r]);
    dft16_stepB<SGN>(x);
    #pragma unroll
    for (int s = 0; s < 4; ++s)
        dft4p_out01<SGN>(x[4 * s], x[4 * s + 1], x[4 * s + 2], x[4 * s + 3], y[s], y[4 + s]);
}

template<int SGN>
__device__ __forceinline__ void tw_after(cf2* x, float p, float invQ) {
    float s1, c1; __sincosf((float)SGN * 6.283185307179586f * p * invQ, &s1, &c1);
    cf2 w1 = {c1, s1}, w = w1;
    #pragma unroll
    for (int m = 1; m < 16; ++m) { x[PERM(m)] = cmul(x[PERM(m)], w); w = cmul(w, w1); }
}
template<int SGN>
__device__ __forceinline__ void tw_before(cf2* x, float p, float invQ) {
    float s1, c1; __sincosf((float)SGN * 6.283185307179586f * p * invQ, &s1, &c1);
    cf2 w1 = {c1, s1}, w = w1;
    #pragma unroll
    for (int j = 1; j < 16; ++j) { x[j] = cmul(x[j], w); w = cmul(w, w1); }
}

__global__ __launch_bounds__(256) void fft_fwd_kernel(
    const ushort_t* __restrict__ ubf, const float* __restrict__ s4k,
    uint4* __restrict__ uf, uint4* __restrict__ kf)
{
    __shared__ cf2 S[4368];
    int wg = blockIdx.x, t = threadIdx.x;
    cf2 x[16];
    if (wg < 2048) {
        int bp = wg >> 9, e = wg & 511;
        const ushort_t* p0 = ubf + (size_t)e * NBL + (size_t)bp * 4096;
        #pragma unroll
        for (int j = 0; j < 8; ++j) {
            int i = j * 256 + t;
            x[j] = cf2{bf2f(p0[i]), bf2f(p0[i + 2048])};
        }
    } else {
        const float* p0 = s4k + (size_t)(wg - 2048) * 2048;
        #pragma unroll
        for (int j = 0; j < 8; ++j) x[j] = cf2{p0[j * 256 + t], 0.f};
    }
    dft16_halfin<-1>(x);
    tw_after<-1>(x, (float)t, 1.f / 4096.f);
    int tb = 17 * (t >> 4) + (t & 15);
    #pragma unroll
    for (int m = 0; m < 16; ++m) S[tb + 273 * m] = x[PERM(m)];
    __syncthreads();
    int b2 = 273 * (t >> 4) + (t & 15);
    #pragma unroll
    for (int j = 0; j < 16; ++j) x[j] = S[b2 + 17 * j];
    dft16p<-1>(x);
    tw_after<-1>(x, (float)(t & 15), 1.f / 256.f);
    #pragma unroll
    for (int m = 0; m < 16; ++m) S[b2 + 17 * m] = x[PERM(m)];
    __syncthreads();
    int b3 = 273 * (t >> 4) + 17 * (t & 15);
    #pragma unroll
    for (int j = 0; j < 16; ++j) x[j] = S[b3 + j];
    dft16p<-1>(x);
    const float sc = (wg < 2048) ? 1.f : (1.f / 4096.f);
    uint4* dst = ((wg < 2048) ? (uf + (size_t)wg * 1024) : (kf + (size_t)(wg - 2048) * 1024)) + 4 * t;
    #pragma unroll
    for (int q = 0; q < 4; ++q) {
        uint4 o;
        cf2 v0 = x[PERM(4 * q)] * sc, v1 = x[PERM(4 * q + 1)] * sc;
        cf2 v2 = x[PERM(4 * q + 2)] * sc, v3 = x[PERM(4 * q + 3)] * sc;
        o.x = pack_bf2(v0.x, v0.y);
        o.y = pack_bf2(v1.x, v1.y);
        o.z = pack_bf2(v2.x, v2.y);
        o.w = pack_bf2(v3.x, v3.y);
        dst[q] = o;
    }
}

__global__ __launch_bounds__(256) void fft_inv_kernel(
    const uint4* __restrict__ uf, const uint4* __restrict__ kf,
    const ushort_t* __restrict__ ubf, const float* __restrict__ s4D,
    ushort_t* __restrict__ g)
{
    __shared__ cf2 S[4368];
    int wg = blockIdx.x, t = threadIdx.x;
    int bp = wg >> 11, ch = (wg >> 9) & 3, e = wg & 511;
    const uint4* zr = uf + (size_t)(bp * 512 + e) * 1024 + 4 * t;
    const uint4* kr = kf + (size_t)(ch * 512 + e) * 1024 + 4 * t;
    cf2 x[16];
    #pragma unroll
    for (int q = 0; q < 4; ++q) {
        uint4 a4 = zr[q], b4 = kr[q];
        x[4 * q + 0] = cmul(unpack_c(a4.x), unpack_c(b4.x));
        x[4 * q + 1] = cmul(unpack_c(a4.y), unpack_c(b4.y));
        x[4 * q + 2] = cmul(unpack_c(a4.z), unpack_c(b4.z));
        x[4 * q + 3] = cmul(unpack_c(a4.w), unpack_c(b4.w));
    }
    dft16p<1>(x);
    int b1 = 273 * (t >> 4) + 17 * (t & 15);
    #pragma unroll
    for (int m = 0; m < 16; ++m) S[b1 + m] = x[PERM(m)];
    __syncthreads();
    int b2 = 273 * (t >> 4) + (t & 15);
    #pragma unroll
    for (int j = 0; j < 16; ++j) x[j] = S[b2 + 17 * j];
    tw_before<1>(x, (float)(t & 15), 1.f / 256.f);
    dft16p<1>(x);
    #pragma unroll
    for (int m = 0; m < 16; ++m) S[b2 + 17 * m] = x[PERM(m)];
    __syncthreads();
    int b3 = 17 * (t >> 4) + (t & 15);
    #pragma unroll
    for (int j = 0; j < 16; ++j) x[j] = S[b3 + 273 * j];
    tw_before<1>(x, (float)t, 1.f / 4096.f);
    cf2 y[8];
    dft16_halfout<1>(x, y);
    float dD = s4D[ch * 512 + e];
    const ushort_t* ub = ubf + (size_t)e * NBL + (size_t)bp * 4096;
    __hip_bfloat16* go = (__hip_bfloat16*)g + ((size_t)(ch * 512 + e) * NBL + (size_t)bp * 4096);
    #pragma unroll
    for (int m = 0; m < 8; ++m) {
        int l = m * 256 + t;
        go[l]        = __float2bfloat16(gelu_f(fmaf(dD, bf2f(ub[l]), y[m].x)));
        go[l + 2048] = __float2bfloat16(gelu_f(fmaf(dD, bf2f(ub[l + 2048]), y[m].y)));
    }
}

// ============================ bf16 MFMA GEMM, software-pipelined ============================
// Both operands k-major. Register prefetch: store staged regs -> barrier -> issue next
// global loads -> MFMA on current LDS tile -> barrier. Loads land during MFMA phase.
// BSRC 0: Bm = B^T [N][K].  BSRC 1: im2col rows from h0pT (K reordered k'=dk*256+c).
// EPI: 0 gelu(acc+bias)->bf16 | 1 acc+I->bf16 | 2 acc->bf16 | 3 acc+bias->bf16 | 4 final outputs
template<int BSRC, int EPI>
__global__ __launch_bounds__(256) void gemm_kernel(
    const ushort_t* __restrict__ A, const ushort_t* __restrict__ Bm,
    ushort_t* __restrict__ Cb, float* __restrict__ Cf,
    int M, int N, int K,
    const float* __restrict__ bias, const float* __restrict__ bias2,
    const ushort_t* __restrict__ xnb, float* __restrict__ dout)
{
    __shared__ ushort_t Alds[128 * 40];
    __shared__ ushort_t Blds[128 * 40];
    const int t = threadIdx.x;
    const int n0 = blockIdx.x * 128, m0 = blockIdx.y * 128;
    const int w = t >> 6, lane = t & 63, quad = lane >> 4, lr = lane & 15;
    const int wm = (w >> 1) * 64, wn = (w & 1) * 64;

    const int i_s = t >> 1, j0 = (t & 1) * 16;
    int bI = 0, lI = 0;
    if (BSRC == 1) { int n = n0 + i_s; bI = n >> 11; lI = n & 2047; }

    float4_t acc[4][4];
    #pragma unroll
    for (int i = 0; i < 4; ++i)
        #pragma unroll
        for (int j = 0; j < 4; ++j) { float4_t z = {0.f, 0.f, 0.f, 0.f}; acc[i][j] = z; }

    short8 pa0, pa1, pb0, pb1;
    {   // initial tile (kt = 0)
        const short8* sa = (const short8*)(A + (size_t)(m0 + i_s) * K + j0);
        pa0 = sa[0]; pa1 = sa[1];
        const ushort_t* sp;
        if (BSRC == 0) sp = Bm + (size_t)(n0 + i_s) * K + j0;
        else           sp = Bm + (size_t)(bI * 2050 + lI) * 256 + j0;
        const short8* sb = (const short8*)sp;
        pb0 = sb[0]; pb1 = sb[1];
    }

    for (int kt = 0; kt < K; kt += 32) {
        if (kt) __syncthreads();            // all waves done reading prev tile
        *(short8*)&Alds[i_s * 40 + j0]     = pa0;
        *(short8*)&Alds[i_s * 40 + j0 + 8] = pa1;
        *(short8*)&Blds[i_s * 40 + j0]     = pb0;
        *(short8*)&Blds[i_s * 40 + j0 + 8] = pb1;
        __syncthreads();
        int kn = kt + 32;
        if (kn < K) {                       // prefetch next tile; lands during MFMA
            const short8* sa = (const short8*)(A + (size_t)(m0 + i_s) * K + kn + j0);
            pa0 = sa[0]; pa1 = sa[1];
            const ushort_t* sp;
            if (BSRC == 0) sp = Bm + (size_t)(n0 + i_s) * K + kn + j0;
            else { int dk = kn >> 8, cb = kn & 255; sp = Bm + (size_t)(bI * 2050 + lI + dk) * 256 + cb + j0; }
            const short8* sb = (const short8*)sp;
            pb0 = sb[0]; pb1 = sb[1];
        }
        short8 af[4], bfr[4];
        #pragma unroll
        for (int im = 0; im < 4; ++im)
            af[im] = *(const short8*)&Alds[(wm + im * 16 + lr) * 40 + quad * 8];
        #pragma unroll
        for (int in_ = 0; in_ < 4; ++in_)
            bfr[in_] = *(const short8*)&Blds[(wn + in_ * 16 + lr) * 40 + quad * 8];
        #pragma unroll
        for (int im = 0; im < 4; ++im)
            #pragma unroll
            for (int in_ = 0; in_ < 4; ++in_)
                acc[im][in_] = __builtin_amdgcn_mfma_f32_16x16x32_bf16(af[im], bfr[in_], acc[im][in_], 0, 0, 0);
    }

    #pragma unroll
    for (int im = 0; im < 4; ++im) {
        #pragma unroll
        for (int in_ = 0; in_ < 4; ++in_) {
            int n = n0 + wn + in_ * 16 + lr;
            int mb = m0 + wm + im * 16 + quad * 4;
            #pragma unroll
            for (int r = 0; r < 4; ++r) {
                int m = mb + r;
                float v = acc[im][in_][r];
                if (EPI == 0) {
                    v += bias[m];
                    ((__hip_bfloat16*)Cb)[(size_t)m * N + n] = __float2bfloat16(gelu_f(v));
                } else if (EPI == 1) {
                    v += (m == n) ? 1.0f : 0.0f;
                    ((__hip_bfloat16*)Cb)[(size_t)m * N + n] = __float2bfloat16(v);
                } else if (EPI == 2) {
                    ((__hip_bfloat16*)Cb)[(size_t)m * N + n] = __float2bfloat16(v);
                } else if (EPI == 3) {
                    v += bias[m];
                    ((__hip_bfloat16*)Cb)[(size_t)m * N + n] = __float2bfloat16(v);
                } else {
                    int bb = n >> 11, ll = n & 2047;
                    if (m < 256) {
                        v += bias[m];
                        int idx = (bb << 19) + (m << 11) + ll;
                        dout[idx] = (bf2f(xnb[idx]) + v) * 0.70710678118654752f;
                    } else {
                        v += bias2[m - 256];
                        dout[4194304 + (bb << 19) + ((m - 256) << 11) + ll] = v;
                    }
                }
            }
        }
    }
}

// ============================ fused gate + transpose ============================
__global__ __launch_bounds__(256) void gate_t_kernel(
    const ushort_t* __restrict__ h2, ushort_t* __restrict__ gateT)
{
    __shared__ ushort_t S[64 * 65];
    int n0 = blockIdx.x * 64, m0 = blockIdx.y * 64;
    int t = threadIdx.x, lx = t & 63, ly0 = t >> 6;
    const __hip_bfloat16* h2b = (const __hip_bfloat16*)h2;
    #pragma unroll
    for (int ly = ly0; ly < 64; ly += 4) {
        float a = __bfloat162float(h2b[(size_t)(m0 + ly) * NBL + n0 + lx]);
        float b = __bfloat162float(h2b[(size_t)(m0 + 256 + ly) * NBL + n0 + lx]);
        __hip_bfloat16 v = __float2bfloat16(tanh_f(a) * sigmoid_f(b));
        S[ly * 65 + lx] = *(ushort_t*)&v;
    }
    __syncthreads();
    #pragma unroll
    for (int ly = ly0; ly < 64; ly += 4)
        gateT[(size_t)(n0 + ly) * 256 + m0 + lx] = S[lx * 65 + ly];
}

// ============================ launch ============================
extern "C" void kernel_launch(void* const* d_in, const int* in_sizes, int n_in,
                              void* d_out, int out_size, void* d_ws, size_t ws_size,
                              hipStream_t stream)
{
    const float* x         = (const float*)d_in[0];
    const float* original  = (const float*)d_in[1];
    const float* sn_scale  = (const float*)d_in[2];
    const float* conv_w    = (const float*)d_in[3];
    const float* conv_b    = (const float*)d_in[4];
    const float* s4_ln_g   = (const float*)d_in[5];
    const float* s4_ln_b   = (const float*)d_in[6];
    const float* s4_kernel = (const float*)d_in[7];
    const float* s4_D      = (const float*)d_in[8];
    const float* s4_out_w  = (const float*)d_in[9];
    const float* s4_out_b  = (const float*)d_in[10];
    const float* attn_v_w  = (const float*)d_in[11];
    const float* attn_v_b  = (const float*)d_in[12];
    const float* attn_o_w  = (const float*)d_in[13];
    const float* attn_o_b  = (const float*)d_in[14];
    const float* res_w     = (const float*)d_in[15];
    const float* res_b     = (const float*)d_in[16];
    const float* skip_w    = (const float*)d_in[17];
    const float* skip_b    = (const float*)d_in[18];

    char* ws = (char*)d_ws;
    __hip_bfloat16* convA = (__hip_bfloat16*)(ws + WS_CONVA);
    __hip_bfloat16* WvT   = (__hip_bfloat16*)(ws + WS_WV);
    __hip_bfloat16* WoBf  = (__hip_bfloat16*)(ws + WS_WO);
    __hip_bfloat16* W1T   = (__hip_bfloat16*)(ws + WS_W1);
    __hip_bfloat16* Wcat  = (__hip_bfloat16*)(ws + WS_WCAT);
    ushort_t* A2    = (ushort_t*)(ws + WS_A2);
    ushort_t* Acomb = (ushort_t*)(ws + WS_ACOMB);
    float* bcombp  = (float*)(ws + WS_BCOMB);
    ushort_t* xnb  = (ushort_t*)(ws + WS_XN);
    ushort_t* h0pT = (ushort_t*)(ws + WS_H0PT);
    ushort_t* hP   = (ushort_t*)(ws + WS_U);
    ushort_t* ubP  = (ushort_t*)(ws + WS_UB);
    uint4* ufP = (uint4*)(ws + WS_UF);
    uint4* kfP = (uint4*)(ws + WS_KF);
    ushort_t* gP    = (ushort_t*)(ws + WS_G);
    ushort_t* gT    = (ushort_t*)(ws + WS_GT);
    ushort_t* h2P   = (ushort_t*)(ws + WS_H2);
    ushort_t* gateT = (ushort_t*)(ws + WS_GATET);

    // weight prep + attention-fold precompute
    wprep_kernel<<<dim3(4096), dim3(256), 0, stream>>>(conv_w, attn_v_w, attn_o_w, s4_out_w,
        res_w, skip_w, convA, WvT, WoBf, W1T, Wcat);
    gemm_kernel<0, 1><<<dim3(4, 4), dim3(256), 0, stream>>>(
        (const ushort_t*)WoBf, (const ushort_t*)WvT, A2, nullptr, 512, 512, 512,
        nullptr, nullptr, nullptr, nullptr);
    bias2_kernel<<<dim3(512), dim3(256), 0, stream>>>(
        (const __hip_bfloat16*)A2, s4_out_b, attn_o_w, attn_v_b, attn_o_b, bcombp);
    gemm_kernel<0, 2><<<dim3(16, 4), dim3(256), 0, stream>>>(
        A2, (const ushort_t*)W1T, Acomb, nullptr, 512, 2048, 512,
        nullptr, nullptr, nullptr, nullptr);

    // main pipeline
    prep_kernel<<<dim3(256), dim3(512), 0, stream>>>(x, original, sn_scale, xnb, h0pT);
    gemm_kernel<1, 0><<<dim3(128, 4), dim3(256), 0, stream>>>(
        (const ushort_t*)convA, h0pT, hP, nullptr, 512, NBL, 768,
        conv_b, nullptr, nullptr, nullptr);
    ln_kernel<<<dim3(256), dim3(512), 0, stream>>>(hP, ubP, s4_ln_g, s4_ln_b);
    fft_fwd_kernel<<<dim3(4096), dim3(256), 0, stream>>>(ubP, s4_kernel, ufP, kfP);
    fft_inv_kernel<<<dim3(8192), dim3(256), 0, stream>>>(ufP, kfP, ubP, s4_D, gP);
    transpose_kernel<<<dim3(256, 32), dim3(256), 0, stream>>>(gP, gT, 2048, 16384);
    gemm_kernel<0, 3><<<dim3(128, 4), dim3(256), 0, stream>>>(
        (const ushort_t*)Acomb, gT, h2P, nullptr, 512, NBL, 2048,
        bcombp, nullptr, nullptr, nullptr);
    gate_t_kernel<<<dim3(256, 4), dim3(256), 0, stream>>>(h2P, gateT);
    gemm_kernel<0, 4><<<dim3(128, 4), dim3(256), 0, stream>>>(
        (const ushort_t*)Wcat, gateT, nullptr, nullptr, 512, NBL, 256,
        res_b, skip_b, xnb, (float*)d_out);
}

// Round 8
// 421.752 us; speedup vs baseline: 2.0885x; 1.0451x over previous
//
#include <hip/hip_runtime.h>
#include <hip/hip_bf16.h>
#include <math.h>

typedef __attribute__((ext_vector_type(8))) short short8;
typedef __attribute__((ext_vector_type(4))) float float4_t;
typedef __attribute__((ext_vector_type(2))) float cf2;   // complex (re, im) -> v_pk_* ops
typedef unsigned short ushort_t;
typedef unsigned int uint_t;

// Problem constants: B=8, C=256, L=2048, E=512, CH=4
#define NBL 16384          // B*L

// ---------------- workspace layout (bytes) ----------------
#define WS_CONVA   ((size_t)0)          // bf16 [512][768]  K reordered: k' = dk*256 + c
#define WS_WV      ((size_t)786432)     // bf16 [512][512]  Wv^T
#define WS_WO      ((size_t)1310720)    // bf16 [512][512]  Wo natural
#define WS_W1      ((size_t)1835008)    // bf16 [2048][512] s4_out_w^T
#define WS_WCAT    ((size_t)3932160)    // bf16 [512][256]
#define WS_A2      ((size_t)4194304)    // bf16 [512][512]  I + Wo@Wv
#define WS_ACOMB   ((size_t)4718592)    // bf16 [512][2048] A2 @ s4_out_w
#define WS_BCOMB   ((size_t)6815744)    // f32 [512]
#define WS_XN      ((size_t)6819840)    // bf16 [8][256][2048]
#define WS_H0PT    ((size_t)23597056)   // bf16 [16400][256]  padded x+orig, transposed
#define WS_U       ((size_t)31993856)   // bf16 [512][16384]  conv+gelu output h
#define WS_GT      ((size_t)65548288)   // bf16 [16384][2048] g^T  (67,108,864 B, ends 132657152)
#define WS_UF      WS_GT                // bf162 [2048][4096] u-pair spectra (dead before gT written)
#define WS_KF      ((size_t)99102720)   // bf162 [2048][4096] kernel spectra (pre-scaled 1/4096)
#define WS_G       ((size_t)132657152)  // uint [2048][8192]  packed raw y pairs  end 199766016
#define WS_GATET   (WS_G + 25165824)    // bf16 [16384][256]  (g dead by gemm3)
#define WS_UB      ((size_t)208162816)  // bf16-pair uint [512][8192]  LN output u, end 224940032

// ---------------- fast transcendental helpers ----------------
__device__ __forceinline__ float gelu_f(float x) {
    float t = x * x;
    float a2 = x * fmaf(0.07135481627f, t, 1.59576912161f);
    return x / (1.f + __expf(-a2));
}
__device__ __forceinline__ float tanh_f(float a) {
    return 1.f - 2.f / (1.f + __expf(2.f * a));
}
__device__ __forceinline__ float sigmoid_f(float b) {
    return 1.f / (1.f + __expf(-b));
}

__device__ __forceinline__ unsigned int pack_bf2(float a, float b) {
#if __has_builtin(__builtin_amdgcn_cvt_pk_bf16_f32)
    auto v = __builtin_amdgcn_cvt_pk_bf16_f32(a, b);
    unsigned int r; __builtin_memcpy(&r, &v, 4); return r;
#else
    __hip_bfloat16 ha = __float2bfloat16(a), hb = __float2bfloat16(b);
    unsigned short ua = *(unsigned short*)&ha, ub = *(unsigned short*)&hb;
    return (unsigned int)ua | ((unsigned int)ub << 16);
#endif
}
__device__ __forceinline__ ushort_t f2bfu(float a) {
    __hip_bfloat16 h = __float2bfloat16(a);
    return *(ushort_t*)&h;
}
__device__ __forceinline__ cf2 unpack_c(unsigned int v) {
    cf2 r;
    r.x = __uint_as_float(v << 16);
    r.y = __uint_as_float(v & 0xffff0000u);
    return r;
}
__device__ __forceinline__ float bf2f(ushort_t u) {
    return __uint_as_float(((unsigned int)u) << 16);
}

// ---------------- packed complex primitives ----------------
__device__ __forceinline__ cf2 cswap(cf2 a) { return __builtin_shufflevector(a, a, 1, 0); }
template<int SGN>
__device__ __forceinline__ cf2 cmuli(cf2 a) {
    cf2 s = cswap(a);
    return s * cf2{(float)(-SGN), (float)SGN};
}
__device__ __forceinline__ cf2 cmul(cf2 a, cf2 b) {
    cf2 t = cswap(a) * cf2{-b.y, b.y};
    return a * cf2{b.x, b.x} + t;
}
__device__ __forceinline__ cf2 cmulc(cf2 a, float wr, float wi) {
    cf2 t = cswap(a) * cf2{-wi, wi};
    return a * cf2{wr, wr} + t;
}

// ============================ weight prep ============================
__global__ __launch_bounds__(256) void wprep_kernel(
    const float* __restrict__ conv_w, const float* __restrict__ attn_v_w,
    const float* __restrict__ attn_o_w, const float* __restrict__ s4_out_w,
    const float* __restrict__ res_w, const float* __restrict__ skip_w,
    __hip_bfloat16* __restrict__ convA, __hip_bfloat16* __restrict__ WvT,
    __hip_bfloat16* __restrict__ WoBf, __hip_bfloat16* __restrict__ W1T,
    __hip_bfloat16* __restrict__ Wcat)
{
    const int N0 = 393216, N1 = 655360, N2c = 917504, N3 = 1966080, N4 = 2097152;
    for (int i = blockIdx.x * 256 + threadIdx.x; i < N4; i += gridDim.x * 256) {
        if (i < N0) {
            int m = i / 768, r = i - m * 768, dk = r >> 8, c = r & 255;
            convA[i] = __float2bfloat16(conv_w[m * 768 + c * 3 + dk]);
        } else if (i < N1) {
            int j = i - N0; int row = j >> 9, e = j & 511;
            WvT[j] = __float2bfloat16(attn_v_w[e * 512 + row]);
        } else if (i < N2c) {
            WoBf[i - N1] = __float2bfloat16(attn_o_w[i - N1]);
        } else if (i < N3) {
            int j = i - N2c; int ck = j >> 9, e = j & 511;
            W1T[j] = __float2bfloat16(s4_out_w[e * 2048 + ck]);
        } else {
            int j = i - N3; int m = j >> 8, c = j & 255;
            float v = (m < 256) ? res_w[m * 256 + c] : skip_w[(m - 256) * 256 + c];
            Wcat[j] = __float2bfloat16(v);
        }
    }
}

__global__ __launch_bounds__(256) void bias2_kernel(
    const __hip_bfloat16* __restrict__ A2, const float* __restrict__ s4_out_b,
    const float* __restrict__ attn_o_w, const float* __restrict__ attn_v_b,
    const float* __restrict__ attn_o_b, float* __restrict__ bcomb)
{
    __shared__ float red[256];
    int o = blockIdx.x, t = threadIdx.x;
    float s = 0.f;
    for (int e = t; e < 512; e += 256)
        s += __bfloat162float(A2[o * 512 + e]) * s4_out_b[e] + attn_o_w[o * 512 + e] * attn_v_b[e];
    red[t] = s; __syncthreads();
    for (int k = 128; k > 0; k >>= 1) { if (t < k) red[t] += red[t + k]; __syncthreads(); }
    if (t == 0) bcomb[o] = red[0] + attn_o_b[o];
}

// ============================ prep: RMSNorm->xn bf16, (x+orig)->h0pT via LDS tile ============================
__global__ __launch_bounds__(512) void prep_kernel(
    const float* __restrict__ x, const float* __restrict__ orig,
    const float* __restrict__ sn, ushort_t* __restrict__ xnb, ushort_t* __restrict__ h0pT)
{
    __shared__ float red[8][64];
    __shared__ ushort_t T[256 * 66];
    int blk = blockIdx.x, t = threadIdx.x;
    int lane = t & 63, cg = t >> 6;
    int b = blk >> 5, l0 = (blk & 31) << 6;
    size_t basein = (size_t)b * 524288 + l0 + lane;
    float ss = 0.f;
    for (int c = cg; c < 256; c += 8) {
        size_t idx = basein + (size_t)c * 2048;
        float xv = x[idx], ov = orig[idx];
        ss += xv * xv;
        T[c * 66 + lane] = f2bfu(xv + ov);
    }
    red[cg][lane] = ss;
    __syncthreads();
    float tot = 0.f;
    #pragma unroll
    for (int k = 0; k < 8; ++k) tot += red[k][lane];
    float inv = 1.0f / (sqrtf(tot) * 0.0625f + 1e-8f);
    __hip_bfloat16* xo = (__hip_bfloat16*)xnb;
    for (int c = cg; c < 256; c += 8) {
        size_t idx = basein + (size_t)c * 2048;
        xo[idx] = __float2bfloat16(sn[c] * x[idx] * inv);
    }
    int c2 = t & 255, half = t >> 8;
    size_t rowbase = (size_t)(b * 2050 + 1 + l0);
    for (int r = half; r < 64; r += 2)
        h0pT[(rowbase + r) * 256 + c2] = T[c2 * 66 + r];
    if ((blk & 31) == 0) {
        if (t < 256) h0pT[(size_t)(b * 2050) * 256 + t] = 0;
        else         h0pT[(size_t)(b * 2050 + 2049) * 256 + (t - 256)] = 0;
    }
}

// ============================ LayerNorm over E: bf16 h -> pair-interleaved bf16 u ============================
// u stored as uint pairs: ushort idx = e*16384 + (b>>1)*4096 + 2*l + (b&1)
__global__ __launch_bounds__(512) void ln_kernel(
    const ushort_t* __restrict__ h, ushort_t* __restrict__ ub,
    const float* __restrict__ gam, const float* __restrict__ bet)
{
    __shared__ float r1[8][64], r2[8][64];
    int blk = blockIdx.x, t = threadIdx.x;
    int lane = t & 63, og = t >> 6;
    int n = (blk << 6) + lane;
    float s1 = 0.f, s2 = 0.f;
    for (int o = og; o < 512; o += 8) { float v = bf2f(h[(size_t)o * NBL + n]); s1 += v; s2 += v * v; }
    r1[og][lane] = s1; r2[og][lane] = s2;
    __syncthreads();
    float mu = 0.f, m2 = 0.f;
    #pragma unroll
    for (int k = 0; k < 8; ++k) { mu += r1[k][lane]; m2 += r2[k][lane]; }
    mu *= (1.f / 512.f); m2 *= (1.f / 512.f);
    float rstd = rsqrtf(m2 - mu * mu + 1e-5f);
    int b = n >> 11, l = n & 2047;
    size_t sbase = (size_t)(b >> 1) * 4096 + 2 * l + (b & 1);
    for (int o = og; o < 512; o += 8) {
        size_t idx = (size_t)o * NBL + n;
        ub[(size_t)o * 16384 + sbase] = f2bfu((bf2f(h[idx]) - mu) * rstd * gam[o] + bet[o]);
    }
}

// ============================ FFT: 4096-pt radix-16, LDS slot(i)=273B+17c+d ============================
#define PERM(m) ((((m) & 3) << 2) | ((m) >> 2))

template<int SGN>
__device__ __forceinline__ void dft4p(cf2& a0, cf2& a1, cf2& a2, cf2& a3) {
    cf2 t0 = a0 + a2, t1 = a0 - a2, t2 = a1 + a3, t3 = a1 - a3;
    cf2 j3 = cmuli<SGN>(t3);
    a0 = t0 + t2; a2 = t0 - t2;
    a1 = t1 + j3; a3 = t1 - j3;
}
template<int SGN>
__device__ __forceinline__ void dft4p_half(cf2& a0, cf2& a1, cf2& a2, cf2& a3) {
    cf2 u0 = a0, u1 = a1;
    cf2 j1 = cmuli<SGN>(u1);
    a0 = u0 + u1; a2 = u0 - u1;
    a1 = u0 + j1; a3 = u0 - j1;
}
template<int SGN>
__device__ __forceinline__ void dft4p_out01(cf2 a0, cf2 a1, cf2 a2, cf2 a3, cf2& o0, cf2& o1) {
    cf2 t0 = a0 + a2, t1 = a0 - a2, t2 = a1 + a3, t3 = a1 - a3;
    o0 = t0 + t2;
    o1 = t1 + cmuli<SGN>(t3);
}

template<int SGN>
__device__ __forceinline__ void dft16_stepB(cf2* x) {
    const float sg = (float)SGN;
    const float C16[10] = {1.f, 0.92387953f, 0.70710678f, 0.38268343f, 0.f,
                           -0.38268343f, -0.70710678f, -0.92387953f, -1.f, -0.92387953f};
    const float S16[10] = {0.f, 0.38268343f, 0.70710678f, 0.92387953f, 1.f,
                           0.92387953f, 0.70710678f, 0.38268343f, 0.f, -0.38268343f};
    #pragma unroll
    for (int s = 1; s < 4; ++s)
        #pragma unroll
        for (int r = 1; r < 4; ++r) {
            int e = s * r;
            x[4 * s + r] = cmulc(x[4 * s + r], C16[e], sg * S16[e]);
        }
}
template<int SGN>
__device__ __forceinline__ void dft16p(cf2* x) {
    #pragma unroll
    for (int r = 0; r < 4; ++r) dft4p<SGN>(x[r], x[4 + r], x[8 + r], x[12 + r]);
    dft16_stepB<SGN>(x);
    #pragma unroll
    for (int s = 0; s < 4; ++s) dft4p<SGN>(x[4 * s], x[4 * s + 1], x[4 * s + 2], x[4 * s + 3]);
}
template<int SGN>
__device__ __forceinline__ void dft16_halfin(cf2* x) {
    #pragma unroll
    for (int r = 0; r < 4; ++r) dft4p_half<SGN>(x[r], x[4 + r], x[8 + r], x[12 + r]);
    dft16_stepB<SGN>(x);
    #pragma unroll
    for (int s = 0; s < 4; ++s) dft4p<SGN>(x[4 * s], x[4 * s + 1], x[4 * s + 2], x[4 * s + 3]);
}
template<int SGN>
__device__ __forceinline__ void dft16_halfout(cf2* x, cf2* y) {
    #pragma unroll
    for (int r = 0; r < 4; ++r) dft4p<SGN>(x[r], x[4 + r], x[8 + r], x[12 + r]);
    dft16_stepB<SGN>(x);
    #pragma unroll
    for (int s = 0; s < 4; ++s)
        dft4p_out01<SGN>(x[4 * s], x[4 * s + 1], x[4 * s + 2], x[4 * s + 3], y[s], y[4 + s]);
}

template<int SGN>
__device__ __forceinline__ void tw_after(cf2* x, float p, float invQ) {
    float s1, c1; __sincosf((float)SGN * 6.283185307179586f * p * invQ, &s1, &c1);
    cf2 w1 = {c1, s1}, w = w1;
    #pragma unroll
    for (int m = 1; m < 16; ++m) { x[PERM(m)] = cmul(x[PERM(m)], w); w = cmul(w, w1); }
}
template<int SGN>
__device__ __forceinline__ void tw_before(cf2* x, float p, float invQ) {
    float s1, c1; __sincosf((float)SGN * 6.283185307179586f * p * invQ, &s1, &c1);
    cf2 w1 = {c1, s1}, w = w1;
    #pragma unroll
    for (int j = 1; j < 16; ++j) { x[j] = cmul(x[j], w); w = cmul(w, w1); }
}

// forward: wg<2048 -> packed u-pair rows (uint pair loads); wg>=2048 -> kernel rows (f32, pre-scale 1/4096)
__global__ __launch_bounds__(256) void fft_fwd_kernel(
    const ushort_t* __restrict__ ubf, const float* __restrict__ s4k,
    uint4* __restrict__ uf, uint4* __restrict__ kf)
{
    __shared__ cf2 S[4368];
    int wg = blockIdx.x, t = threadIdx.x;
    cf2 x[16];
    if (wg < 2048) {
        int bp = wg >> 9, e = wg & 511;
        const unsigned int* p0 = (const unsigned int*)ubf + (size_t)e * 8192 + (size_t)bp * 2048;
        #pragma unroll
        for (int j = 0; j < 8; ++j) x[j] = unpack_c(p0[j * 256 + t]);
    } else {
        const float* p0 = s4k + (size_t)(wg - 2048) * 2048;
        #pragma unroll
        for (int j = 0; j < 8; ++j) x[j] = cf2{p0[j * 256 + t], 0.f};
    }
    dft16_halfin<-1>(x);
    tw_after<-1>(x, (float)t, 1.f / 4096.f);
    int tb = 17 * (t >> 4) + (t & 15);
    #pragma unroll
    for (int m = 0; m < 16; ++m) S[tb + 273 * m] = x[PERM(m)];
    __syncthreads();
    int b2 = 273 * (t >> 4) + (t & 15);
    #pragma unroll
    for (int j = 0; j < 16; ++j) x[j] = S[b2 + 17 * j];
    dft16p<-1>(x);
    tw_after<-1>(x, (float)(t & 15), 1.f / 256.f);
    #pragma unroll
    for (int m = 0; m < 16; ++m) S[b2 + 17 * m] = x[PERM(m)];
    __syncthreads();
    int b3 = 273 * (t >> 4) + 17 * (t & 15);
    #pragma unroll
    for (int j = 0; j < 16; ++j) x[j] = S[b3 + j];
    dft16p<-1>(x);
    const float sc = (wg < 2048) ? 1.f : (1.f / 4096.f);
    uint4* dst = ((wg < 2048) ? (uf + (size_t)wg * 1024) : (kf + (size_t)(wg - 2048) * 1024)) + 4 * t;
    #pragma unroll
    for (int q = 0; q < 4; ++q) {
        uint4 o;
        cf2 v0 = x[PERM(4 * q)] * sc, v1 = x[PERM(4 * q + 1)] * sc;
        cf2 v2 = x[PERM(4 * q + 2)] * sc, v3 = x[PERM(4 * q + 3)] * sc;
        o.x = pack_bf2(v0.x, v0.y);
        o.y = pack_bf2(v1.x, v1.y);
        o.z = pack_bf2(v2.x, v2.y);
        o.w = pack_bf2(v3.x, v3.y);
        dst[q] = o;
    }
}

// inverse: spectra product in registers, DIT stages, half-out; stores packed raw y pairs (uint).
__global__ __launch_bounds__(256) void fft_inv_kernel(
    const uint4* __restrict__ uf, const uint4* __restrict__ kf,
    unsigned int* __restrict__ g2)
{
    __shared__ cf2 S[4368];
    int wg = blockIdx.x, t = threadIdx.x;
    int bp = wg >> 11, ch = (wg >> 9) & 3, e = wg & 511;
    const uint4* zr = uf + (size_t)(bp * 512 + e) * 1024 + 4 * t;
    const uint4* kr = kf + (size_t)(ch * 512 + e) * 1024 + 4 * t;
    cf2 x[16];
    #pragma unroll
    for (int q = 0; q < 4; ++q) {
        uint4 a4 = zr[q], b4 = kr[q];
        x[4 * q + 0] = cmul(unpack_c(a4.x), unpack_c(b4.x));
        x[4 * q + 1] = cmul(unpack_c(a4.y), unpack_c(b4.y));
        x[4 * q + 2] = cmul(unpack_c(a4.z), unpack_c(b4.z));
        x[4 * q + 3] = cmul(unpack_c(a4.w), unpack_c(b4.w));
    }
    dft16p<1>(x);
    int b1 = 273 * (t >> 4) + 17 * (t & 15);
    #pragma unroll
    for (int m = 0; m < 16; ++m) S[b1 + m] = x[PERM(m)];
    __syncthreads();
    int b2 = 273 * (t >> 4) + (t & 15);
    #pragma unroll
    for (int j = 0; j < 16; ++j) x[j] = S[b2 + 17 * j];
    tw_before<1>(x, (float)(t & 15), 1.f / 256.f);
    dft16p<1>(x);
    #pragma unroll
    for (int m = 0; m < 16; ++m) S[b2 + 17 * m] = x[PERM(m)];
    __syncthreads();
    int b3 = 17 * (t >> 4) + (t & 15);
    #pragma unroll
    for (int j = 0; j < 16; ++j) x[j] = S[b3 + 273 * j];
    tw_before<1>(x, (float)t, 1.f / 4096.f);
    cf2 y[8];
    dft16_halfout<1>(x, y);
    unsigned int* go = g2 + (size_t)(ch * 512 + e) * 8192 + (size_t)bp * 2048;
    #pragma unroll
    for (int m = 0; m < 8; ++m)
        go[m * 256 + t] = pack_bf2(y[m].x, y[m].y);
}

// ============================ gdt: D-skip + gelu + pair-unpack transpose ============================
// g2[2048 rows r=ch*512+e][8192 cols cp=bp*2048+l] (uint pairs) -> gT[16384 n][2048 r] bf16
__global__ __launch_bounds__(256) void gdt_kernel(
    const unsigned int* __restrict__ g2, const unsigned int* __restrict__ ub2,
    const float* __restrict__ s4D, ushort_t* __restrict__ gT)
{
    __shared__ unsigned int S2[64 * 65];
    int c0 = blockIdx.x * 64, r0 = blockIdx.y * 64;
    int t = threadIdx.x, lx = t & 63, ly0 = t >> 6;
    #pragma unroll
    for (int ly = ly0; ly < 64; ly += 4) {
        int r = r0 + ly, cp = c0 + lx;
        cf2 y2 = unpack_c(g2[(size_t)r * 8192 + cp]);
        cf2 u2 = unpack_c(ub2[(size_t)(r & 511) * 8192 + cp]);
        float d = s4D[r];
        float v0 = gelu_f(fmaf(d, u2.x, y2.x));
        float v1 = gelu_f(fmaf(d, u2.y, y2.y));
        S2[ly * 65 + lx] = pack_bf2(v0, v1);
    }
    __syncthreads();
    #pragma unroll
    for (int ly = ly0; ly < 64; ly += 4) {
        int oc = c0 + ly;
        unsigned int v = S2[lx * 65 + ly];
        int bp = oc >> 11, l = oc & 2047;
        size_t na = (size_t)(bp * 4096 + l) * 2048 + r0 + lx;
        gT[na] = (ushort_t)(v & 0xffff);
        gT[na + 4194304] = (ushort_t)(v >> 16);
    }
}

// ============================ bf16 MFMA GEMM, software-pipelined ============================
// Both operands k-major. BSRC 0: Bm = B^T [N][K].  BSRC 1: im2col rows from h0pT.
// EPI: 0 gelu(acc+bias)->bf16 | 1 acc+I->bf16 | 2 acc->bf16 | 4 final outputs
//      5 gate-fused: block y computes h2 rows {64y..64y+63}u{256+64y..}, writes gateT[n][256]
template<int BSRC, int EPI>
__global__ __launch_bounds__(256) void gemm_kernel(
    const ushort_t* __restrict__ A, const ushort_t* __restrict__ Bm,
    ushort_t* __restrict__ Cb, float* __restrict__ Cf,
    int M, int N, int K,
    const float* __restrict__ bias, const float* __restrict__ bias2,
    const ushort_t* __restrict__ xnb, float* __restrict__ dout)
{
    __shared__ ushort_t SM[10240];       // Alds[128*40] ++ Blds[128*40]; reused as gate tile (EPI 5)
    ushort_t* Alds = SM;
    ushort_t* Blds = SM + 5120;
    const int t = threadIdx.x;
    const int n0 = blockIdx.x * 128, m0 = blockIdx.y * 128;
    const int w = t >> 6, lane = t & 63, quad = lane >> 4, lr = lane & 15;
    const int wm = (w >> 1) * 64, wn = (w & 1) * 64;

    const int i_s = t >> 1, j0 = (t & 1) * 16;
    int a_row = m0 + i_s;
    if (EPI == 5) a_row = (i_s < 64) ? (64 * blockIdx.y + i_s) : (192 + 64 * blockIdx.y + i_s);
    int bI = 0, lI = 0;
    if (BSRC == 1) { int n = n0 + i_s; bI = n >> 11; lI = n & 2047; }

    float4_t acc[4][4];
    #pragma unroll
    for (int i = 0; i < 4; ++i)
        #pragma unroll
        for (int j = 0; j < 4; ++j) { float4_t z = {0.f, 0.f, 0.f, 0.f}; acc[i][j] = z; }

    short8 pa0, pa1, pb0, pb1;
    {
        const short8* sa = (const short8*)(A + (size_t)a_row * K + j0);
        pa0 = sa[0]; pa1 = sa[1];
        const ushort_t* sp;
        if (BSRC == 0) sp = Bm + (size_t)(n0 + i_s) * K + j0;
        else           sp = Bm + (size_t)(bI * 2050 + lI) * 256 + j0;
        const short8* sb = (const short8*)sp;
        pb0 = sb[0]; pb1 = sb[1];
    }

    for (int kt = 0; kt < K; kt += 32) {
        if (kt) __syncthreads();
        *(short8*)&Alds[i_s * 40 + j0]     = pa0;
        *(short8*)&Alds[i_s * 40 + j0 + 8] = pa1;
        *(short8*)&Blds[i_s * 40 + j0]     = pb0;
        *(short8*)&Blds[i_s * 40 + j0 + 8] = pb1;
        __syncthreads();
        int kn = kt + 32;
        if (kn < K) {
            const short8* sa = (const short8*)(A + (size_t)a_row * K + kn + j0);
            pa0 = sa[0]; pa1 = sa[1];
            const ushort_t* sp;
            if (BSRC == 0) sp = Bm + (size_t)(n0 + i_s) * K + kn + j0;
            else { int dk = kn >> 8, cb = kn & 255; sp = Bm + (size_t)(bI * 2050 + lI + dk) * 256 + cb + j0; }
            const short8* sb = (const short8*)sp;
            pb0 = sb[0]; pb1 = sb[1];
        }
        short8 af[4], bfr[4];
        #pragma unroll
        for (int im = 0; im < 4; ++im)
            af[im] = *(const short8*)&Alds[(wm + im * 16 + lr) * 40 + quad * 8];
        #pragma unroll
        for (int in_ = 0; in_ < 4; ++in_)
            bfr[in_] = *(const short8*)&Blds[(wn + in_ * 16 + lr) * 40 + quad * 8];
        #pragma unroll
        for (int im = 0; im < 4; ++im)
            #pragma unroll
            for (int in_ = 0; in_ < 4; ++in_)
                acc[im][in_] = __builtin_amdgcn_mfma_f32_16x16x32_bf16(af[im], bfr[in_], acc[im][in_], 0, 0, 0);
    }

    if (EPI == 5) {
        const int by = blockIdx.y;
        __syncthreads();                       // staging LDS now dead; reuse as TG[128][68]
        #pragma unroll
        for (int p = 0; p < 2; ++p) {
            if (p) __syncthreads();
            if ((w & 1) == p) {                // waves owning this n-half
                #pragma unroll
                for (int im = 0; im < 4; ++im)
                    #pragma unroll
                    for (int in_ = 0; in_ < 4; ++in_) {
                        int nl = in_ * 16 + lr;
                        #pragma unroll
                        for (int r = 0; r < 4; ++r) {
                            int i = wm + im * 16 + quad * 4 + r;
                            int me = (i < 64) ? (64 * by + i) : (192 + 64 * by + i);
                            SM[i * 68 + nl] = f2bfu(acc[im][in_][r] + bias[me]);
                        }
                    }
            }
            __syncthreads();
            int nl = t >> 2, gcb = (t & 3) * 16;
            size_t obase = (size_t)(n0 + 64 * p + nl) * 256 + 64 * by + gcb;
            short8 o0, o1;
            #pragma unroll
            for (int j = 0; j < 16; ++j) {
                int gc = gcb + j;
                float a = bf2f(SM[gc * 68 + nl]);
                float bb = bf2f(SM[(gc + 64) * 68 + nl]);
                ushort_t gv = f2bfu(tanh_f(a) * sigmoid_f(bb));
                if (j < 8) o0[j] = (short)gv; else o1[j - 8] = (short)gv;
            }
            *(short8*)(Cb + obase) = o0;
            *(short8*)(Cb + obase + 8) = o1;
        }
        return;
    }

    #pragma unroll
    for (int im = 0; im < 4; ++im) {
        #pragma unroll
        for (int in_ = 0; in_ < 4; ++in_) {
            int n = n0 + wn + in_ * 16 + lr;
            int mb = m0 + wm + im * 16 + quad * 4;
            #pragma unroll
            for (int r = 0; r < 4; ++r) {
                int m = mb + r;
                float v = acc[im][in_][r];
                if (EPI == 0) {
                    v += bias[m];
                    ((__hip_bfloat16*)Cb)[(size_t)m * N + n] = __float2bfloat16(gelu_f(v));
                } else if (EPI == 1) {
                    v += (m == n) ? 1.0f : 0.0f;
                    ((__hip_bfloat16*)Cb)[(size_t)m * N + n] = __float2bfloat16(v);
                } else if (EPI == 2) {
                    ((__hip_bfloat16*)Cb)[(size_t)m * N + n] = __float2bfloat16(v);
                } else {
                    int bb = n >> 11, ll = n & 2047;
                    if (m < 256) {
                        v += bias[m];
                        int idx = (bb << 19) + (m << 11) + ll;
                        dout[idx] = (bf2f(xnb[idx]) + v) * 0.70710678118654752f;
                    } else {
                        v += bias2[m - 256];
                        dout[4194304 + (bb << 19) + ((m - 256) << 11) + ll] = v;
                    }
                }
            }
        }
    }
}

// ============================ launch ============================
extern "C" void kernel_launch(void* const* d_in, const int* in_sizes, int n_in,
                              void* d_out, int out_size, void* d_ws, size_t ws_size,
                              hipStream_t stream)
{
    const float* x         = (const float*)d_in[0];
    const float* original  = (const float*)d_in[1];
    const float* sn_scale  = (const float*)d_in[2];
    const float* conv_w    = (const float*)d_in[3];
    const float* conv_b    = (const float*)d_in[4];
    const float* s4_ln_g   = (const float*)d_in[5];
    const float* s4_ln_b   = (const float*)d_in[6];
    const float* s4_kernel = (const float*)d_in[7];
    const float* s4_D      = (const float*)d_in[8];
    const float* s4_out_w  = (const float*)d_in[9];
    const float* s4_out_b  = (const float*)d_in[10];
    const float* attn_v_w  = (const float*)d_in[11];
    const float* attn_v_b  = (const float*)d_in[12];
    const float* attn_o_w  = (const float*)d_in[13];
    const float* attn_o_b  = (const float*)d_in[14];
    const float* res_w     = (const float*)d_in[15];
    const float* res_b     = (const float*)d_in[16];
    const float* skip_w    = (const float*)d_in[17];
    const float* skip_b    = (const float*)d_in[18];

    char* ws = (char*)d_ws;
    __hip_bfloat16* convA = (__hip_bfloat16*)(ws + WS_CONVA);
    __hip_bfloat16* WvT   = (__hip_bfloat16*)(ws + WS_WV);
    __hip_bfloat16* WoBf  = (__hip_bfloat16*)(ws + WS_WO);
    __hip_bfloat16* W1T   = (__hip_bfloat16*)(ws + WS_W1);
    __hip_bfloat16* Wcat  = (__hip_bfloat16*)(ws + WS_WCAT);
    ushort_t* A2    = (ushort_t*)(ws + WS_A2);
    ushort_t* Acomb = (ushort_t*)(ws + WS_ACOMB);
    float* bcombp  = (float*)(ws + WS_BCOMB);
    ushort_t* xnb  = (ushort_t*)(ws + WS_XN);
    ushort_t* h0pT = (ushort_t*)(ws + WS_H0PT);
    ushort_t* hP   = (ushort_t*)(ws + WS_U);
    ushort_t* ubP  = (ushort_t*)(ws + WS_UB);
    uint4* ufP = (uint4*)(ws + WS_UF);
    uint4* kfP = (uint4*)(ws + WS_KF);
    unsigned int* g2P = (unsigned int*)(ws + WS_G);
    ushort_t* gT    = (ushort_t*)(ws + WS_GT);
    ushort_t* gateT = (ushort_t*)(ws + WS_GATET);

    // weight prep + attention-fold precompute
    wprep_kernel<<<dim3(4096), dim3(256), 0, stream>>>(conv_w, attn_v_w, attn_o_w, s4_out_w,
        res_w, skip_w, convA, WvT, WoBf, W1T, Wcat);
    gemm_kernel<0, 1><<<dim3(4, 4), dim3(256), 0, stream>>>(
        (const ushort_t*)WoBf, (const ushort_t*)WvT, A2, nullptr, 512, 512, 512,
        nullptr, nullptr, nullptr, nullptr);
    bias2_kernel<<<dim3(512), dim3(256), 0, stream>>>(
        (const __hip_bfloat16*)A2, s4_out_b, attn_o_w, attn_v_b, attn_o_b, bcombp);
    gemm_kernel<0, 2><<<dim3(16, 4), dim3(256), 0, stream>>>(
        A2, (const ushort_t*)W1T, Acomb, nullptr, 512, 2048, 512,
        nullptr, nullptr, nullptr, nullptr);

    // main pipeline
    prep_kernel<<<dim3(256), dim3(512), 0, stream>>>(x, original, sn_scale, xnb, h0pT);
    gemm_kernel<1, 0><<<dim3(128, 4), dim3(256), 0, stream>>>(
        (const ushort_t*)convA, h0pT, hP, nullptr, 512, NBL, 768,
        conv_b, nullptr, nullptr, nullptr);
    ln_kernel<<<dim3(256), dim3(512), 0, stream>>>(hP, ubP, s4_ln_g, s4_ln_b);
    fft_fwd_kernel<<<dim3(4096), dim3(256), 0, stream>>>(ubP, s4_kernel, ufP, kfP);
    fft_inv_kernel<<<dim3(8192), dim3(256), 0, stream>>>(ufP, kfP, g2P);
    gdt_kernel<<<dim3(128, 32), dim3(256), 0, stream>>>(
        g2P, (const unsigned int*)ubP, s4_D, gT);
    gemm_kernel<0, 5><<<dim3(128, 4), dim3(256), 0, stream>>>(
        (const ushort_t*)Acomb, gT, gateT, nullptr, 512, NBL, 2048,
        bcombp, nullptr, nullptr, nullptr);
    gemm_kernel<0, 4><<<dim3(128, 4), dim3(256), 0, stream>>>(
        (const ushort_t*)Wcat, gateT, nullptr, nullptr, 512, NBL, 256,
        res_b, skip_b, xnb, (float*)d_out);
}